// Round 1
// 843.556 us; speedup vs baseline: 1.0832x; 1.0832x over previous
//
#include <hip/hip_runtime.h>

#define L_ 2
#define B_ 2
#define T_ 2048
#define C_ 1024
#define H_ 16
#define D_ 64
#define F_ 4096
#define NTOK 4096      // B*T
#define NELEM 4194304  // B*T*C

typedef unsigned short u16;
typedef __attribute__((ext_vector_type(8))) short short8;
typedef __attribute__((ext_vector_type(4))) float float4v;

__device__ __forceinline__ float bf2f(u16 u) {
  unsigned v = ((unsigned)u) << 16;
  return __builtin_bit_cast(float, v);
}
__device__ __forceinline__ u16 f2bf(float f) {
  unsigned u = __builtin_bit_cast(unsigned, f);
  u += 0x7FFFu + ((u >> 16) & 1u);   // round-to-nearest-even
  return (u16)(u >> 16);
}

// ---------------- elementwise ----------------
__global__ void k_copyf(const float* __restrict__ in, float* __restrict__ out) {
  const int i = blockIdx.x * 256 + threadIdx.x;
  out[i] = in[i];
}

// ---------------- RMSNorm variants (block per row) ----------------
__device__ __forceinline__ void rms_tail(float* vloc, const float* __restrict__ g,
                                         u16* __restrict__ orow) {
  float s = vloc[0] * vloc[0] + vloc[1] * vloc[1] + vloc[2] * vloc[2] + vloc[3] * vloc[3];
#pragma unroll
  for (int o = 32; o; o >>= 1) s += __shfl_down(s, o);
  __shared__ float red[4];
  __shared__ float rsv;
  if ((threadIdx.x & 63) == 0) red[threadIdx.x >> 6] = s;
  __syncthreads();
  if (threadIdx.x == 0) {
    float t = red[0] + red[1] + red[2] + red[3];
    rsv = rsqrtf(t * (1.f / C_) + 1e-6f);
  }
  __syncthreads();
  const float rr = rsv;
#pragma unroll
  for (int i = 0; i < 4; i++) {
    const int c = threadIdx.x + i * 256;
    orow[c] = f2bf(vloc[i] * rr * g[c]);
  }
}

__global__ __launch_bounds__(256) void k_rms_first(const float* __restrict__ xin,
                                                   const float* __restrict__ g,
                                                   float* __restrict__ x,
                                                   u16* __restrict__ out) {
  const int row = blockIdx.x;
  const float* sr = xin + (size_t)row * C_;
  float* xr = x + (size_t)row * C_;
  float vloc[4];
#pragma unroll
  for (int i = 0; i < 4; i++) {
    const int c = threadIdx.x + i * 256;
    const float v = sr[c];
    vloc[i] = v;
    xr[c] = v;
  }
  rms_tail(vloc, g, out + (size_t)row * C_);
}

__global__ __launch_bounds__(256) void k_rms(const float* __restrict__ x,
                                             const float* __restrict__ g,
                                             u16* __restrict__ out) {
  const int row = blockIdx.x;
  const float* xr = x + (size_t)row * C_;
  float vloc[4];
#pragma unroll
  for (int i = 0; i < 4; i++) vloc[i] = xr[threadIdx.x + i * 256];
  rms_tail(vloc, g, out + (size_t)row * C_);
}

__global__ __launch_bounds__(256) void k_rms2mix(float* __restrict__ x,
                                                 const float* __restrict__ gates,
                                                 const float* __restrict__ ret,
                                                 const float* __restrict__ g,
                                                 u16* __restrict__ out) {
  const int row = blockIdx.x;
  const int b = row >> 11;   // T=2048
  const float g2 = gates[row * 2 + 1];
  const float* rr_ = ret + b * C_;
  float* xr = x + (size_t)row * C_;
  float vloc[4];
#pragma unroll
  for (int i = 0; i < 4; i++) {
    const int c = threadIdx.x + i * 256;
    const float v = xr[c] + g2 * rr_[c];
    vloc[i] = v;
    xr[c] = v;
  }
  rms_tail(vloc, g, out + (size_t)row * C_);
}

// ---------------- batched transpose+convert: two f32 (K,N) -> bf16 (N,K) ----------
__global__ void k_tr2(const float* __restrict__ s0, u16* __restrict__ d0,
                      int K0, int N0, int t0,
                      const float* __restrict__ s1, u16* __restrict__ d1,
                      int K1, int N1) {
  __shared__ float tile[32][33];
  int t = blockIdx.x;
  const float* src; u16* dst; int K, N;
  if (t < t0) { src = s0; dst = d0; K = K0; N = N0; }
  else { t -= t0; src = s1; dst = d1; K = K1; N = N1; }
  const int ntx = N >> 5;
  const int tx = t % ntx, ty = t / ntx;
  const int x = tx * 32 + threadIdx.x;
  const int y0 = ty * 32 + threadIdx.y;
#pragma unroll
  for (int i = 0; i < 32; i += 8) tile[threadIdx.y + i][threadIdx.x] = src[(size_t)(y0 + i) * N + x];
  __syncthreads();
  const int x2 = ty * 32 + threadIdx.x;
  const int y2 = tx * 32 + threadIdx.y;
#pragma unroll
  for (int i = 0; i < 32; i += 8) dst[(size_t)(y2 + i) * K + x2] = f2bf(tile[threadIdx.x][threadIdx.y + i]);
}

__global__ void k_tr1(const float* __restrict__ in, u16* __restrict__ out, int K, int N) {
  __shared__ float tile[32][33];
  const int ntx = N >> 5;
  const int tx = blockIdx.x % ntx, ty = blockIdx.x / ntx;
  const int x = tx * 32 + threadIdx.x;
  const int y0 = ty * 32 + threadIdx.y;
#pragma unroll
  for (int i = 0; i < 32; i += 8) tile[threadIdx.y + i][threadIdx.x] = in[(size_t)(y0 + i) * N + x];
  __syncthreads();
  const int x2 = ty * 32 + threadIdx.x;
  const int y2 = tx * 32 + threadIdx.y;
#pragma unroll
  for (int i = 0; i < 32; i += 8) out[(size_t)(y2 + i) * K + x2] = f2bf(tile[threadIdx.x][threadIdx.y + i]);
}

// ---------------- V transpose ----------------
__global__ void k_vt(const u16* __restrict__ qkv, u16* __restrict__ Vt) {
  __shared__ u16 tile[32][34];
  const int jt = blockIdx.x;
  const int dt = blockIdx.y;
  const int bh = blockIdx.z;
  const int b = bh >> 4;
  const int h = bh & 15;
  const int tx = threadIdx.x, ty = threadIdx.y;
#pragma unroll
  for (int i = 0; i < 32; i += 8) {
    const int j = jt * 32 + ty + i;
    const int d = dt * 32 + tx;
    tile[ty + i][tx] = qkv[(size_t)(b * T_ + j) * (3 * C_) + 2 * C_ + h * D_ + d];
  }
  __syncthreads();
#pragma unroll
  for (int i = 0; i < 32; i += 8) {
    const int d = dt * 32 + ty + i;
    const int j = jt * 32 + tx;
    Vt[(size_t)(bh * D_ + d) * T_ + j] = tile[tx][ty + i];
  }
}

// ================== 8-phase 256-wide-tile GEMM machinery ==================
// T2 (XOR swizzle, pre-swizzled global source + swizzled ds_read) +
// T3/T4 (8-phase interleave, counted vmcnt — never 0 in main loop) +
// T5 (setprio around MFMA clusters). 512 thr = 8 waves (2M x 4N).
// LDS: 128 KiB dynamic, double-buffered.

#define VMW(n) asm volatile("s_waitcnt vmcnt(" #n ")" ::: "memory")
#define LGKM0 asm volatile("s_waitcnt lgkmcnt(0)" ::: "memory")
#define GBAR() __builtin_amdgcn_s_barrier()
#define PRIO1() __builtin_amdgcn_s_setprio(1)
#define PRIO0() __builtin_amdgcn_s_setprio(0)

// Stage one 128-row x 64-col bf16 half-tile: 2 x global_load_lds_dwordx4.
// Dest is linear (wave-uniform base + lane*16); source column is pre-swizzled.
#define STG8(gsrc, grow0, dstbyte, kk)                                                    \
  do {                                                                                    \
    const u16* g0_ = (gsrc) + (size_t)((grow0) + wid * 8 + srow) * K + (kk) + scol;       \
    __builtin_amdgcn_global_load_lds(                                                     \
        (const __attribute__((address_space(1))) void*)g0_,                               \
        (__attribute__((address_space(3))) void*)(lc + (dstbyte) + wid * 8 * 128),        \
        16, 0, 0);                                                                        \
    const u16* g1_ = g0_ + (size_t)64 * K;                                                \
    __builtin_amdgcn_global_load_lds(                                                     \
        (const __attribute__((address_space(1))) void*)g1_,                               \
        (__attribute__((address_space(3))) void*)(lc + (dstbyte) + (64 + wid * 8) * 128), \
        16, 0, 0);                                                                        \
  } while (0)

// A-fragment reads: 4 m-frags x 2 ksub (8 x ds_read_b128), swizzled slot.
#define RDA4(dst, bufbyte, ig0)                                                           \
  { _Pragma("unroll") for (int i_ = 0; i_ < 4; ++i_) {                                    \
      _Pragma("unroll") for (int s_ = 0; s_ < 2; ++s_)                                    \
        dst[i_][s_] = *(const short8*)(lc + (bufbyte) +                                   \
            (wm * 128 + ((ig0) + i_) * 16 + m16) * 128 + (((s_ * 4 + quad) ^ csw) * 16)); } }

// B-fragment reads (plain kernel, 64-col wave band): 2 n-frags x 2 ksub.
#define RDB4(dst, bufbyte, jg0)                                                           \
  { _Pragma("unroll") for (int j_ = 0; j_ < 2; ++j_) {                                    \
      _Pragma("unroll") for (int s_ = 0; s_ < 2; ++s_)                                    \
        dst[j_][s_] = *(const short8*)(lc + (bufbyte) +                                   \
            (wn * 64 + ((jg0) + j_) * 16 + m16) * 128 + (((s_ * 4 + quad) ^ csw) * 16)); } }

// B-fragment reads (swiglu kernel, 32-col wave band).
#define RDBS(dst, bufbyte)                                                                \
  { _Pragma("unroll") for (int j_ = 0; j_ < 2; ++j_) {                                    \
      _Pragma("unroll") for (int s_ = 0; s_ < 2; ++s_)                                    \
        dst[j_][s_] = *(const short8*)(lc + (bufbyte) +                                   \
            (wn * 32 + j_ * 16 + m16) * 128 + (((s_ * 4 + quad) ^ csw) * 16)); } }

// 16 MFMA cluster (one C-quadrant x K=64).
#define MM16(ig0, jg0, bv_)                                                               \
  { _Pragma("unroll") for (int i_ = 0; i_ < 4; ++i_) {                                    \
      _Pragma("unroll") for (int j_ = 0; j_ < 2; ++j_) {                                  \
        _Pragma("unroll") for (int s_ = 0; s_ < 2; ++s_)                                  \
          acc[(ig0) + i_][(jg0) + j_] = __builtin_amdgcn_mfma_f32_16x16x32_bf16(          \
              av[i_][s_], bv_[j_][s_], acc[(ig0) + i_][(jg0) + j_], 0, 0, 0); } } }

#define MMS(accv, ig0, bv_)                                                               \
  { _Pragma("unroll") for (int i_ = 0; i_ < 4; ++i_) {                                    \
      _Pragma("unroll") for (int j_ = 0; j_ < 2; ++j_) {                                  \
        _Pragma("unroll") for (int s_ = 0; s_ < 2; ++s_)                                  \
          accv[(ig0) + i_][j_] = __builtin_amdgcn_mfma_f32_16x16x32_bf16(                 \
              av[i_][s_], bv_[j_][s_], accv[(ig0) + i_][j_], 0, 0, 0); } } }

// ---------------- plain 256x256 GEMM, C = A @ Bt^T, split-K via gridDim.z ----------
// EPI=0: Cc = bf16(v); EPI=1: atomicAdd(Xf, gate0*v); EPI=2: atomicAdd(Xf, v)
template <int EPI>
__global__ __launch_bounds__(512, 2) void k_g256(const u16* __restrict__ A,
                                                 const u16* __restrict__ Bt,
                                                 u16* __restrict__ Cc,
                                                 float* __restrict__ Xf,
                                                 const float* __restrict__ gates,
                                                 int N, int K) {
  extern __shared__ __align__(16) u16 lds[];
  char* const lc = (char*)lds;
  // byte layout: buf0.A[0,32K) buf0.B[32K,64K) buf1.A[64K,96K) buf1.B[96K,128K)
  enum { A0B = 0, B0B = 32768, A1B = 65536, B1B = 98304 };
  const int tid = threadIdx.x;
  const int wid = tid >> 6, lane = tid & 63;
  const int wm = wid >> 2, wn = wid & 3;
  const int quad = lane >> 4, m16 = lane & 15;
  const int srow = lane >> 3, sc = lane & 7;
  const int scol = ((sc ^ srow) & 7) * 8;
  const int csw = m16 & 7;
  const int m0 = blockIdx.x * 256, n0 = blockIdx.y * 256;
  const int Kslice = K / gridDim.z;
  const int kbeg = blockIdx.z * Kslice;
  const int ntile = Kslice >> 6;   // 64-wide K tiles; must be even (all configs are)
  const int nit = ntile >> 1;

  float4v acc[8][4];
#pragma unroll
  for (int i = 0; i < 8; i++)
#pragma unroll
    for (int j = 0; j < 4; j++) acc[i][j] = (float4v){0.f, 0.f, 0.f, 0.f};
  short8 av[4][2], b01[2][2], b23[2][2];

  // prologue: T0 fully (B0,B1,A0,A1) + T1.B0,B1 ; retire T0, leave T1.B in flight
  STG8(Bt, n0, B0B, kbeg);
  STG8(Bt, n0 + 128, B0B + 16384, kbeg);
  STG8(A, m0, A0B, kbeg);
  STG8(A, m0 + 128, A0B + 16384, kbeg);
  STG8(Bt, n0, B1B, kbeg + 64);
  STG8(Bt, n0 + 128, B1B + 16384, kbeg + 64);
  VMW(4);
  GBAR();

#pragma unroll 1
  for (int it = 0; it < nit; ++it) {
    const int t2 = 2 * it + 2, t3 = 2 * it + 3;
    const int k1 = kbeg + (2 * it + 1) * 64;                      // never wraps
    const int k2 = kbeg + (t2 < ntile ? t2 : t2 - ntile) * 64;    // wraps last iter (dead data)
    const int k3 = kbeg + (t3 < ntile ? t3 : t3 - ntile) * 64;
    // P1: buf0 A(m0-3)+B(n0-1); stage T1.A0->buf1
    RDA4(av, A0B, 0);
    RDB4(b01, B0B, 0);
    STG8(A, m0, A1B, k1);
    GBAR(); LGKM0;
    PRIO1(); MM16(0, 0, b01); PRIO0();
    GBAR();
    // P2: B(n2-3); stage T1.A1->buf1
    RDB4(b23, B0B, 2);
    STG8(A, m0 + 128, A1B + 16384, k1);
    GBAR(); LGKM0;
    PRIO1(); MM16(0, 2, b23); PRIO0();
    GBAR();
    // P3: A(m4-7); stage T2.B0->buf0 (buf0.B fully read after P2)
    RDA4(av, A0B, 4);
    STG8(Bt, n0, B0B, k2);
    GBAR(); LGKM0;
    PRIO1(); MM16(4, 2, b23); PRIO0();
    GBAR();
    // P4: stage T2.B1->buf0; counted vmcnt retires T1 (needed P5-P8)
    STG8(Bt, n0 + 128, B0B + 16384, k2);
    VMW(4);
    GBAR(); LGKM0;
    PRIO1(); MM16(4, 0, b01); PRIO0();
    GBAR();
    // P5: buf1 A(m0-3)+B(n0-1); stage T2.A0->buf0 (buf0.A fully read after P3)
    RDA4(av, A1B, 0);
    RDB4(b01, B1B, 0);
    STG8(A, m0, A0B, k2);
    GBAR(); LGKM0;
    PRIO1(); MM16(0, 0, b01); PRIO0();
    GBAR();
    // P6: stage T2.A1->buf0
    RDB4(b23, B1B, 2);
    STG8(A, m0 + 128, A0B + 16384, k2);
    GBAR(); LGKM0;
    PRIO1(); MM16(0, 2, b23); PRIO0();
    GBAR();
    // P7: stage T3.B0->buf1 (buf1.B fully read after P6)
    RDA4(av, A1B, 4);
    STG8(Bt, n0, B1B, k3);
    GBAR(); LGKM0;
    PRIO1(); MM16(4, 2, b23); PRIO0();
    GBAR();
    // P8: stage T3.B1->buf1; counted vmcnt retires T2
    STG8(Bt, n0 + 128, B1B + 16384, k3);
    VMW(4);
    GBAR(); LGKM0;
    PRIO1(); MM16(4, 0, b01); PRIO0();
    GBAR();
  }

#pragma unroll
  for (int i = 0; i < 8; i++) {
    const int row0 = m0 + wm * 128 + i * 16 + quad * 4;
#pragma unroll
    for (int j = 0; j < 4; j++) {
      const int col = n0 + wn * 64 + j * 16 + m16;
#pragma unroll
      for (int r = 0; r < 4; r++) {
        const size_t idx = (size_t)(row0 + r) * N + col;
        const float v = acc[i][j][r];
        if (EPI == 0) Cc[idx] = f2bf(v);
        else if (EPI == 1) unsafeAtomicAdd(&Xf[idx], gates[(row0 + r) * 2] * v);
        else unsafeAtomicAdd(&Xf[idx], v);
      }
    }
  }
}

// ---------------- fused SwiGLU dual-GEMM, 256x128 tile, 8-phase ----------
__global__ __launch_bounds__(512, 2) void k_g256s(const u16* __restrict__ A,
                                                  const u16* __restrict__ Btg,
                                                  const u16* __restrict__ Btu,
                                                  u16* __restrict__ Cc,
                                                  int N, int K) {
  extern __shared__ __align__(16) u16 lds[];
  char* const lc = (char*)lds;
  // byte layout: buf0: A[0,32K) Bg[32K,48K) Bu[48K,64K); buf1 at +64K
  enum { SA0 = 0, SG0 = 32768, SU0 = 49152, SA1 = 65536, SG1 = 98304, SU1 = 114688 };
  const int tid = threadIdx.x;
  const int wid = tid >> 6, lane = tid & 63;
  const int wm = wid >> 2, wn = wid & 3;
  const int quad = lane >> 4, m16 = lane & 15;
  const int srow = lane >> 3, sc = lane & 7;
  const int scol = ((sc ^ srow) & 7) * 8;
  const int csw = m16 & 7;
  const int m0 = blockIdx.x * 256, n0 = blockIdx.y * 128;
  const int kbeg = 0;
  const int ntile = K >> 6;
  const int nit = ntile >> 1;

  float4v accg[8][2], accu[8][2];
#pragma unroll
  for (int i = 0; i < 8; i++)
#pragma unroll
    for (int j = 0; j < 2; j++) {
      accg[i][j] = (float4v){0.f, 0.f, 0.f, 0.f};
      accu[i][j] = (float4v){0.f, 0.f, 0.f, 0.f};
    }
  short8 av[4][2], bg[2][2], bu[2][2];

  // prologue: T0 {Bg,Bu,A0,A1} + T1 {Bg,Bu,A0}; retire T0, 3 halves in flight
  STG8(Btg, n0, SG0, kbeg);
  STG8(Btu, n0, SU0, kbeg);
  STG8(A, m0, SA0, kbeg);
  STG8(A, m0 + 128, SA0 + 16384, kbeg);
  STG8(Btg, n0, SG1, kbeg + 64);
  STG8(Btu, n0, SU1, kbeg + 64);
  STG8(A, m0, SA1, kbeg + 64);
  VMW(6);
  GBAR();

#pragma unroll 1
  for (int it = 0; it < nit; ++it) {
    const int t2 = 2 * it + 2, t3 = 2 * it + 3;
    const int k1 = kbeg + (2 * it + 1) * 64;
    const int k2 = kbeg + (t2 < ntile ? t2 : t2 - ntile) * 64;
    const int k3 = kbeg + (t3 < ntile ? t3 : t3 - ntile) * 64;
    // P1: A(m0-3)+Bg buf0; stage T1.A1->buf1; g MFMA (lo)
    RDA4(av, SA0, 0);
    RDBS(bg, SG0);
    STG8(A, m0 + 128, SA1 + 16384, k1);
    GBAR(); LGKM0;
    PRIO1(); MMS(accg, 0, bg); PRIO0();
    GBAR();
    // P2: Bu buf0; stage T2.Bg->buf0 (Bg read done P1); u MFMA (lo)
    RDBS(bu, SU0);
    STG8(Btg, n0, SG0, k2);
    GBAR(); LGKM0;
    PRIO1(); MMS(accu, 0, bu); PRIO0();
    GBAR();
    // P3: A(m4-7) buf0; stage T2.Bu->buf0; u MFMA (hi)
    RDA4(av, SA0, 4);
    STG8(Btu, n0, SU0, k2);
    GBAR(); LGKM0;
    PRIO1(); MMS(accu, 4, bu); PRIO0();
    GBAR();
    // P4: stage T2.A0->buf0 (A read done P3); vmcnt retires T1; g MFMA (hi)
    STG8(A, m0, SA0, k2);
    VMW(6);
    GBAR(); LGKM0;
    PRIO1(); MMS(accg, 4, bg); PRIO0();
    GBAR();
    // P5: buf1 A(m0-3)+Bg; stage T2.A1->buf0
    RDA4(av, SA1, 0);
    RDBS(bg, SG1);
    STG8(A, m0 + 128, SA0 + 16384, k2);
    GBAR(); LGKM0;
    PRIO1(); MMS(accg, 0, bg); PRIO0();
    GBAR();
    // P6: Bu buf1; stage T3.Bg->buf1
    RDBS(bu, SU1);
    STG8(Btg, n0, SG1, k3);
    GBAR(); LGKM0;
    PRIO1(); MMS(accu, 0, bu); PRIO0();
    GBAR();
    // P7: A(m4-7) buf1; stage T3.Bu->buf1
    RDA4(av, SA1, 4);
    STG8(Btu, n0, SU1, k3);
    GBAR(); LGKM0;
    PRIO1(); MMS(accu, 4, bu); PRIO0();
    GBAR();
    // P8: stage T3.A0->buf1; vmcnt retires T2
    STG8(A, m0, SA1, k3);
    VMW(6);
    GBAR(); LGKM0;
    PRIO1(); MMS(accg, 4, bg); PRIO0();
    GBAR();
  }

#pragma unroll
  for (int i = 0; i < 8; i++) {
    const int row0 = m0 + wm * 128 + i * 16 + quad * 4;
#pragma unroll
    for (int j = 0; j < 2; j++) {
      const int col = n0 + wn * 32 + j * 16 + m16;
#pragma unroll
      for (int r = 0; r < 4; r++) {
        const float g = accg[i][j][r];
        const float u = accu[i][j][r];
        Cc[(size_t)(row0 + r) * N + col] = f2bf(u * g / (1.f + __expf(-g)));
      }
    }
  }
}

// ---------------- fused attention: one wave per (b, h, 16-query tile) -------------
__global__ __launch_bounds__(256) void k_attn(const u16* __restrict__ qkv,
                                              const u16* __restrict__ Vt,
                                              u16* __restrict__ o) {
  __shared__ u16 lds[4][16][290];
  const int wave = threadIdx.x >> 6;
  const int widG = blockIdx.x * 4 + wave;
  const int lane = threadIdx.x & 63;
  const int quad = lane >> 4;
  const int c16 = lane & 15;
  const int qt = (widG & 127) * 16;
  const int h = (widG >> 7) & 15;
  const int b = widG >> 11;
  const size_t rs = 3 * C_;
  const int jt0 = qt - 256;

  const u16* qrow = qkv + (size_t)(b * T_ + qt + c16) * rs + h * D_ + quad * 8;
  const short8 a0 = *(const short8*)(qrow);
  const short8 a1 = *(const short8*)(qrow + 32);
  float4v S[17];
  const short8 z8 = (short8){0, 0, 0, 0, 0, 0, 0, 0};
#pragma unroll
  for (int t = 0; t < 17; t++) {
    if (jt0 + t * 16 + 15 < 0) { S[t] = (float4v){0.f, 0.f, 0.f, 0.f}; continue; }
    const int j = jt0 + t * 16 + c16;
    short8 b0 = z8, b1 = z8;
    if (j >= 0) {
      const u16* krow = qkv + (size_t)(b * T_ + j) * rs + C_ + h * D_ + quad * 8;
      b0 = *(const short8*)(krow);
      b1 = *(const short8*)(krow + 32);
    }
    float4v z = (float4v){0.f, 0.f, 0.f, 0.f};
    z = __builtin_amdgcn_mfma_f32_16x16x32_bf16(a0, b0, z, 0, 0, 0);
    z = __builtin_amdgcn_mfma_f32_16x16x32_bf16(a1, b1, z, 0, 0, 0);
    S[t] = z;
  }
#pragma unroll
  for (int r = 0; r < 4; r++) {
    const int q = qt + quad * 4 + r;
    float mx = -1.0e30f;
#pragma unroll
    for (int t = 0; t < 17; t++) {
      const int j = jt0 + t * 16 + c16;
      const int w = j - q + 255;
      const bool vis = (j >= 0) && (w >= 0) && (w < 256);
      if (vis) {
        const float s = S[t][r] * 0.125f;
        S[t][r] = s;
        mx = fmaxf(mx, s);
      } else {
        S[t][r] = -1.0e30f;
      }
    }
#pragma unroll
    for (int o2 = 1; o2 < 16; o2 <<= 1) mx = fmaxf(mx, __shfl_xor(mx, o2));
    float sum = 0.f;
#pragma unroll
    for (int t = 0; t < 17; t++) {
      const float e = (S[t][r] > -0.9e30f) ? __expf(S[t][r] - mx) : 0.f;
      S[t][r] = e;
      sum += e;
    }
#pragma unroll
    for (int o2 = 1; o2 < 16; o2 <<= 1) sum += __shfl_xor(sum, o2);
    const float inv = 1.f / fmaxf(sum, 1e-30f);
    const int prow = quad * 4 + r;
#pragma unroll
    for (int t = 0; t < 17; t++) lds[wave][prow][t * 16 + c16] = f2bf(S[t][r] * inv);
    lds[wave][prow][272 + c16] = 0;
  }
  __syncthreads();

  float4v acc[4];
#pragma unroll
  for (int md = 0; md < 4; md++) acc[md] = (float4v){0.f, 0.f, 0.f, 0.f};
  const u16* vtb = Vt + (size_t)((b * H_ + h) * D_) * T_;
  const uint* prow32 = (const uint*)(&lds[wave][c16][0]);
  union { short8 s8; uint u[4]; } bf;
#pragma unroll
  for (int c = 0; c < 9; c++) {
    const int jbase = jt0 + c * 32;
    if (jbase + 31 < 0) continue;
#pragma unroll
    for (int w2 = 0; w2 < 4; w2++) bf.u[w2] = prow32[c * 16 + quad * 4 + w2];
    int j0 = jbase + quad * 8;
    j0 = (j0 < 0) ? 0 : ((j0 > T_ - 8) ? (T_ - 8) : j0);
#pragma unroll
    for (int md = 0; md < 4; md++) {
      const short8 af = *(const short8*)(vtb + (size_t)(md * 16 + c16) * T_ + j0);
      acc[md] = __builtin_amdgcn_mfma_f32_16x16x32_bf16(af, bf.s8, acc[md], 0, 0, 0);
    }
  }
#pragma unroll
  for (int md = 0; md < 4; md++) {
    uint u0 = (uint)f2bf(acc[md][0]) | ((uint)f2bf(acc[md][1]) << 16);
    uint u1 = (uint)f2bf(acc[md][2]) | ((uint)f2bf(acc[md][3]) << 16);
    uint2 pk = make_uint2(u0, u1);
    u16* dst = o + (size_t)(b * T_ + qt + c16) * C_ + h * D_ + md * 16 + quad * 4;
    *(uint2*)dst = pk;
  }
}

// ---------------- gate logits + 2-way softmax ----------
__global__ __launch_bounds__(256) void k_gate(const u16* __restrict__ h,
                                              const float* __restrict__ gW,
                                              const float* __restrict__ gb,
                                              float* __restrict__ gates) {
  const int row = blockIdx.x * 4 + (threadIdx.x >> 6);
  const int lane = threadIdx.x & 63;
  const u16* hr = h + (size_t)row * C_;
  float s0 = 0.f, s2 = 0.f;
  for (int k = lane; k < C_; k += 64) {
    const float hv = bf2f(hr[k]);
    s0 += hv * gW[k * 3 + 0];
    s2 += hv * gW[k * 3 + 2];
  }
#pragma unroll
  for (int o = 32; o; o >>= 1) { s0 += __shfl_down(s0, o); s2 += __shfl_down(s2, o); }
  if (lane == 0) {
    const float l0 = s0 + gb[0];
    const float l2 = s2 + gb[2];
    const float m = fmaxf(l0, l2);
    const float e0 = __expf(l0 - m), e2 = __expf(l2 - m);
    const float inv = 1.f / (e0 + e2);
    gates[row * 2 + 0] = e0 * inv;
    gates[row * 2 + 1] = e2 * inv;
  }
}

// ---------------- both layers' retrieval projections ---------------
__global__ void k_ret2(const float* __restrict__ rc, const float* __restrict__ rW,
                       float* __restrict__ ret) {
  const int l = blockIdx.x >> 3;
  const int bid = blockIdx.x & 7;
  const int b = bid >> 2;
  const int col = (bid & 3) * 256 + threadIdx.x;
  const float* rWl = rW + (size_t)l * C_ * C_;
  float s = 0.f;
  for (int k = 0; k < C_; k++) s += rc[b * C_ + k] * rWl[(size_t)k * C_ + col];
  ret[(size_t)l * B_ * C_ + b * C_ + col] = s;
}

// ---------------- launcher ----------------
extern "C" void kernel_launch(void* const* d_in, const int* in_sizes, int n_in,
                              void* d_out, int out_size, void* d_ws, size_t ws_size,
                              hipStream_t stream) {
  (void)in_sizes; (void)n_in; (void)out_size; (void)ws_size;
  const float* xin  = (const float*)d_in[0];
  const float* rc   = (const float*)d_in[1];
  const float* n1g  = (const float*)d_in[2];
  const float* Wqkv = (const float*)d_in[3];
  const float* Wpro = (const float*)d_in[4];
  const float* gW   = (const float*)d_in[5];
  const float* gb   = (const float*)d_in[6];
  const float* rW   = (const float*)d_in[7];
  const float* n2g  = (const float*)d_in[8];
  const float* fgW  = (const float*)d_in[9];
  const float* fuW  = (const float*)d_in[10];
  const float* fdW  = (const float*)d_in[11];

  static bool attr_done = false;
  if (!attr_done) {
    hipFuncSetAttribute((const void*)k_g256<0>, hipFuncAttributeMaxDynamicSharedMemorySize, 131072);
    hipFuncSetAttribute((const void*)k_g256<1>, hipFuncAttributeMaxDynamicSharedMemorySize, 131072);
    hipFuncSetAttribute((const void*)k_g256<2>, hipFuncAttributeMaxDynamicSharedMemorySize, 131072);
    hipFuncSetAttribute((const void*)k_g256s, hipFuncAttributeMaxDynamicSharedMemorySize, 131072);
    attr_done = true;
  }

  // ---- workspace layout: 56.06 MiB ----
  char* w = (char*)d_ws;
  float* gates = (float*)(w);                            // 32 KB (per-layer, reused)
  float* retb  = (float*)(w + 32768);                    // 16 KB: [L][B][C]
  float* xf32  = (float*)(w + 65536);                    // 16.78 MB residual (f32)
  u16* hbuf    = (u16*)(w + 65536 + (size_t)NELEM * 4);  // 8.39 MB h | h2 | fd^T
  u16* big     = hbuf + NELEM;                           // 33.55 MB region
  u16* qkv  = big;                          // 25.17 MB (attn phase)
  u16* obuf = big + (size_t)NTOK * 3 * C_;  // 8.39 MB  (attn phase)
  u16* gbuf = big;                          // 33.55 MB (FFN phase)
  u16* wT  = (u16*)d_out;                    // 8.39 MB
  u16* wTp = wT + (size_t)3 * C_ * C_;       // Wproj^T
  u16* Vt  = (u16*)d_out + (size_t)NELEM;    // 8.39 MB upper half
  u16* wT2 = Vt;                             // FFN alias

  k_ret2<<<16, 256, 0, stream>>>(rc, rW, retb);

  for (int l = 0; l < L_; l++) {
    if (l == 0)
      k_rms_first<<<NTOK, 256, 0, stream>>>(xin, n1g, xf32, hbuf);
    else
      k_rms<<<NTOK, 256, 0, stream>>>(xf32, n1g + l * C_, hbuf);
    k_tr2<<<3072 + 1024, dim3(32, 8), 0, stream>>>(
        Wqkv + (size_t)l * C_ * 3 * C_, wT, C_, 3 * C_, 3072,
        Wpro + (size_t)l * C_ * C_, wTp, C_, C_);
    // qkv = h @ Wqkv  (8-phase 256^2)
    k_g256<0><<<dim3(NTOK / 256, 3 * C_ / 256, 1), 512, 131072, stream>>>(
        hbuf, wT, qkv, nullptr, nullptr, 3 * C_, C_);
    k_gate<<<NTOK / 4, 256, 0, stream>>>(hbuf, gW + (size_t)l * C_ * 3, gb + l * 3, gates);
    k_vt<<<dim3(64, 2, 32), dim3(32, 8), 0, stream>>>(qkv, Vt);
    k_attn<<<1024, 256, 0, stream>>>(qkv, Vt, obuf);
    // x += gate0 * (o @ Wproj)   [split-K=2, f32 atomic into residual]
    k_g256<1><<<dim3(NTOK / 256, C_ / 256, 2), 512, 131072, stream>>>(
        obuf, wTp, nullptr, xf32, gates, C_, C_);
    k_rms2mix<<<NTOK, 256, 0, stream>>>(xf32, gates, retb + (size_t)l * B_ * C_,
                                        n2g + l * C_, hbuf);
    k_tr2<<<4096 + 4096, dim3(32, 8), 0, stream>>>(
        fgW + (size_t)l * C_ * F_, wT, C_, F_, 4096,
        fuW + (size_t)l * C_ * F_, wT2, C_, F_);
    // gbuf = silu(h2@Wg) * (h2@Wu)  (fused 8-phase 256x128)
    k_g256s<<<dim3(NTOK / 256, F_ / 128, 1), 512, 131072, stream>>>(
        hbuf, wT, wT2, gbuf, F_, C_);
    k_tr1<<<4096, dim3(32, 8), 0, stream>>>(fdW + (size_t)l * F_ * C_, hbuf, F_, C_);
    // x += gbuf @ Wd   [split-K=4, f32 atomic into residual]
    k_g256<2><<<dim3(NTOK / 256, C_ / 256, 4), 512, 131072, stream>>>(
        gbuf, hbuf, nullptr, xf32, nullptr, C_, F_);
  }

  k_copyf<<<NELEM / 256, 256, 0, stream>>>(xf32, (float*)d_out);
}

// Round 2
// 822.643 us; speedup vs baseline: 1.1108x; 1.0254x over previous
//
#include <hip/hip_runtime.h>

#define L_ 2
#define B_ 2
#define T_ 2048
#define C_ 1024
#define H_ 16
#define D_ 64
#define F_ 4096
#define NTOK 4096      // B*T
#define NELEM 4194304  // B*T*C

typedef unsigned short u16;
typedef __attribute__((ext_vector_type(8))) short short8;
typedef __attribute__((ext_vector_type(4))) float float4v;

__device__ __forceinline__ float bf2f(u16 u) {
  unsigned v = ((unsigned)u) << 16;
  return __builtin_bit_cast(float, v);
}
__device__ __forceinline__ u16 f2bf(float f) {
  unsigned u = __builtin_bit_cast(unsigned, f);
  u += 0x7FFFu + ((u >> 16) & 1u);   // round-to-nearest-even
  return (u16)(u >> 16);
}

// ---------------- elementwise ----------------
__global__ void k_copyf_acc(const float* __restrict__ in, float* __restrict__ out) {
  // out aliases the f32 partial buffer: out = x + partial (in place)
  const int i = blockIdx.x * 256 + threadIdx.x;
  out[i] = in[i] + out[i];
}

// ---------------- RMSNorm variants (block per row) ----------------
__device__ __forceinline__ void rms_tail(float* vloc, const float* __restrict__ g,
                                         u16* __restrict__ orow) {
  float s = vloc[0] * vloc[0] + vloc[1] * vloc[1] + vloc[2] * vloc[2] + vloc[3] * vloc[3];
#pragma unroll
  for (int o = 32; o; o >>= 1) s += __shfl_down(s, o);
  __shared__ float red[4];
  __shared__ float rsv;
  if ((threadIdx.x & 63) == 0) red[threadIdx.x >> 6] = s;
  __syncthreads();
  if (threadIdx.x == 0) {
    float t = red[0] + red[1] + red[2] + red[3];
    rsv = rsqrtf(t * (1.f / C_) + 1e-6f);
  }
  __syncthreads();
  const float rr = rsv;
#pragma unroll
  for (int i = 0; i < 4; i++) {
    const int c = threadIdx.x + i * 256;
    orow[c] = f2bf(vloc[i] * rr * g[c]);
  }
}

__global__ __launch_bounds__(256) void k_rms_first(const float* __restrict__ xin,
                                                   const float* __restrict__ g,
                                                   float* __restrict__ x,
                                                   u16* __restrict__ out) {
  const int row = blockIdx.x;
  const float* sr = xin + (size_t)row * C_;
  float* xr = x + (size_t)row * C_;
  float vloc[4];
#pragma unroll
  for (int i = 0; i < 4; i++) {
    const int c = threadIdx.x + i * 256;
    const float v = sr[c];
    vloc[i] = v;
    xr[c] = v;
  }
  rms_tail(vloc, g, out + (size_t)row * C_);
}

// first norm + fold-in of the down-proj z0 partial: x += pf (write back), rms -> out
__global__ __launch_bounds__(256) void k_rms_acc(float* __restrict__ x,
                                                 const float* __restrict__ pf,
                                                 const float* __restrict__ g,
                                                 u16* __restrict__ out) {
  const int row = blockIdx.x;
  float* xr = x + (size_t)row * C_;
  const float* pr = pf + (size_t)row * C_;
  float vloc[4];
#pragma unroll
  for (int i = 0; i < 4; i++) {
    const int c = threadIdx.x + i * 256;
    const float v = xr[c] + pr[c];
    vloc[i] = v;
    xr[c] = v;
  }
  rms_tail(vloc, g, out + (size_t)row * C_);
}

__global__ __launch_bounds__(256) void k_rms2mix(float* __restrict__ x,
                                                 const float* __restrict__ gates,
                                                 const float* __restrict__ ret,
                                                 const float* __restrict__ g,
                                                 u16* __restrict__ out) {
  const int row = blockIdx.x;
  const int b = row >> 11;   // T=2048
  const float g2 = gates[row * 2 + 1];
  const float* rr_ = ret + b * C_;
  float* xr = x + (size_t)row * C_;
  float vloc[4];
#pragma unroll
  for (int i = 0; i < 4; i++) {
    const int c = threadIdx.x + i * 256;
    const float v = xr[c] + g2 * rr_[c];
    vloc[i] = v;
    xr[c] = v;
  }
  rms_tail(vloc, g, out + (size_t)row * C_);
}

// ---------------- batched transpose+convert: two f32 (K,N) -> bf16 (N,K) ----------
__global__ void k_tr2(const float* __restrict__ s0, u16* __restrict__ d0,
                      int K0, int N0, int t0,
                      const float* __restrict__ s1, u16* __restrict__ d1,
                      int K1, int N1) {
  __shared__ float tile[32][33];
  int t = blockIdx.x;
  const float* src; u16* dst; int K, N;
  if (t < t0) { src = s0; dst = d0; K = K0; N = N0; }
  else { t -= t0; src = s1; dst = d1; K = K1; N = N1; }
  const int ntx = N >> 5;
  const int tx = t % ntx, ty = t / ntx;
  const int x = tx * 32 + threadIdx.x;
  const int y0 = ty * 32 + threadIdx.y;
#pragma unroll
  for (int i = 0; i < 32; i += 8) tile[threadIdx.y + i][threadIdx.x] = src[(size_t)(y0 + i) * N + x];
  __syncthreads();
  const int x2 = ty * 32 + threadIdx.x;
  const int y2 = tx * 32 + threadIdx.y;
#pragma unroll
  for (int i = 0; i < 32; i += 8) dst[(size_t)(y2 + i) * K + x2] = f2bf(tile[threadIdx.x][threadIdx.y + i]);
}

__global__ void k_tr1(const float* __restrict__ in, u16* __restrict__ out, int K, int N) {
  __shared__ float tile[32][33];
  const int ntx = N >> 5;
  const int tx = blockIdx.x % ntx, ty = blockIdx.x / ntx;
  const int x = tx * 32 + threadIdx.x;
  const int y0 = ty * 32 + threadIdx.y;
#pragma unroll
  for (int i = 0; i < 32; i += 8) tile[threadIdx.y + i][threadIdx.x] = in[(size_t)(y0 + i) * N + x];
  __syncthreads();
  const int x2 = ty * 32 + threadIdx.x;
  const int y2 = tx * 32 + threadIdx.y;
#pragma unroll
  for (int i = 0; i < 32; i += 8) out[(size_t)(y2 + i) * K + x2] = f2bf(tile[threadIdx.x][threadIdx.y + i]);
}

// ---------------- V transpose ----------------
__global__ void k_vt(const u16* __restrict__ qkv, u16* __restrict__ Vt) {
  __shared__ u16 tile[32][34];
  const int jt = blockIdx.x;
  const int dt = blockIdx.y;
  const int bh = blockIdx.z;
  const int b = bh >> 4;
  const int h = bh & 15;
  const int tx = threadIdx.x, ty = threadIdx.y;
#pragma unroll
  for (int i = 0; i < 32; i += 8) {
    const int j = jt * 32 + ty + i;
    const int d = dt * 32 + tx;
    tile[ty + i][tx] = qkv[(size_t)(b * T_ + j) * (3 * C_) + 2 * C_ + h * D_ + d];
  }
  __syncthreads();
#pragma unroll
  for (int i = 0; i < 32; i += 8) {
    const int d = dt * 32 + ty + i;
    const int j = jt * 32 + tx;
    Vt[(size_t)(bh * D_ + d) * T_ + j] = tile[tx][ty + i];
  }
}

// ================== 8-phase 256-wide-tile GEMM machinery ==================
#define VMW(n) asm volatile("s_waitcnt vmcnt(" #n ")" ::: "memory")
#define LGKM0 asm volatile("s_waitcnt lgkmcnt(0)" ::: "memory")
#define GBAR() __builtin_amdgcn_s_barrier()
#define PRIO1() __builtin_amdgcn_s_setprio(1)
#define PRIO0() __builtin_amdgcn_s_setprio(0)

// Stage one 128-row x 64-col bf16 half-tile: 2 x global_load_lds_dwordx4.
#define STG8(gsrc, grow0, dstbyte, kk)                                                    \
  do {                                                                                    \
    const u16* g0_ = (gsrc) + (size_t)((grow0) + wid * 8 + srow) * K + (kk) + scol;       \
    __builtin_amdgcn_global_load_lds(                                                     \
        (const __attribute__((address_space(1))) void*)g0_,                               \
        (__attribute__((address_space(3))) void*)(lc + (dstbyte) + wid * 8 * 128),        \
        16, 0, 0);                                                                        \
    const u16* g1_ = g0_ + (size_t)64 * K;                                                \
    __builtin_amdgcn_global_load_lds(                                                     \
        (const __attribute__((address_space(1))) void*)g1_,                               \
        (__attribute__((address_space(3))) void*)(lc + (dstbyte) + (64 + wid * 8) * 128), \
        16, 0, 0);                                                                        \
  } while (0)

#define RDA4(dst, bufbyte, ig0)                                                           \
  { _Pragma("unroll") for (int i_ = 0; i_ < 4; ++i_) {                                    \
      _Pragma("unroll") for (int s_ = 0; s_ < 2; ++s_)                                    \
        dst[i_][s_] = *(const short8*)(lc + (bufbyte) +                                   \
            (wm * 128 + ((ig0) + i_) * 16 + m16) * 128 + (((s_ * 4 + quad) ^ csw) * 16)); } }

#define RDB4(dst, bufbyte, jg0)                                                           \
  { _Pragma("unroll") for (int j_ = 0; j_ < 2; ++j_) {                                    \
      _Pragma("unroll") for (int s_ = 0; s_ < 2; ++s_)                                    \
        dst[j_][s_] = *(const short8*)(lc + (bufbyte) +                                   \
            (wn * 64 + ((jg0) + j_) * 16 + m16) * 128 + (((s_ * 4 + quad) ^ csw) * 16)); } }

#define RDBS(dst, bufbyte)                                                                \
  { _Pragma("unroll") for (int j_ = 0; j_ < 2; ++j_) {                                    \
      _Pragma("unroll") for (int s_ = 0; s_ < 2; ++s_)                                    \
        dst[j_][s_] = *(const short8*)(lc + (bufbyte) +                                   \
            (wn * 32 + j_ * 16 + m16) * 128 + (((s_ * 4 + quad) ^ csw) * 16)); } }

#define MM16(ig0, jg0, bv_)                                                               \
  { _Pragma("unroll") for (int i_ = 0; i_ < 4; ++i_) {                                    \
      _Pragma("unroll") for (int j_ = 0; j_ < 2; ++j_) {                                  \
        _Pragma("unroll") for (int s_ = 0; s_ < 2; ++s_)                                  \
          acc[(ig0) + i_][(jg0) + j_] = __builtin_amdgcn_mfma_f32_16x16x32_bf16(          \
              av[i_][s_], bv_[j_][s_], acc[(ig0) + i_][(jg0) + j_], 0, 0, 0); } } }

#define MMS(accv, ig0, bv_)                                                               \
  { _Pragma("unroll") for (int i_ = 0; i_ < 4; ++i_) {                                    \
      _Pragma("unroll") for (int j_ = 0; j_ < 2; ++j_) {                                  \
        _Pragma("unroll") for (int s_ = 0; s_ < 2; ++s_)                                  \
          accv[(ig0) + i_][j_] = __builtin_amdgcn_mfma_f32_16x16x32_bf16(                 \
              av[i_][s_], bv_[j_][s_], accv[(ig0) + i_][j_], 0, 0, 0); } } }

// 16-MFMA cluster using av8[ig0..ig0+3]
#define MMN(ig0, bv_)                                                                     \
  { _Pragma("unroll") for (int i_ = 0; i_ < 4; ++i_) {                                    \
      _Pragma("unroll") for (int j_ = 0; j_ < 2; ++j_) {                                  \
        _Pragma("unroll") for (int s_ = 0; s_ < 2; ++s_)                                  \
          acc[(ig0) + i_][j_] = __builtin_amdgcn_mfma_f32_16x16x32_bf16(                  \
              av8[(ig0) + i_][s_], bv_[j_][s_], acc[(ig0) + i_][j_], 0, 0, 0); } } }

// ---------------- plain 256x256 GEMM (EPI=0 only: Cc = bf16(v)) ----------
template <int EPI>
__global__ __launch_bounds__(512, 2) void k_g256(const u16* __restrict__ A,
                                                 const u16* __restrict__ Bt,
                                                 u16* __restrict__ Cc,
                                                 float* __restrict__ Xf,
                                                 const float* __restrict__ gates,
                                                 int N, int K) {
  extern __shared__ __align__(16) u16 lds[];
  char* const lc = (char*)lds;
  enum { A0B = 0, B0B = 32768, A1B = 65536, B1B = 98304 };
  const int tid = threadIdx.x;
  const int wid = tid >> 6, lane = tid & 63;
  const int wm = wid >> 2, wn = wid & 3;
  const int quad = lane >> 4, m16 = lane & 15;
  const int srow = lane >> 3, sc = lane & 7;
  const int scol = ((sc ^ srow) & 7) * 8;
  const int csw = m16 & 7;
  const int m0 = blockIdx.x * 256, n0 = blockIdx.y * 256;
  const int Kslice = K / gridDim.z;
  const int kbeg = blockIdx.z * Kslice;
  const int ntile = Kslice >> 6;
  const int nit = ntile >> 1;

  float4v acc[8][4];
#pragma unroll
  for (int i = 0; i < 8; i++)
#pragma unroll
    for (int j = 0; j < 4; j++) acc[i][j] = (float4v){0.f, 0.f, 0.f, 0.f};
  short8 av[4][2], b01[2][2], b23[2][2];

  STG8(Bt, n0, B0B, kbeg);
  STG8(Bt, n0 + 128, B0B + 16384, kbeg);
  STG8(A, m0, A0B, kbeg);
  STG8(A, m0 + 128, A0B + 16384, kbeg);
  STG8(Bt, n0, B1B, kbeg + 64);
  STG8(Bt, n0 + 128, B1B + 16384, kbeg + 64);
  VMW(4);
  GBAR();

#pragma unroll 1
  for (int it = 0; it < nit; ++it) {
    const int t2 = 2 * it + 2, t3 = 2 * it + 3;
    const int k1 = kbeg + (2 * it + 1) * 64;
    const int k2 = kbeg + (t2 < ntile ? t2 : t2 - ntile) * 64;
    const int k3 = kbeg + (t3 < ntile ? t3 : t3 - ntile) * 64;
    RDA4(av, A0B, 0);
    RDB4(b01, B0B, 0);
    STG8(A, m0, A1B, k1);
    GBAR(); LGKM0;
    PRIO1(); MM16(0, 0, b01); PRIO0();
    GBAR();
    RDB4(b23, B0B, 2);
    STG8(A, m0 + 128, A1B + 16384, k1);
    GBAR(); LGKM0;
    PRIO1(); MM16(0, 2, b23); PRIO0();
    GBAR();
    RDA4(av, A0B, 4);
    STG8(Bt, n0, B0B, k2);
    GBAR(); LGKM0;
    PRIO1(); MM16(4, 2, b23); PRIO0();
    GBAR();
    STG8(Bt, n0 + 128, B0B + 16384, k2);
    VMW(4);
    GBAR(); LGKM0;
    PRIO1(); MM16(4, 0, b01); PRIO0();
    GBAR();
    RDA4(av, A1B, 0);
    RDB4(b01, B1B, 0);
    STG8(A, m0, A0B, k2);
    GBAR(); LGKM0;
    PRIO1(); MM16(0, 0, b01); PRIO0();
    GBAR();
    RDB4(b23, B1B, 2);
    STG8(A, m0 + 128, A0B + 16384, k2);
    GBAR(); LGKM0;
    PRIO1(); MM16(0, 2, b23); PRIO0();
    GBAR();
    RDA4(av, A1B, 4);
    STG8(Bt, n0, B1B, k3);
    GBAR(); LGKM0;
    PRIO1(); MM16(4, 2, b23); PRIO0();
    GBAR();
    STG8(Bt, n0 + 128, B1B + 16384, k3);
    VMW(4);
    GBAR(); LGKM0;
    PRIO1(); MM16(4, 0, b01); PRIO0();
    GBAR();
  }

#pragma unroll
  for (int i = 0; i < 8; i++) {
    const int row0 = m0 + wm * 128 + i * 16 + quad * 4;
#pragma unroll
    for (int j = 0; j < 4; j++) {
      const int col = n0 + wn * 64 + j * 16 + m16;
#pragma unroll
      for (int r = 0; r < 4; r++) {
        const size_t idx = (size_t)(row0 + r) * N + col;
        const float v = acc[i][j][r];
        if (EPI == 0) Cc[idx] = f2bf(v);
        else if (EPI == 1) unsafeAtomicAdd(&Xf[idx], gates[(row0 + r) * 2] * v);
        else unsafeAtomicAdd(&Xf[idx], v);
      }
    }
  }
}

// ---------------- 256x128 single-B 4-phase GEMM (no atomics) ----------
// EPI=1 (proj, z=1):  Xf[idx] += gates[row*2] * v        (single-writer RMW)
// EPI=2 (down, z=2):  z0: Pf[idx] = v ; z1: Xf[idx] += v (single-writer each)
template <int EPI>
__global__ __launch_bounds__(512, 2) void k_g256n(const u16* __restrict__ A,
                                                  const u16* __restrict__ Bt,
                                                  float* __restrict__ Xf,
                                                  float* __restrict__ Pf,
                                                  const float* __restrict__ gates,
                                                  int N, int K) {
  extern __shared__ __align__(16) u16 lds[];
  char* const lc = (char*)lds;
  // buf0: A[0,32K) B[32K,48K); buf1: A[48K,80K) B[80K,96K)
  enum { SA0 = 0, SB0 = 32768, SA1 = 49152, SB1 = 81920 };
  const int tid = threadIdx.x;
  const int wid = tid >> 6, lane = tid & 63;
  const int wm = wid >> 2, wn = wid & 3;
  const int quad = lane >> 4, m16 = lane & 15;
  const int srow = lane >> 3, sc = lane & 7;
  const int scol = ((sc ^ srow) & 7) * 8;
  const int csw = m16 & 7;
  const int m0 = blockIdx.x * 256, n0 = blockIdx.y * 128;
  const int Kslice = K / gridDim.z;
  const int kbeg = blockIdx.z * Kslice;
  const int ntile = Kslice >> 6;
  const int nit = ntile >> 1;

  float4v acc[8][2];
#pragma unroll
  for (int i = 0; i < 8; i++)
#pragma unroll
    for (int j = 0; j < 2; j++) acc[i][j] = (float4v){0.f, 0.f, 0.f, 0.f};
  short8 av8[8][2], bv[2][2];

  // prologue = steady state: t0 {B,A0,A1}, t1 {B,A0,A1}; retire t0, t1 in flight
  STG8(Bt, n0, SB0, kbeg);
  STG8(A, m0, SA0, kbeg);
  STG8(A, m0 + 128, SA0 + 16384, kbeg);
  STG8(Bt, n0, SB1, kbeg + 64);
  STG8(A, m0, SA1, kbeg + 64);
  STG8(A, m0 + 128, SA1 + 16384, kbeg + 64);
  VMW(6);
  GBAR();

#pragma unroll 1
  for (int it = 0; it < nit; ++it) {
    const int t2 = 2 * it + 2, t3 = 2 * it + 3;
    const int k2 = kbeg + (t2 < ntile ? t2 : t2 - ntile) * 64;  // wraps last iter (dead)
    const int k3 = kbeg + (t3 < ntile ? t3 : t3 - ntile) * 64;
    // P1: read ALL of buf0 (t0); MFMA lo
    RDA4(av8, SA0, 0);
    RDA4((&av8[4]), SA0, 4);
    RDBS(bv, SB0);
    GBAR(); LGKM0;
    PRIO1(); MMN(0, bv); PRIO0();
    GBAR();
    // P2: stage t2 -> buf0 (fully read); VMW(6) retires t1 (needed P3); MFMA hi
    STG8(Bt, n0, SB0, k2);
    STG8(A, m0, SA0, k2);
    STG8(A, m0 + 128, SA0 + 16384, k2);
    VMW(6);
    GBAR(); LGKM0;
    PRIO1(); MMN(4, bv); PRIO0();
    GBAR();
    // P3: read ALL of buf1 (t1); MFMA lo
    RDA4(av8, SA1, 0);
    RDA4((&av8[4]), SA1, 4);
    RDBS(bv, SB1);
    GBAR(); LGKM0;
    PRIO1(); MMN(0, bv); PRIO0();
    GBAR();
    // P4: stage t3 -> buf1; VMW(6) retires t2 (needed next P1); MFMA hi
    STG8(Bt, n0, SB1, k3);
    STG8(A, m0, SA1, k3);
    STG8(A, m0 + 128, SA1 + 16384, k3);
    VMW(6);
    GBAR(); LGKM0;
    PRIO1(); MMN(4, bv); PRIO0();
    GBAR();
  }

#pragma unroll
  for (int i = 0; i < 8; i++) {
    const int row0 = m0 + wm * 128 + i * 16 + quad * 4;
#pragma unroll
    for (int j = 0; j < 2; j++) {
      const int col = n0 + wn * 32 + j * 16 + m16;
#pragma unroll
      for (int r = 0; r < 4; r++) {
        const size_t idx = (size_t)(row0 + r) * N + col;
        const float v = acc[i][j][r];
        if (EPI == 1) {
          Xf[idx] += gates[(row0 + r) * 2] * v;
        } else {
          if (blockIdx.z == 0) Pf[idx] = v;
          else Xf[idx] += v;
        }
      }
    }
  }
}

// ---------------- fused SwiGLU dual-GEMM, 256x128 tile, 8-phase ----------
__global__ __launch_bounds__(512, 2) void k_g256s(const u16* __restrict__ A,
                                                  const u16* __restrict__ Btg,
                                                  const u16* __restrict__ Btu,
                                                  u16* __restrict__ Cc,
                                                  int N, int K) {
  extern __shared__ __align__(16) u16 lds[];
  char* const lc = (char*)lds;
  enum { SA0 = 0, SG0 = 32768, SU0 = 49152, SA1 = 65536, SG1 = 98304, SU1 = 114688 };
  const int tid = threadIdx.x;
  const int wid = tid >> 6, lane = tid & 63;
  const int wm = wid >> 2, wn = wid & 3;
  const int quad = lane >> 4, m16 = lane & 15;
  const int srow = lane >> 3, sc = lane & 7;
  const int scol = ((sc ^ srow) & 7) * 8;
  const int csw = m16 & 7;
  const int m0 = blockIdx.x * 256, n0 = blockIdx.y * 128;
  const int kbeg = 0;
  const int ntile = K >> 6;
  const int nit = ntile >> 1;
  const int K2 = K;
  (void)K2;

  float4v accg[8][2], accu[8][2];
#pragma unroll
  for (int i = 0; i < 8; i++)
#pragma unroll
    for (int j = 0; j < 2; j++) {
      accg[i][j] = (float4v){0.f, 0.f, 0.f, 0.f};
      accu[i][j] = (float4v){0.f, 0.f, 0.f, 0.f};
    }
  short8 av[4][2], bg[2][2], bu[2][2];

  STG8(Btg, n0, SG0, kbeg);
  STG8(Btu, n0, SU0, kbeg);
  STG8(A, m0, SA0, kbeg);
  STG8(A, m0 + 128, SA0 + 16384, kbeg);
  STG8(Btg, n0, SG1, kbeg + 64);
  STG8(Btu, n0, SU1, kbeg + 64);
  STG8(A, m0, SA1, kbeg + 64);
  VMW(6);
  GBAR();

#pragma unroll 1
  for (int it = 0; it < nit; ++it) {
    const int t2 = 2 * it + 2, t3 = 2 * it + 3;
    const int k1 = kbeg + (2 * it + 1) * 64;
    const int k2 = kbeg + (t2 < ntile ? t2 : t2 - ntile) * 64;
    const int k3 = kbeg + (t3 < ntile ? t3 : t3 - ntile) * 64;
    RDA4(av, SA0, 0);
    RDBS(bg, SG0);
    STG8(A, m0 + 128, SA1 + 16384, k1);
    GBAR(); LGKM0;
    PRIO1(); MMS(accg, 0, bg); PRIO0();
    GBAR();
    RDBS(bu, SU0);
    STG8(Btg, n0, SG0, k2);
    GBAR(); LGKM0;
    PRIO1(); MMS(accu, 0, bu); PRIO0();
    GBAR();
    RDA4(av, SA0, 4);
    STG8(Btu, n0, SU0, k2);
    GBAR(); LGKM0;
    PRIO1(); MMS(accu, 4, bu); PRIO0();
    GBAR();
    STG8(A, m0, SA0, k2);
    VMW(6);
    GBAR(); LGKM0;
    PRIO1(); MMS(accg, 4, bg); PRIO0();
    GBAR();
    RDA4(av, SA1, 0);
    RDBS(bg, SG1);
    STG8(A, m0 + 128, SA0 + 16384, k2);
    GBAR(); LGKM0;
    PRIO1(); MMS(accg, 0, bg); PRIO0();
    GBAR();
    RDBS(bu, SU1);
    STG8(Btg, n0, SG1, k3);
    GBAR(); LGKM0;
    PRIO1(); MMS(accu, 0, bu); PRIO0();
    GBAR();
    RDA4(av, SA1, 4);
    STG8(Btu, n0, SU1, k3);
    GBAR(); LGKM0;
    PRIO1(); MMS(accu, 4, bu); PRIO0();
    GBAR();
    STG8(A, m0, SA1, k3);
    VMW(6);
    GBAR(); LGKM0;
    PRIO1(); MMS(accg, 4, bg); PRIO0();
    GBAR();
  }

#pragma unroll
  for (int i = 0; i < 8; i++) {
    const int row0 = m0 + wm * 128 + i * 16 + quad * 4;
#pragma unroll
    for (int j = 0; j < 2; j++) {
      const int col = n0 + wn * 32 + j * 16 + m16;
#pragma unroll
      for (int r = 0; r < 4; r++) {
        const float g = accg[i][j][r];
        const float u = accu[i][j][r];
        Cc[(size_t)(row0 + r) * N + col] = f2bf(u * g / (1.f + __expf(-g)));
      }
    }
  }
}

// ---------------- fused attention ----------------
__global__ __launch_bounds__(256) void k_attn(const u16* __restrict__ qkv,
                                              const u16* __restrict__ Vt,
                                              u16* __restrict__ o) {
  __shared__ u16 lds[4][16][290];
  const int wave = threadIdx.x >> 6;
  const int widG = blockIdx.x * 4 + wave;
  const int lane = threadIdx.x & 63;
  const int quad = lane >> 4;
  const int c16 = lane & 15;
  const int qt = (widG & 127) * 16;
  const int h = (widG >> 7) & 15;
  const int b = widG >> 11;
  const size_t rs = 3 * C_;
  const int jt0 = qt - 256;

  const u16* qrow = qkv + (size_t)(b * T_ + qt + c16) * rs + h * D_ + quad * 8;
  const short8 a0 = *(const short8*)(qrow);
  const short8 a1 = *(const short8*)(qrow + 32);
  float4v S[17];
  const short8 z8 = (short8){0, 0, 0, 0, 0, 0, 0, 0};
#pragma unroll
  for (int t = 0; t < 17; t++) {
    if (jt0 + t * 16 + 15 < 0) { S[t] = (float4v){0.f, 0.f, 0.f, 0.f}; continue; }
    const int j = jt0 + t * 16 + c16;
    short8 b0 = z8, b1 = z8;
    if (j >= 0) {
      const u16* krow = qkv + (size_t)(b * T_ + j) * rs + C_ + h * D_ + quad * 8;
      b0 = *(const short8*)(krow);
      b1 = *(const short8*)(krow + 32);
    }
    float4v z = (float4v){0.f, 0.f, 0.f, 0.f};
    z = __builtin_amdgcn_mfma_f32_16x16x32_bf16(a0, b0, z, 0, 0, 0);
    z = __builtin_amdgcn_mfma_f32_16x16x32_bf16(a1, b1, z, 0, 0, 0);
    S[t] = z;
  }
#pragma unroll
  for (int r = 0; r < 4; r++) {
    const int q = qt + quad * 4 + r;
    float mx = -1.0e30f;
#pragma unroll
    for (int t = 0; t < 17; t++) {
      const int j = jt0 + t * 16 + c16;
      const int w = j - q + 255;
      const bool vis = (j >= 0) && (w >= 0) && (w < 256);
      if (vis) {
        const float s = S[t][r] * 0.125f;
        S[t][r] = s;
        mx = fmaxf(mx, s);
      } else {
        S[t][r] = -1.0e30f;
      }
    }
#pragma unroll
    for (int o2 = 1; o2 < 16; o2 <<= 1) mx = fmaxf(mx, __shfl_xor(mx, o2));
    float sum = 0.f;
#pragma unroll
    for (int t = 0; t < 17; t++) {
      const float e = (S[t][r] > -0.9e30f) ? __expf(S[t][r] - mx) : 0.f;
      S[t][r] = e;
      sum += e;
    }
#pragma unroll
    for (int o2 = 1; o2 < 16; o2 <<= 1) sum += __shfl_xor(sum, o2);
    const float inv = 1.f / fmaxf(sum, 1e-30f);
    const int prow = quad * 4 + r;
#pragma unroll
    for (int t = 0; t < 17; t++) lds[wave][prow][t * 16 + c16] = f2bf(S[t][r] * inv);
    lds[wave][prow][272 + c16] = 0;
  }
  __syncthreads();

  float4v acc[4];
#pragma unroll
  for (int md = 0; md < 4; md++) acc[md] = (float4v){0.f, 0.f, 0.f, 0.f};
  const u16* vtb = Vt + (size_t)((b * H_ + h) * D_) * T_;
  const uint* prow32 = (const uint*)(&lds[wave][c16][0]);
  union { short8 s8; uint u[4]; } bf;
#pragma unroll
  for (int c = 0; c < 9; c++) {
    const int jbase = jt0 + c * 32;
    if (jbase + 31 < 0) continue;
#pragma unroll
    for (int w2 = 0; w2 < 4; w2++) bf.u[w2] = prow32[c * 16 + quad * 4 + w2];
    int j0 = jbase + quad * 8;
    j0 = (j0 < 0) ? 0 : ((j0 > T_ - 8) ? (T_ - 8) : j0);
#pragma unroll
    for (int md = 0; md < 4; md++) {
      const short8 af = *(const short8*)(vtb + (size_t)(md * 16 + c16) * T_ + j0);
      acc[md] = __builtin_amdgcn_mfma_f32_16x16x32_bf16(af, bf.s8, acc[md], 0, 0, 0);
    }
  }
#pragma unroll
  for (int md = 0; md < 4; md++) {
    uint u0 = (uint)f2bf(acc[md][0]) | ((uint)f2bf(acc[md][1]) << 16);
    uint u1 = (uint)f2bf(acc[md][2]) | ((uint)f2bf(acc[md][3]) << 16);
    uint2 pk = make_uint2(u0, u1);
    u16* dst = o + (size_t)(b * T_ + qt + c16) * C_ + h * D_ + md * 16 + quad * 4;
    *(uint2*)dst = pk;
  }
}

// ---------------- gate logits + 2-way softmax ----------
__global__ __launch_bounds__(256) void k_gate(const u16* __restrict__ h,
                                              const float* __restrict__ gW,
                                              const float* __restrict__ gb,
                                              float* __restrict__ gates) {
  const int row = blockIdx.x * 4 + (threadIdx.x >> 6);
  const int lane = threadIdx.x & 63;
  const u16* hr = h + (size_t)row * C_;
  float s0 = 0.f, s2 = 0.f;
  for (int k = lane; k < C_; k += 64) {
    const float hv = bf2f(hr[k]);
    s0 += hv * gW[k * 3 + 0];
    s2 += hv * gW[k * 3 + 2];
  }
#pragma unroll
  for (int o = 32; o; o >>= 1) { s0 += __shfl_down(s0, o); s2 += __shfl_down(s2, o); }
  if (lane == 0) {
    const float l0 = s0 + gb[0];
    const float l2 = s2 + gb[2];
    const float m = fmaxf(l0, l2);
    const float e0 = __expf(l0 - m), e2 = __expf(l2 - m);
    const float inv = 1.f / (e0 + e2);
    gates[row * 2 + 0] = e0 * inv;
    gates[row * 2 + 1] = e2 * inv;
  }
}

// ---------------- both layers' retrieval projections ---------------
__global__ void k_ret2(const float* __restrict__ rc, const float* __restrict__ rW,
                       float* __restrict__ ret) {
  const int l = blockIdx.x >> 3;
  const int bid = blockIdx.x & 7;
  const int b = bid >> 2;
  const int col = (bid & 3) * 256 + threadIdx.x;
  const float* rWl = rW + (size_t)l * C_ * C_;
  float s = 0.f;
  for (int k = 0; k < C_; k++) s += rc[b * C_ + k] * rWl[(size_t)k * C_ + col];
  ret[(size_t)l * B_ * C_ + b * C_ + col] = s;
}

// ---------------- launcher ----------------
extern "C" void kernel_launch(void* const* d_in, const int* in_sizes, int n_in,
                              void* d_out, int out_size, void* d_ws, size_t ws_size,
                              hipStream_t stream) {
  (void)in_sizes; (void)n_in; (void)out_size; (void)ws_size;
  const float* xin  = (const float*)d_in[0];
  const float* rc   = (const float*)d_in[1];
  const float* n1g  = (const float*)d_in[2];
  const float* Wqkv = (const float*)d_in[3];
  const float* Wpro = (const float*)d_in[4];
  const float* gW   = (const float*)d_in[5];
  const float* gb   = (const float*)d_in[6];
  const float* rW   = (const float*)d_in[7];
  const float* n2g  = (const float*)d_in[8];
  const float* fgW  = (const float*)d_in[9];
  const float* fuW  = (const float*)d_in[10];
  const float* fdW  = (const float*)d_in[11];

  static bool attr_done = false;
  if (!attr_done) {
    hipFuncSetAttribute((const void*)k_g256<0>, hipFuncAttributeMaxDynamicSharedMemorySize, 131072);
    hipFuncSetAttribute((const void*)k_g256s, hipFuncAttributeMaxDynamicSharedMemorySize, 131072);
    hipFuncSetAttribute((const void*)k_g256n<1>, hipFuncAttributeMaxDynamicSharedMemorySize, 98304);
    hipFuncSetAttribute((const void*)k_g256n<2>, hipFuncAttributeMaxDynamicSharedMemorySize, 98304);
    attr_done = true;
  }

  // ---- workspace layout ----
  char* w = (char*)d_ws;
  float* gates = (float*)(w);                            // 32 KB (per-layer, reused)
  float* retb  = (float*)(w + 32768);                    // 16 KB: [L][B][C]
  float* xf32  = (float*)(w + 65536);                    // 16.78 MB residual (f32)
  u16* hbuf    = (u16*)(w + 65536 + (size_t)NELEM * 4);  // 8.39 MB h | h2 | fd^T
  u16* big     = hbuf + NELEM;                           // 33.55 MB region
  u16* qkv  = big;                          // 25.17 MB (attn phase)
  u16* obuf = big + (size_t)NTOK * 3 * C_;  // 8.39 MB  (attn phase)
  u16* gbuf = big;                          // 33.55 MB (FFN phase)
  u16* wT  = (u16*)d_out;                    // 8.39 MB
  u16* wTp = wT + (size_t)3 * C_ * C_;       // Wproj^T
  u16* Vt  = (u16*)d_out + (size_t)NELEM;    // 8.39 MB upper half
  u16* wT2 = Vt;                             // FFN alias
  float* Pf = (float*)d_out;                 // down-proj z0 partial (16.78 MB, FFN tail)

  k_ret2<<<16, 256, 0, stream>>>(rc, rW, retb);

  for (int l = 0; l < L_; l++) {
    if (l == 0)
      k_rms_first<<<NTOK, 256, 0, stream>>>(xin, n1g, xf32, hbuf);
    else
      k_rms_acc<<<NTOK, 256, 0, stream>>>(xf32, Pf, n1g + l * C_, hbuf);
    k_tr2<<<3072 + 1024, dim3(32, 8), 0, stream>>>(
        Wqkv + (size_t)l * C_ * 3 * C_, wT, C_, 3 * C_, 3072,
        Wpro + (size_t)l * C_ * C_, wTp, C_, C_);
    // qkv = h @ Wqkv  (8-phase 256^2)
    k_g256<0><<<dim3(NTOK / 256, 3 * C_ / 256, 1), 512, 131072, stream>>>(
        hbuf, wT, qkv, nullptr, nullptr, 3 * C_, C_);
    k_gate<<<NTOK / 4, 256, 0, stream>>>(hbuf, gW + (size_t)l * C_ * 3, gb + l * 3, gates);
    k_vt<<<dim3(64, 2, 32), dim3(32, 8), 0, stream>>>(qkv, Vt);
    k_attn<<<1024, 256, 0, stream>>>(qkv, Vt, obuf);
    // x += gate0 * (o @ Wproj)   [z=1, 256x128, single-writer RMW, no atomics]
    k_g256n<1><<<dim3(NTOK / 256, C_ / 128, 1), 512, 98304, stream>>>(
        obuf, wTp, xf32, nullptr, gates, C_, C_);
    k_rms2mix<<<NTOK, 256, 0, stream>>>(xf32, gates, retb + (size_t)l * B_ * C_,
                                        n2g + l * C_, hbuf);
    k_tr2<<<4096 + 4096, dim3(32, 8), 0, stream>>>(
        fgW + (size_t)l * C_ * F_, wT, C_, F_, 4096,
        fuW + (size_t)l * C_ * F_, wT2, C_, F_);
    // gbuf = silu(h2@Wg) * (h2@Wu)  (fused 8-phase 256x128)
    k_g256s<<<dim3(NTOK / 256, F_ / 128, 1), 512, 131072, stream>>>(
        hbuf, wT, wT2, gbuf, F_, C_);
    k_tr1<<<4096, dim3(32, 8), 0, stream>>>(fdW + (size_t)l * F_ * C_, hbuf, F_, C_);
    // down: z=2 hybrid — z0 writes f32 partial Pf (d_out, dead here), z1 RMWs xf32
    k_g256n<2><<<dim3(NTOK / 256, C_ / 128, 2), 512, 98304, stream>>>(
        gbuf, hbuf, xf32, Pf, nullptr, C_, F_);
  }

  // out = xf32 + Pf (Pf aliases d_out; in-place add)
  k_copyf_acc<<<NELEM / 256, 256, 0, stream>>>(xf32, (float*)d_out);
}

// Round 3
// 821.626 us; speedup vs baseline: 1.1121x; 1.0012x over previous
//
#include <hip/hip_runtime.h>

#define L_ 2
#define B_ 2
#define T_ 2048
#define C_ 1024
#define H_ 16
#define D_ 64
#define F_ 4096
#define NTOK 4096      // B*T
#define NELEM 4194304  // B*T*C

typedef unsigned short u16;
typedef __attribute__((ext_vector_type(8))) short short8;
typedef __attribute__((ext_vector_type(4))) float float4v;

__device__ __forceinline__ float bf2f(u16 u) {
  unsigned v = ((unsigned)u) << 16;
  return __builtin_bit_cast(float, v);
}
__device__ __forceinline__ u16 f2bf(float f) {
  unsigned u = __builtin_bit_cast(unsigned, f);
  u += 0x7FFFu + ((u >> 16) & 1u);   // round-to-nearest-even
  return (u16)(u >> 16);
}

// Bijective XCD-chunked block swizzle (m204): XCD k owns a contiguous range of
// flat tile ids, x-fastest within the chunk -> B-panels stay L2-resident.
__device__ __forceinline__ void xcd_swz(int& bx, int& by) {
  const int gx = gridDim.x;
  const int nwg = gx * gridDim.y;
  const int orig = by * gx + bx;
  const int q = nwg >> 3, r = nwg & 7;
  const int xcd = orig & 7, lid = orig >> 3;
  const int wg = (xcd < r ? xcd * (q + 1) : r * (q + 1) + (xcd - r) * q) + lid;
  bx = wg % gx;
  by = wg / gx;
}

// ---------------- elementwise ----------------
__global__ void k_copyf_acc(const float* __restrict__ in, float* __restrict__ out) {
  // out aliases the f32 partial buffer: out = x + partial (in place)
  const int i = blockIdx.x * 256 + threadIdx.x;
  out[i] = in[i] + out[i];
}

// ---------------- RMSNorm variants (block per row) ----------------
__device__ __forceinline__ void rms_tail(float* vloc, const float* __restrict__ g,
                                         u16* __restrict__ orow) {
  float s = vloc[0] * vloc[0] + vloc[1] * vloc[1] + vloc[2] * vloc[2] + vloc[3] * vloc[3];
#pragma unroll
  for (int o = 32; o; o >>= 1) s += __shfl_down(s, o);
  __shared__ float red[4];
  __shared__ float rsv;
  if ((threadIdx.x & 63) == 0) red[threadIdx.x >> 6] = s;
  __syncthreads();
  if (threadIdx.x == 0) {
    float t = red[0] + red[1] + red[2] + red[3];
    rsv = rsqrtf(t * (1.f / C_) + 1e-6f);
  }
  __syncthreads();
  const float rr = rsv;
#pragma unroll
  for (int i = 0; i < 4; i++) {
    const int c = threadIdx.x + i * 256;
    orow[c] = f2bf(vloc[i] * rr * g[c]);
  }
}

__global__ __launch_bounds__(256) void k_rms_first(const float* __restrict__ xin,
                                                   const float* __restrict__ g,
                                                   float* __restrict__ x,
                                                   u16* __restrict__ out) {
  const int row = blockIdx.x;
  const float* sr = xin + (size_t)row * C_;
  float* xr = x + (size_t)row * C_;
  float vloc[4];
#pragma unroll
  for (int i = 0; i < 4; i++) {
    const int c = threadIdx.x + i * 256;
    const float v = sr[c];
    vloc[i] = v;
    xr[c] = v;
  }
  rms_tail(vloc, g, out + (size_t)row * C_);
}

// first norm + fold-in of the down-proj z0 partial: x += pf (write back), rms -> out
__global__ __launch_bounds__(256) void k_rms_acc(float* __restrict__ x,
                                                 const float* __restrict__ pf,
                                                 const float* __restrict__ g,
                                                 u16* __restrict__ out) {
  const int row = blockIdx.x;
  float* xr = x + (size_t)row * C_;
  const float* pr = pf + (size_t)row * C_;
  float vloc[4];
#pragma unroll
  for (int i = 0; i < 4; i++) {
    const int c = threadIdx.x + i * 256;
    const float v = xr[c] + pr[c];
    vloc[i] = v;
    xr[c] = v;
  }
  rms_tail(vloc, g, out + (size_t)row * C_);
}

__global__ __launch_bounds__(256) void k_rms2mix(float* __restrict__ x,
                                                 const float* __restrict__ gates,
                                                 const float* __restrict__ ret,
                                                 const float* __restrict__ g,
                                                 u16* __restrict__ out) {
  const int row = blockIdx.x;
  const int b = row >> 11;   // T=2048
  const float g2 = gates[row * 2 + 1];
  const float* rr_ = ret + b * C_;
  float* xr = x + (size_t)row * C_;
  float vloc[4];
#pragma unroll
  for (int i = 0; i < 4; i++) {
    const int c = threadIdx.x + i * 256;
    const float v = xr[c] + g2 * rr_[c];
    vloc[i] = v;
    xr[c] = v;
  }
  rms_tail(vloc, g, out + (size_t)row * C_);
}

// ---------------- batched transpose+convert: two f32 (K,N) -> bf16 (N,K) ----------
__global__ void k_tr2(const float* __restrict__ s0, u16* __restrict__ d0,
                      int K0, int N0, int t0,
                      const float* __restrict__ s1, u16* __restrict__ d1,
                      int K1, int N1) {
  __shared__ float tile[32][33];
  int t = blockIdx.x;
  const float* src; u16* dst; int K, N;
  if (t < t0) { src = s0; dst = d0; K = K0; N = N0; }
  else { t -= t0; src = s1; dst = d1; K = K1; N = N1; }
  const int ntx = N >> 5;
  const int tx = t % ntx, ty = t / ntx;
  const int x = tx * 32 + threadIdx.x;
  const int y0 = ty * 32 + threadIdx.y;
#pragma unroll
  for (int i = 0; i < 32; i += 8) tile[threadIdx.y + i][threadIdx.x] = src[(size_t)(y0 + i) * N + x];
  __syncthreads();
  const int x2 = ty * 32 + threadIdx.x;
  const int y2 = tx * 32 + threadIdx.y;
#pragma unroll
  for (int i = 0; i < 32; i += 8) dst[(size_t)(y2 + i) * K + x2] = f2bf(tile[threadIdx.x][threadIdx.y + i]);
}

__global__ void k_tr1(const float* __restrict__ in, u16* __restrict__ out, int K, int N) {
  __shared__ float tile[32][33];
  const int ntx = N >> 5;
  const int tx = blockIdx.x % ntx, ty = blockIdx.x / ntx;
  const int x = tx * 32 + threadIdx.x;
  const int y0 = ty * 32 + threadIdx.y;
#pragma unroll
  for (int i = 0; i < 32; i += 8) tile[threadIdx.y + i][threadIdx.x] = in[(size_t)(y0 + i) * N + x];
  __syncthreads();
  const int x2 = ty * 32 + threadIdx.x;
  const int y2 = tx * 32 + threadIdx.y;
#pragma unroll
  for (int i = 0; i < 32; i += 8) out[(size_t)(y2 + i) * K + x2] = f2bf(tile[threadIdx.x][threadIdx.y + i]);
}

// ---------------- V transpose ----------------
__global__ void k_vt(const u16* __restrict__ qkv, u16* __restrict__ Vt) {
  __shared__ u16 tile[32][34];
  const int jt = blockIdx.x;
  const int dt = blockIdx.y;
  const int bh = blockIdx.z;
  const int b = bh >> 4;
  const int h = bh & 15;
  const int tx = threadIdx.x, ty = threadIdx.y;
#pragma unroll
  for (int i = 0; i < 32; i += 8) {
    const int j = jt * 32 + ty + i;
    const int d = dt * 32 + tx;
    tile[ty + i][tx] = qkv[(size_t)(b * T_ + j) * (3 * C_) + 2 * C_ + h * D_ + d];
  }
  __syncthreads();
#pragma unroll
  for (int i = 0; i < 32; i += 8) {
    const int d = dt * 32 + ty + i;
    const int j = jt * 32 + tx;
    Vt[(size_t)(bh * D_ + d) * T_ + j] = tile[tx][ty + i];
  }
}

// ================== 8-phase 256-wide-tile GEMM machinery ==================
#define VMW(n) asm volatile("s_waitcnt vmcnt(" #n ")" ::: "memory")
#define LGKM0 asm volatile("s_waitcnt lgkmcnt(0)" ::: "memory")
#define GBAR() __builtin_amdgcn_s_barrier()
#define PRIO1() __builtin_amdgcn_s_setprio(1)
#define PRIO0() __builtin_amdgcn_s_setprio(0)

// Stage one 128-row x 64-col bf16 half-tile: 2 x global_load_lds_dwordx4.
#define STG8(gsrc, grow0, dstbyte, kk)                                                    \
  do {                                                                                    \
    const u16* g0_ = (gsrc) + (size_t)((grow0) + wid * 8 + srow) * K + (kk) + scol;       \
    __builtin_amdgcn_global_load_lds(                                                     \
        (const __attribute__((address_space(1))) void*)g0_,                               \
        (__attribute__((address_space(3))) void*)(lc + (dstbyte) + wid * 8 * 128),        \
        16, 0, 0);                                                                        \
    const u16* g1_ = g0_ + (size_t)64 * K;                                                \
    __builtin_amdgcn_global_load_lds(                                                     \
        (const __attribute__((address_space(1))) void*)g1_,                               \
        (__attribute__((address_space(3))) void*)(lc + (dstbyte) + (64 + wid * 8) * 128), \
        16, 0, 0);                                                                        \
  } while (0)

#define RDA4(dst, bufbyte, ig0)                                                           \
  { _Pragma("unroll") for (int i_ = 0; i_ < 4; ++i_) {                                    \
      _Pragma("unroll") for (int s_ = 0; s_ < 2; ++s_)                                    \
        dst[i_][s_] = *(const short8*)(lc + (bufbyte) +                                   \
            (wm * 128 + ((ig0) + i_) * 16 + m16) * 128 + (((s_ * 4 + quad) ^ csw) * 16)); } }

#define RDB4(dst, bufbyte, jg0)                                                           \
  { _Pragma("unroll") for (int j_ = 0; j_ < 2; ++j_) {                                    \
      _Pragma("unroll") for (int s_ = 0; s_ < 2; ++s_)                                    \
        dst[j_][s_] = *(const short8*)(lc + (bufbyte) +                                   \
            (wn * 64 + ((jg0) + j_) * 16 + m16) * 128 + (((s_ * 4 + quad) ^ csw) * 16)); } }

#define RDBS(dst, bufbyte)                                                                \
  { _Pragma("unroll") for (int j_ = 0; j_ < 2; ++j_) {                                    \
      _Pragma("unroll") for (int s_ = 0; s_ < 2; ++s_)                                    \
        dst[j_][s_] = *(const short8*)(lc + (bufbyte) +                                   \
            (wn * 32 + j_ * 16 + m16) * 128 + (((s_ * 4 + quad) ^ csw) * 16)); } }

#define MM16(ig0, jg0, bv_)                                                               \
  { _Pragma("unroll") for (int i_ = 0; i_ < 4; ++i_) {                                    \
      _Pragma("unroll") for (int j_ = 0; j_ < 2; ++j_) {                                  \
        _Pragma("unroll") for (int s_ = 0; s_ < 2; ++s_)                                  \
          acc[(ig0) + i_][(jg0) + j_] = __builtin_amdgcn_mfma_f32_16x16x32_bf16(          \
              av[i_][s_], bv_[j_][s_], acc[(ig0) + i_][(jg0) + j_], 0, 0, 0); } } }

#define MMS(accv, ig0, bv_)                                                               \
  { _Pragma("unroll") for (int i_ = 0; i_ < 4; ++i_) {                                    \
      _Pragma("unroll") for (int j_ = 0; j_ < 2; ++j_) {                                  \
        _Pragma("unroll") for (int s_ = 0; s_ < 2; ++s_)                                  \
          accv[(ig0) + i_][j_] = __builtin_amdgcn_mfma_f32_16x16x32_bf16(                 \
              av[i_][s_], bv_[j_][s_], accv[(ig0) + i_][j_], 0, 0, 0); } } }

// 16-MFMA cluster using av8[ig0..ig0+3]
#define MMN(ig0, bv_)                                                                     \
  { _Pragma("unroll") for (int i_ = 0; i_ < 4; ++i_) {                                    \
      _Pragma("unroll") for (int j_ = 0; j_ < 2; ++j_) {                                  \
        _Pragma("unroll") for (int s_ = 0; s_ < 2; ++s_)                                  \
          acc[(ig0) + i_][j_] = __builtin_amdgcn_mfma_f32_16x16x32_bf16(                  \
              av8[(ig0) + i_][s_], bv_[j_][s_], acc[(ig0) + i_][j_], 0, 0, 0); } } }

// ---------------- plain 256x256 GEMM (EPI=0 only: Cc = bf16(v)) ----------
template <int EPI>
__global__ __launch_bounds__(512, 2) void k_g256(const u16* __restrict__ A,
                                                 const u16* __restrict__ Bt,
                                                 u16* __restrict__ Cc,
                                                 float* __restrict__ Xf,
                                                 const float* __restrict__ gates,
                                                 int N, int K) {
  extern __shared__ __align__(16) u16 lds[];
  char* const lc = (char*)lds;
  enum { A0B = 0, B0B = 32768, A1B = 65536, B1B = 98304 };
  const int tid = threadIdx.x;
  const int wid = tid >> 6, lane = tid & 63;
  const int wm = wid >> 2, wn = wid & 3;
  const int quad = lane >> 4, m16 = lane & 15;
  const int srow = lane >> 3, sc = lane & 7;
  const int scol = ((sc ^ srow) & 7) * 8;
  const int csw = m16 & 7;
  int bx = blockIdx.x, by = blockIdx.y;
  xcd_swz(bx, by);
  const int m0 = bx * 256, n0 = by * 256;
  const int Kslice = K / gridDim.z;
  const int kbeg = blockIdx.z * Kslice;
  const int ntile = Kslice >> 6;
  const int nit = ntile >> 1;

  float4v acc[8][4];
#pragma unroll
  for (int i = 0; i < 8; i++)
#pragma unroll
    for (int j = 0; j < 4; j++) acc[i][j] = (float4v){0.f, 0.f, 0.f, 0.f};
  short8 av[4][2], b01[2][2], b23[2][2];

  STG8(Bt, n0, B0B, kbeg);
  STG8(Bt, n0 + 128, B0B + 16384, kbeg);
  STG8(A, m0, A0B, kbeg);
  STG8(A, m0 + 128, A0B + 16384, kbeg);
  STG8(Bt, n0, B1B, kbeg + 64);
  STG8(Bt, n0 + 128, B1B + 16384, kbeg + 64);
  VMW(4);
  GBAR();

#pragma unroll 1
  for (int it = 0; it < nit; ++it) {
    const int t2 = 2 * it + 2, t3 = 2 * it + 3;
    const int k1 = kbeg + (2 * it + 1) * 64;
    const int k2 = kbeg + (t2 < ntile ? t2 : t2 - ntile) * 64;
    const int k3 = kbeg + (t3 < ntile ? t3 : t3 - ntile) * 64;
    RDA4(av, A0B, 0);
    RDB4(b01, B0B, 0);
    STG8(A, m0, A1B, k1);
    GBAR(); LGKM0;
    PRIO1(); MM16(0, 0, b01); PRIO0();
    GBAR();
    RDB4(b23, B0B, 2);
    STG8(A, m0 + 128, A1B + 16384, k1);
    GBAR(); LGKM0;
    PRIO1(); MM16(0, 2, b23); PRIO0();
    GBAR();
    RDA4(av, A0B, 4);
    STG8(Bt, n0, B0B, k2);
    GBAR(); LGKM0;
    PRIO1(); MM16(4, 2, b23); PRIO0();
    GBAR();
    STG8(Bt, n0 + 128, B0B + 16384, k2);
    VMW(4);
    GBAR(); LGKM0;
    PRIO1(); MM16(4, 0, b01); PRIO0();
    GBAR();
    RDA4(av, A1B, 0);
    RDB4(b01, B1B, 0);
    STG8(A, m0, A0B, k2);
    GBAR(); LGKM0;
    PRIO1(); MM16(0, 0, b01); PRIO0();
    GBAR();
    RDB4(b23, B1B, 2);
    STG8(A, m0 + 128, A0B + 16384, k2);
    GBAR(); LGKM0;
    PRIO1(); MM16(0, 2, b23); PRIO0();
    GBAR();
    RDA4(av, A1B, 4);
    STG8(Bt, n0, B1B, k3);
    GBAR(); LGKM0;
    PRIO1(); MM16(4, 2, b23); PRIO0();
    GBAR();
    STG8(Bt, n0 + 128, B1B + 16384, k3);
    VMW(4);
    GBAR(); LGKM0;
    PRIO1(); MM16(4, 0, b01); PRIO0();
    GBAR();
  }

#pragma unroll
  for (int i = 0; i < 8; i++) {
    const int row0 = m0 + wm * 128 + i * 16 + quad * 4;
#pragma unroll
    for (int j = 0; j < 4; j++) {
      const int col = n0 + wn * 64 + j * 16 + m16;
#pragma unroll
      for (int r = 0; r < 4; r++) {
        const size_t idx = (size_t)(row0 + r) * N + col;
        const float v = acc[i][j][r];
        if (EPI == 0) Cc[idx] = f2bf(v);
        else if (EPI == 1) unsafeAtomicAdd(&Xf[idx], gates[(row0 + r) * 2] * v);
        else unsafeAtomicAdd(&Xf[idx], v);
      }
    }
  }
}

// ---------------- 256x128 single-B 4-phase GEMM (no atomics) ----------
// EPI=1 (proj, z=1):  Xf[idx] += gates[row*2] * v        (single-writer RMW)
// EPI=2 (down, z=2):  z0: Pf[idx] = v ; z1: Xf[idx] += v (single-writer each)
template <int EPI>
__global__ __launch_bounds__(512, 2) void k_g256n(const u16* __restrict__ A,
                                                  const u16* __restrict__ Bt,
                                                  float* __restrict__ Xf,
                                                  float* __restrict__ Pf,
                                                  const float* __restrict__ gates,
                                                  int N, int K) {
  extern __shared__ __align__(16) u16 lds[];
  char* const lc = (char*)lds;
  // buf0: A[0,32K) B[32K,48K); buf1: A[48K,80K) B[80K,96K)
  enum { SA0 = 0, SB0 = 32768, SA1 = 49152, SB1 = 81920 };
  const int tid = threadIdx.x;
  const int wid = tid >> 6, lane = tid & 63;
  const int wm = wid >> 2, wn = wid & 3;
  const int quad = lane >> 4, m16 = lane & 15;
  const int srow = lane >> 3, sc = lane & 7;
  const int scol = ((sc ^ srow) & 7) * 8;
  const int csw = m16 & 7;
  int bx = blockIdx.x, by = blockIdx.y;
  xcd_swz(bx, by);
  const int m0 = bx * 256, n0 = by * 128;
  const int Kslice = K / gridDim.z;
  const int kbeg = blockIdx.z * Kslice;
  const int ntile = Kslice >> 6;
  const int nit = ntile >> 1;

  float4v acc[8][2];
#pragma unroll
  for (int i = 0; i < 8; i++)
#pragma unroll
    for (int j = 0; j < 2; j++) acc[i][j] = (float4v){0.f, 0.f, 0.f, 0.f};
  short8 av8[8][2], bv[2][2];

  // prologue = steady state: t0 {B,A0,A1}, t1 {B,A0,A1}; retire t0, t1 in flight
  STG8(Bt, n0, SB0, kbeg);
  STG8(A, m0, SA0, kbeg);
  STG8(A, m0 + 128, SA0 + 16384, kbeg);
  STG8(Bt, n0, SB1, kbeg + 64);
  STG8(A, m0, SA1, kbeg + 64);
  STG8(A, m0 + 128, SA1 + 16384, kbeg + 64);
  VMW(6);
  GBAR();

#pragma unroll 1
  for (int it = 0; it < nit; ++it) {
    const int t2 = 2 * it + 2, t3 = 2 * it + 3;
    const int k2 = kbeg + (t2 < ntile ? t2 : t2 - ntile) * 64;  // wraps last iter (dead)
    const int k3 = kbeg + (t3 < ntile ? t3 : t3 - ntile) * 64;
    // P1: read ALL of buf0 (t0); MFMA lo
    RDA4(av8, SA0, 0);
    RDA4((&av8[4]), SA0, 4);
    RDBS(bv, SB0);
    GBAR(); LGKM0;
    PRIO1(); MMN(0, bv); PRIO0();
    GBAR();
    // P2: stage t2 -> buf0 (fully read); VMW(6) retires t1 (needed P3); MFMA hi
    STG8(Bt, n0, SB0, k2);
    STG8(A, m0, SA0, k2);
    STG8(A, m0 + 128, SA0 + 16384, k2);
    VMW(6);
    GBAR(); LGKM0;
    PRIO1(); MMN(4, bv); PRIO0();
    GBAR();
    // P3: read ALL of buf1 (t1); MFMA lo
    RDA4(av8, SA1, 0);
    RDA4((&av8[4]), SA1, 4);
    RDBS(bv, SB1);
    GBAR(); LGKM0;
    PRIO1(); MMN(0, bv); PRIO0();
    GBAR();
    // P4: stage t3 -> buf1; VMW(6) retires t2 (needed next P1); MFMA hi
    STG8(Bt, n0, SB1, k3);
    STG8(A, m0, SA1, k3);
    STG8(A, m0 + 128, SA1 + 16384, k3);
    VMW(6);
    GBAR(); LGKM0;
    PRIO1(); MMN(4, bv); PRIO0();
    GBAR();
  }

#pragma unroll
  for (int i = 0; i < 8; i++) {
    const int row0 = m0 + wm * 128 + i * 16 + quad * 4;
#pragma unroll
    for (int j = 0; j < 2; j++) {
      const int col = n0 + wn * 32 + j * 16 + m16;
#pragma unroll
      for (int r = 0; r < 4; r++) {
        const size_t idx = (size_t)(row0 + r) * N + col;
        const float v = acc[i][j][r];
        if (EPI == 1) {
          Xf[idx] += gates[(row0 + r) * 2] * v;
        } else {
          if (blockIdx.z == 0) Pf[idx] = v;
          else Xf[idx] += v;
        }
      }
    }
  }
}

// ---------------- fused SwiGLU dual-GEMM, 256x128 tile, 8-phase ----------
__global__ __launch_bounds__(512, 2) void k_g256s(const u16* __restrict__ A,
                                                  const u16* __restrict__ Btg,
                                                  const u16* __restrict__ Btu,
                                                  u16* __restrict__ Cc,
                                                  int N, int K) {
  extern __shared__ __align__(16) u16 lds[];
  char* const lc = (char*)lds;
  enum { SA0 = 0, SG0 = 32768, SU0 = 49152, SA1 = 65536, SG1 = 98304, SU1 = 114688 };
  const int tid = threadIdx.x;
  const int wid = tid >> 6, lane = tid & 63;
  const int wm = wid >> 2, wn = wid & 3;
  const int quad = lane >> 4, m16 = lane & 15;
  const int srow = lane >> 3, sc = lane & 7;
  const int scol = ((sc ^ srow) & 7) * 8;
  const int csw = m16 & 7;
  int bx = blockIdx.x, by = blockIdx.y;
  xcd_swz(bx, by);
  const int m0 = bx * 256, n0 = by * 128;
  const int kbeg = 0;
  const int ntile = K >> 6;
  const int nit = ntile >> 1;

  float4v accg[8][2], accu[8][2];
#pragma unroll
  for (int i = 0; i < 8; i++)
#pragma unroll
    for (int j = 0; j < 2; j++) {
      accg[i][j] = (float4v){0.f, 0.f, 0.f, 0.f};
      accu[i][j] = (float4v){0.f, 0.f, 0.f, 0.f};
    }
  short8 av[4][2], bg[2][2], bu[2][2];

  STG8(Btg, n0, SG0, kbeg);
  STG8(Btu, n0, SU0, kbeg);
  STG8(A, m0, SA0, kbeg);
  STG8(A, m0 + 128, SA0 + 16384, kbeg);
  STG8(Btg, n0, SG1, kbeg + 64);
  STG8(Btu, n0, SU1, kbeg + 64);
  STG8(A, m0, SA1, kbeg + 64);
  VMW(6);
  GBAR();

#pragma unroll 1
  for (int it = 0; it < nit; ++it) {
    const int t2 = 2 * it + 2, t3 = 2 * it + 3;
    const int k1 = kbeg + (2 * it + 1) * 64;
    const int k2 = kbeg + (t2 < ntile ? t2 : t2 - ntile) * 64;
    const int k3 = kbeg + (t3 < ntile ? t3 : t3 - ntile) * 64;
    RDA4(av, SA0, 0);
    RDBS(bg, SG0);
    STG8(A, m0 + 128, SA1 + 16384, k1);
    GBAR(); LGKM0;
    PRIO1(); MMS(accg, 0, bg); PRIO0();
    GBAR();
    RDBS(bu, SU0);
    STG8(Btg, n0, SG0, k2);
    GBAR(); LGKM0;
    PRIO1(); MMS(accu, 0, bu); PRIO0();
    GBAR();
    RDA4(av, SA0, 4);
    STG8(Btu, n0, SU0, k2);
    GBAR(); LGKM0;
    PRIO1(); MMS(accu, 4, bu); PRIO0();
    GBAR();
    STG8(A, m0, SA0, k2);
    VMW(6);
    GBAR(); LGKM0;
    PRIO1(); MMS(accg, 4, bg); PRIO0();
    GBAR();
    RDA4(av, SA1, 0);
    RDBS(bg, SG1);
    STG8(A, m0 + 128, SA0 + 16384, k2);
    GBAR(); LGKM0;
    PRIO1(); MMS(accg, 0, bg); PRIO0();
    GBAR();
    RDBS(bu, SU1);
    STG8(Btg, n0, SG1, k3);
    GBAR(); LGKM0;
    PRIO1(); MMS(accu, 0, bu); PRIO0();
    GBAR();
    RDA4(av, SA1, 4);
    STG8(Btu, n0, SU1, k3);
    GBAR(); LGKM0;
    PRIO1(); MMS(accu, 4, bu); PRIO0();
    GBAR();
    STG8(A, m0, SA1, k3);
    VMW(6);
    GBAR(); LGKM0;
    PRIO1(); MMS(accg, 4, bg); PRIO0();
    GBAR();
  }

#pragma unroll
  for (int i = 0; i < 8; i++) {
    const int row0 = m0 + wm * 128 + i * 16 + quad * 4;
#pragma unroll
    for (int j = 0; j < 2; j++) {
      const int col = n0 + wn * 32 + j * 16 + m16;
#pragma unroll
      for (int r = 0; r < 4; r++) {
        const float g = accg[i][j][r];
        const float u = accu[i][j][r];
        Cc[(size_t)(row0 + r) * N + col] = f2bf(u * g / (1.f + __expf(-g)));
      }
    }
  }
}

// ---------------- fused attention ----------------
__global__ __launch_bounds__(256) void k_attn(const u16* __restrict__ qkv,
                                              const u16* __restrict__ Vt,
                                              u16* __restrict__ o) {
  __shared__ u16 lds[4][16][290];
  const int wave = threadIdx.x >> 6;
  const int widG = blockIdx.x * 4 + wave;
  const int lane = threadIdx.x & 63;
  const int quad = lane >> 4;
  const int c16 = lane & 15;
  const int qt = (widG & 127) * 16;
  const int h = (widG >> 7) & 15;
  const int b = widG >> 11;
  const size_t rs = 3 * C_;
  const int jt0 = qt - 256;

  const u16* qrow = qkv + (size_t)(b * T_ + qt + c16) * rs + h * D_ + quad * 8;
  const short8 a0 = *(const short8*)(qrow);
  const short8 a1 = *(const short8*)(qrow + 32);
  float4v S[17];
  const short8 z8 = (short8){0, 0, 0, 0, 0, 0, 0, 0};
#pragma unroll
  for (int t = 0; t < 17; t++) {
    if (jt0 + t * 16 + 15 < 0) { S[t] = (float4v){0.f, 0.f, 0.f, 0.f}; continue; }
    const int j = jt0 + t * 16 + c16;
    short8 b0 = z8, b1 = z8;
    if (j >= 0) {
      const u16* krow = qkv + (size_t)(b * T_ + j) * rs + C_ + h * D_ + quad * 8;
      b0 = *(const short8*)(krow);
      b1 = *(const short8*)(krow + 32);
    }
    float4v z = (float4v){0.f, 0.f, 0.f, 0.f};
    z = __builtin_amdgcn_mfma_f32_16x16x32_bf16(a0, b0, z, 0, 0, 0);
    z = __builtin_amdgcn_mfma_f32_16x16x32_bf16(a1, b1, z, 0, 0, 0);
    S[t] = z;
  }
#pragma unroll
  for (int r = 0; r < 4; r++) {
    const int q = qt + quad * 4 + r;
    float mx = -1.0e30f;
#pragma unroll
    for (int t = 0; t < 17; t++) {
      const int j = jt0 + t * 16 + c16;
      const int w = j - q + 255;
      const bool vis = (j >= 0) && (w >= 0) && (w < 256);
      if (vis) {
        const float s = S[t][r] * 0.125f;
        S[t][r] = s;
        mx = fmaxf(mx, s);
      } else {
        S[t][r] = -1.0e30f;
      }
    }
#pragma unroll
    for (int o2 = 1; o2 < 16; o2 <<= 1) mx = fmaxf(mx, __shfl_xor(mx, o2));
    float sum = 0.f;
#pragma unroll
    for (int t = 0; t < 17; t++) {
      const float e = (S[t][r] > -0.9e30f) ? __expf(S[t][r] - mx) : 0.f;
      S[t][r] = e;
      sum += e;
    }
#pragma unroll
    for (int o2 = 1; o2 < 16; o2 <<= 1) sum += __shfl_xor(sum, o2);
    const float inv = 1.f / fmaxf(sum, 1e-30f);
    const int prow = quad * 4 + r;
#pragma unroll
    for (int t = 0; t < 17; t++) lds[wave][prow][t * 16 + c16] = f2bf(S[t][r] * inv);
    lds[wave][prow][272 + c16] = 0;
  }
  __syncthreads();

  float4v acc[4];
#pragma unroll
  for (int md = 0; md < 4; md++) acc[md] = (float4v){0.f, 0.f, 0.f, 0.f};
  const u16* vtb = Vt + (size_t)((b * H_ + h) * D_) * T_;
  const uint* prow32 = (const uint*)(&lds[wave][c16][0]);
  union { short8 s8; uint u[4]; } bf;
#pragma unroll
  for (int c = 0; c < 9; c++) {
    const int jbase = jt0 + c * 32;
    if (jbase + 31 < 0) continue;
#pragma unroll
    for (int w2 = 0; w2 < 4; w2++) bf.u[w2] = prow32[c * 16 + quad * 4 + w2];
    int j0 = jbase + quad * 8;
    j0 = (j0 < 0) ? 0 : ((j0 > T_ - 8) ? (T_ - 8) : j0);
#pragma unroll
    for (int md = 0; md < 4; md++) {
      const short8 af = *(const short8*)(vtb + (size_t)(md * 16 + c16) * T_ + j0);
      acc[md] = __builtin_amdgcn_mfma_f32_16x16x32_bf16(af, bf.s8, acc[md], 0, 0, 0);
    }
  }
#pragma unroll
  for (int md = 0; md < 4; md++) {
    uint u0 = (uint)f2bf(acc[md][0]) | ((uint)f2bf(acc[md][1]) << 16);
    uint u1 = (uint)f2bf(acc[md][2]) | ((uint)f2bf(acc[md][3]) << 16);
    uint2 pk = make_uint2(u0, u1);
    u16* dst = o + (size_t)(b * T_ + qt + c16) * C_ + h * D_ + md * 16 + quad * 4;
    *(uint2*)dst = pk;
  }
}

// ---------------- gate logits + 2-way softmax ----------
__global__ __launch_bounds__(256) void k_gate(const u16* __restrict__ h,
                                              const float* __restrict__ gW,
                                              const float* __restrict__ gb,
                                              float* __restrict__ gates) {
  const int row = blockIdx.x * 4 + (threadIdx.x >> 6);
  const int lane = threadIdx.x & 63;
  const u16* hr = h + (size_t)row * C_;
  float s0 = 0.f, s2 = 0.f;
  for (int k = lane; k < C_; k += 64) {
    const float hv = bf2f(hr[k]);
    s0 += hv * gW[k * 3 + 0];
    s2 += hv * gW[k * 3 + 2];
  }
#pragma unroll
  for (int o = 32; o; o >>= 1) { s0 += __shfl_down(s0, o); s2 += __shfl_down(s2, o); }
  if (lane == 0) {
    const float l0 = s0 + gb[0];
    const float l2 = s2 + gb[2];
    const float m = fmaxf(l0, l2);
    const float e0 = __expf(l0 - m), e2 = __expf(l2 - m);
    const float inv = 1.f / (e0 + e2);
    gates[row * 2 + 0] = e0 * inv;
    gates[row * 2 + 1] = e2 * inv;
  }
}

// ---------------- both layers' retrieval projections ---------------
__global__ void k_ret2(const float* __restrict__ rc, const float* __restrict__ rW,
                       float* __restrict__ ret) {
  const int l = blockIdx.x >> 3;
  const int bid = blockIdx.x & 7;
  const int b = bid >> 2;
  const int col = (bid & 3) * 256 + threadIdx.x;
  const float* rWl = rW + (size_t)l * C_ * C_;
  float s = 0.f;
  for (int k = 0; k < C_; k++) s += rc[b * C_ + k] * rWl[(size_t)k * C_ + col];
  ret[(size_t)l * B_ * C_ + b * C_ + col] = s;
}

// ---------------- launcher ----------------
extern "C" void kernel_launch(void* const* d_in, const int* in_sizes, int n_in,
                              void* d_out, int out_size, void* d_ws, size_t ws_size,
                              hipStream_t stream) {
  (void)in_sizes; (void)n_in; (void)out_size; (void)ws_size;
  const float* xin  = (const float*)d_in[0];
  const float* rc   = (const float*)d_in[1];
  const float* n1g  = (const float*)d_in[2];
  const float* Wqkv = (const float*)d_in[3];
  const float* Wpro = (const float*)d_in[4];
  const float* gW   = (const float*)d_in[5];
  const float* gb   = (const float*)d_in[6];
  const float* rW   = (const float*)d_in[7];
  const float* n2g  = (const float*)d_in[8];
  const float* fgW  = (const float*)d_in[9];
  const float* fuW  = (const float*)d_in[10];
  const float* fdW  = (const float*)d_in[11];

  static bool attr_done = false;
  if (!attr_done) {
    hipFuncSetAttribute((const void*)k_g256<0>, hipFuncAttributeMaxDynamicSharedMemorySize, 131072);
    hipFuncSetAttribute((const void*)k_g256s, hipFuncAttributeMaxDynamicSharedMemorySize, 131072);
    hipFuncSetAttribute((const void*)k_g256n<1>, hipFuncAttributeMaxDynamicSharedMemorySize, 98304);
    hipFuncSetAttribute((const void*)k_g256n<2>, hipFuncAttributeMaxDynamicSharedMemorySize, 98304);
    attr_done = true;
  }

  // ---- workspace layout ----
  char* w = (char*)d_ws;
  float* gates = (float*)(w);                            // 32 KB (per-layer, reused)
  float* retb  = (float*)(w + 32768);                    // 16 KB: [L][B][C]
  float* xf32  = (float*)(w + 65536);                    // 16.78 MB residual (f32)
  u16* hbuf    = (u16*)(w + 65536 + (size_t)NELEM * 4);  // 8.39 MB h | h2 | fd^T
  u16* big     = hbuf + NELEM;                           // 33.55 MB region
  u16* qkv  = big;                          // 25.17 MB (attn phase)
  u16* obuf = big + (size_t)NTOK * 3 * C_;  // 8.39 MB  (attn phase)
  u16* gbuf = big;                          // 33.55 MB (FFN phase)
  u16* wT  = (u16*)d_out;                    // 8.39 MB
  u16* wTp = wT + (size_t)3 * C_ * C_;       // Wproj^T
  u16* Vt  = (u16*)d_out + (size_t)NELEM;    // 8.39 MB upper half
  u16* wT2 = Vt;                             // FFN alias
  float* Pf = (float*)d_out;                 // down-proj z0 partial (16.78 MB, FFN tail)

  k_ret2<<<16, 256, 0, stream>>>(rc, rW, retb);

  for (int l = 0; l < L_; l++) {
    if (l == 0)
      k_rms_first<<<NTOK, 256, 0, stream>>>(xin, n1g, xf32, hbuf);
    else
      k_rms_acc<<<NTOK, 256, 0, stream>>>(xf32, Pf, n1g + l * C_, hbuf);
    k_tr2<<<3072 + 1024, dim3(32, 8), 0, stream>>>(
        Wqkv + (size_t)l * C_ * 3 * C_, wT, C_, 3 * C_, 3072,
        Wpro + (size_t)l * C_ * C_, wTp, C_, C_);
    // qkv = h @ Wqkv  (8-phase 256^2, XCD-swizzled)
    k_g256<0><<<dim3(NTOK / 256, 3 * C_ / 256, 1), 512, 131072, stream>>>(
        hbuf, wT, qkv, nullptr, nullptr, 3 * C_, C_);
    k_gate<<<NTOK / 4, 256, 0, stream>>>(hbuf, gW + (size_t)l * C_ * 3, gb + l * 3, gates);
    k_vt<<<dim3(64, 2, 32), dim3(32, 8), 0, stream>>>(qkv, Vt);
    k_attn<<<1024, 256, 0, stream>>>(qkv, Vt, obuf);
    // x += gate0 * (o @ Wproj)   [z=1, 256x128, single-writer RMW, no atomics]
    k_g256n<1><<<dim3(NTOK / 256, C_ / 128, 1), 512, 98304, stream>>>(
        obuf, wTp, xf32, nullptr, gates, C_, C_);
    k_rms2mix<<<NTOK, 256, 0, stream>>>(xf32, gates, retb + (size_t)l * B_ * C_,
                                        n2g + l * C_, hbuf);
    k_tr2<<<4096 + 4096, dim3(32, 8), 0, stream>>>(
        fgW + (size_t)l * C_ * F_, wT, C_, F_, 4096,
        fuW + (size_t)l * C_ * F_, wT2, C_, F_);
    // gbuf = silu(h2@Wg) * (h2@Wu)  (fused 8-phase 256x128, XCD-swizzled)
    k_g256s<<<dim3(NTOK / 256, F_ / 128, 1), 512, 131072, stream>>>(
        hbuf, wT, wT2, gbuf, F_, C_);
    k_tr1<<<4096, dim3(32, 8), 0, stream>>>(fdW + (size_t)l * F_ * C_, hbuf, F_, C_);
    // down: z=2 hybrid — z0 writes f32 partial Pf (d_out, dead here), z1 RMWs xf32
    k_g256n<2><<<dim3(NTOK / 256, C_ / 128, 2), 512, 98304, stream>>>(
        gbuf, hbuf, xf32, Pf, nullptr, C_, F_);
  }

  // out = xf32 + Pf (Pf aliases d_out; in-place add)
  k_copyf_acc<<<NELEM / 256, 256, 0, stream>>>(xf32, (float*)d_out);
}

// Round 4
// 809.984 us; speedup vs baseline: 1.1281x; 1.0144x over previous
//
#include <hip/hip_runtime.h>

#define L_ 2
#define B_ 2
#define T_ 2048
#define C_ 1024
#define H_ 16
#define D_ 64
#define F_ 4096
#define NTOK 4096      // B*T
#define NELEM 4194304  // B*T*C

typedef unsigned short u16;
typedef __attribute__((ext_vector_type(8))) short short8;
typedef __attribute__((ext_vector_type(4))) float float4v;

__device__ __forceinline__ float bf2f(u16 u) {
  unsigned v = ((unsigned)u) << 16;
  return __builtin_bit_cast(float, v);
}
__device__ __forceinline__ u16 f2bf(float f) {
  unsigned u = __builtin_bit_cast(unsigned, f);
  u += 0x7FFFu + ((u >> 16) & 1u);   // round-to-nearest-even
  return (u16)(u >> 16);
}

// Bijective XCD-chunked block swizzle (m204).
__device__ __forceinline__ void xcd_swz(int& bx, int& by) {
  const int gx = gridDim.x;
  const int nwg = gx * gridDim.y;
  const int orig = by * gx + bx;
  const int q = nwg >> 3, r = nwg & 7;
  const int xcd = orig & 7, lid = orig >> 3;
  const int wg = (xcd < r ? xcd * (q + 1) : r * (q + 1) + (xcd - r) * q) + lid;
  bx = wg % gx;
  by = wg / gx;
}

// ---------------- elementwise ----------------
__global__ void k_copyf_acc(const float* __restrict__ in, float* __restrict__ out) {
  // out aliases the f32 partial buffer: out = x + partial (in place)
  const int i = blockIdx.x * 256 + threadIdx.x;
  out[i] = in[i] + out[i];
}

// ---------------- RMSNorm + fused gate (block per row, C=1024) ----------------
// Computes orow = bf16(rms(v)*g), and gates[row*2] = softmax over {l0, l2}
// where l_j = sum_c h_c * gW[c*3+j] + gb[j]  (channel 1 pinned to -inf).
__device__ __forceinline__ void rms_gate_tail(float* vloc, const float* __restrict__ g,
                                              u16* __restrict__ orow,
                                              const float* __restrict__ gw3,
                                              const float* __restrict__ gb3,
                                              float* __restrict__ gates, int row) {
  float s = vloc[0] * vloc[0] + vloc[1] * vloc[1] + vloc[2] * vloc[2] + vloc[3] * vloc[3];
#pragma unroll
  for (int o = 32; o; o >>= 1) s += __shfl_down(s, o);
  __shared__ float red[4];
  __shared__ float rsv;
  if ((threadIdx.x & 63) == 0) red[threadIdx.x >> 6] = s;
  __syncthreads();
  if (threadIdx.x == 0) {
    float t = red[0] + red[1] + red[2] + red[3];
    rsv = rsqrtf(t * (1.f / C_) + 1e-6f);
  }
  __syncthreads();
  const float rr = rsv;
  float s0 = 0.f, s2 = 0.f;
#pragma unroll
  for (int i = 0; i < 4; i++) {
    const int c = threadIdx.x + i * 256;
    const float h = vloc[i] * rr * g[c];
    orow[c] = f2bf(h);
    s0 += h * gw3[c * 3 + 0];
    s2 += h * gw3[c * 3 + 2];
  }
#pragma unroll
  for (int o = 32; o; o >>= 1) { s0 += __shfl_down(s0, o); s2 += __shfl_down(s2, o); }
  __shared__ float r0[4], r2[4];
  if ((threadIdx.x & 63) == 0) { r0[threadIdx.x >> 6] = s0; r2[threadIdx.x >> 6] = s2; }
  __syncthreads();
  if (threadIdx.x == 0) {
    const float l0 = r0[0] + r0[1] + r0[2] + r0[3] + gb3[0];
    const float l2 = r2[0] + r2[1] + r2[2] + r2[3] + gb3[2];
    const float m = fmaxf(l0, l2);
    const float e0 = __expf(l0 - m), e2 = __expf(l2 - m);
    const float inv = 1.f / (e0 + e2);
    gates[row * 2 + 0] = e0 * inv;
    gates[row * 2 + 1] = e2 * inv;
  }
}

__global__ __launch_bounds__(256) void k_rms_first(const float* __restrict__ xin,
                                                   const float* __restrict__ g,
                                                   float* __restrict__ x,
                                                   u16* __restrict__ out,
                                                   const float* __restrict__ gw3,
                                                   const float* __restrict__ gb3,
                                                   float* __restrict__ gates) {
  const int row = blockIdx.x;
  const float* sr = xin + (size_t)row * C_;
  float* xr = x + (size_t)row * C_;
  float vloc[4];
#pragma unroll
  for (int i = 0; i < 4; i++) {
    const int c = threadIdx.x + i * 256;
    const float v = sr[c];
    vloc[i] = v;
    xr[c] = v;
  }
  rms_gate_tail(vloc, g, out + (size_t)row * C_, gw3, gb3, gates, row);
}

// first norm + fold-in of the down-proj z0 partial: x += pf (write back)
__global__ __launch_bounds__(256) void k_rms_acc(float* __restrict__ x,
                                                 const float* __restrict__ pf,
                                                 const float* __restrict__ g,
                                                 u16* __restrict__ out,
                                                 const float* __restrict__ gw3,
                                                 const float* __restrict__ gb3,
                                                 float* __restrict__ gates) {
  const int row = blockIdx.x;
  float* xr = x + (size_t)row * C_;
  const float* pr = pf + (size_t)row * C_;
  float vloc[4];
#pragma unroll
  for (int i = 0; i < 4; i++) {
    const int c = threadIdx.x + i * 256;
    const float v = xr[c] + pr[c];
    vloc[i] = v;
    xr[c] = v;
  }
  rms_gate_tail(vloc, g, out + (size_t)row * C_, gw3, gb3, gates, row);
}

// second norm: x += proj_z0_partial + g2*ret (write back), rms -> out
__global__ __launch_bounds__(256) void k_rms2mix(float* __restrict__ x,
                                                 const float* __restrict__ gates,
                                                 const float* __restrict__ ret,
                                                 const float* __restrict__ pf,
                                                 const float* __restrict__ g,
                                                 u16* __restrict__ out) {
  const int row = blockIdx.x;
  const int b = row >> 11;   // T=2048
  const float g2 = gates[row * 2 + 1];
  const float* rr_ = ret + b * C_;
  const float* pr = pf + (size_t)row * C_;
  float* xr = x + (size_t)row * C_;
  float vloc[4];
#pragma unroll
  for (int i = 0; i < 4; i++) {
    const int c = threadIdx.x + i * 256;
    const float v = xr[c] + pr[c] + g2 * rr_[c];
    vloc[i] = v;
    xr[c] = v;
  }
  // plain rms tail (no gate)
  float s = vloc[0] * vloc[0] + vloc[1] * vloc[1] + vloc[2] * vloc[2] + vloc[3] * vloc[3];
#pragma unroll
  for (int o = 32; o; o >>= 1) s += __shfl_down(s, o);
  __shared__ float red[4];
  __shared__ float rsv;
  if ((threadIdx.x & 63) == 0) red[threadIdx.x >> 6] = s;
  __syncthreads();
  if (threadIdx.x == 0) {
    float t = red[0] + red[1] + red[2] + red[3];
    rsv = rsqrtf(t * (1.f / C_) + 1e-6f);
  }
  __syncthreads();
  const float rr = rsv;
  u16* orow = out + (size_t)row * C_;
#pragma unroll
  for (int i = 0; i < 4; i++) {
    const int c = threadIdx.x + i * 256;
    orow[c] = f2bf(vloc[i] * rr * g[c]);
  }
}

// ---------------- batched transpose+convert: two f32 (K,N) -> bf16 (N,K) ----------
__global__ void k_tr2(const float* __restrict__ s0, u16* __restrict__ d0,
                      int K0, int N0, int t0,
                      const float* __restrict__ s1, u16* __restrict__ d1,
                      int K1, int N1) {
  __shared__ float tile[32][33];
  int t = blockIdx.x;
  const float* src; u16* dst; int K, N;
  if (t < t0) { src = s0; dst = d0; K = K0; N = N0; }
  else { t -= t0; src = s1; dst = d1; K = K1; N = N1; }
  const int ntx = N >> 5;
  const int tx = t % ntx, ty = t / ntx;
  const int x = tx * 32 + threadIdx.x;
  const int y0 = ty * 32 + threadIdx.y;
#pragma unroll
  for (int i = 0; i < 32; i += 8) tile[threadIdx.y + i][threadIdx.x] = src[(size_t)(y0 + i) * N + x];
  __syncthreads();
  const int x2 = ty * 32 + threadIdx.x;
  const int y2 = tx * 32 + threadIdx.y;
#pragma unroll
  for (int i = 0; i < 32; i += 8) dst[(size_t)(y2 + i) * K + x2] = f2bf(tile[threadIdx.x][threadIdx.y + i]);
}

__global__ void k_tr1(const float* __restrict__ in, u16* __restrict__ out, int K, int N) {
  __shared__ float tile[32][33];
  const int ntx = N >> 5;
  const int tx = blockIdx.x % ntx, ty = blockIdx.x / ntx;
  const int x = tx * 32 + threadIdx.x;
  const int y0 = ty * 32 + threadIdx.y;
#pragma unroll
  for (int i = 0; i < 32; i += 8) tile[threadIdx.y + i][threadIdx.x] = in[(size_t)(y0 + i) * N + x];
  __syncthreads();
  const int x2 = ty * 32 + threadIdx.x;
  const int y2 = tx * 32 + threadIdx.y;
#pragma unroll
  for (int i = 0; i < 32; i += 8) out[(size_t)(y2 + i) * K + x2] = f2bf(tile[threadIdx.x][threadIdx.y + i]);
}

// ---------------- V transpose ----------------
__global__ void k_vt(const u16* __restrict__ qkv, u16* __restrict__ Vt) {
  __shared__ u16 tile[32][34];
  const int jt = blockIdx.x;
  const int dt = blockIdx.y;
  const int bh = blockIdx.z;
  const int b = bh >> 4;
  const int h = bh & 15;
  const int tx = threadIdx.x, ty = threadIdx.y;
#pragma unroll
  for (int i = 0; i < 32; i += 8) {
    const int j = jt * 32 + ty + i;
    const int d = dt * 32 + tx;
    tile[ty + i][tx] = qkv[(size_t)(b * T_ + j) * (3 * C_) + 2 * C_ + h * D_ + d];
  }
  __syncthreads();
#pragma unroll
  for (int i = 0; i < 32; i += 8) {
    const int d = dt * 32 + ty + i;
    const int j = jt * 32 + tx;
    Vt[(size_t)(bh * D_ + d) * T_ + j] = tile[tx][ty + i];
  }
}

// ================== 8-phase 256-wide-tile GEMM machinery ==================
#define VMW(n) asm volatile("s_waitcnt vmcnt(" #n ")" ::: "memory")
#define LGKM0 asm volatile("s_waitcnt lgkmcnt(0)" ::: "memory")
#define GBAR() __builtin_amdgcn_s_barrier()
#define PRIO1() __builtin_amdgcn_s_setprio(1)
#define PRIO0() __builtin_amdgcn_s_setprio(0)

// Stage one 128-row x 64-col bf16 half-tile: 2 x global_load_lds_dwordx4.
#define STG8(gsrc, grow0, dstbyte, kk)                                                    \
  do {                                                                                    \
    const u16* g0_ = (gsrc) + (size_t)((grow0) + wid * 8 + srow) * K + (kk) + scol;       \
    __builtin_amdgcn_global_load_lds(                                                     \
        (const __attribute__((address_space(1))) void*)g0_,                               \
        (__attribute__((address_space(3))) void*)(lc + (dstbyte) + wid * 8 * 128),        \
        16, 0, 0);                                                                        \
    const u16* g1_ = g0_ + (size_t)64 * K;                                                \
    __builtin_amdgcn_global_load_lds(                                                     \
        (const __attribute__((address_space(1))) void*)g1_,                               \
        (__attribute__((address_space(3))) void*)(lc + (dstbyte) + (64 + wid * 8) * 128), \
        16, 0, 0);                                                                        \
  } while (0)

#define RDA4(dst, bufbyte, ig0)                                                           \
  { _Pragma("unroll") for (int i_ = 0; i_ < 4; ++i_) {                                    \
      _Pragma("unroll") for (int s_ = 0; s_ < 2; ++s_)                                    \
        dst[i_][s_] = *(const short8*)(lc + (bufbyte) +                                   \
            (wm * 128 + ((ig0) + i_) * 16 + m16) * 128 + (((s_ * 4 + quad) ^ csw) * 16)); } }

#define RDB4(dst, bufbyte, jg0)                                                           \
  { _Pragma("unroll") for (int j_ = 0; j_ < 2; ++j_) {                                    \
      _Pragma("unroll") for (int s_ = 0; s_ < 2; ++s_)                                    \
        dst[j_][s_] = *(const short8*)(lc + (bufbyte) +                                   \
            (wn * 64 + ((jg0) + j_) * 16 + m16) * 128 + (((s_ * 4 + quad) ^ csw) * 16)); } }

#define RDBS(dst, bufbyte)                                                                \
  { _Pragma("unroll") for (int j_ = 0; j_ < 2; ++j_) {                                    \
      _Pragma("unroll") for (int s_ = 0; s_ < 2; ++s_)                                    \
        dst[j_][s_] = *(const short8*)(lc + (bufbyte) +                                   \
            (wn * 32 + j_ * 16 + m16) * 128 + (((s_ * 4 + quad) ^ csw) * 16)); } }

#define MM16(ig0, jg0, bv_)                                                               \
  { _Pragma("unroll") for (int i_ = 0; i_ < 4; ++i_) {                                    \
      _Pragma("unroll") for (int j_ = 0; j_ < 2; ++j_) {                                  \
        _Pragma("unroll") for (int s_ = 0; s_ < 2; ++s_)                                  \
          acc[(ig0) + i_][(jg0) + j_] = __builtin_amdgcn_mfma_f32_16x16x32_bf16(          \
              av[i_][s_], bv_[j_][s_], acc[(ig0) + i_][(jg0) + j_], 0, 0, 0); } } }

#define MMS(accv, ig0, bv_)                                                               \
  { _Pragma("unroll") for (int i_ = 0; i_ < 4; ++i_) {                                    \
      _Pragma("unroll") for (int j_ = 0; j_ < 2; ++j_) {                                  \
        _Pragma("unroll") for (int s_ = 0; s_ < 2; ++s_)                                  \
          accv[(ig0) + i_][j_] = __builtin_amdgcn_mfma_f32_16x16x32_bf16(                 \
              av[i_][s_], bv_[j_][s_], accv[(ig0) + i_][j_], 0, 0, 0); } } }

// 16-MFMA cluster using av8[ig0..ig0+3]
#define MMN(ig0, bv_)                                                                     \
  { _Pragma("unroll") for (int i_ = 0; i_ < 4; ++i_) {                                    \
      _Pragma("unroll") for (int j_ = 0; j_ < 2; ++j_) {                                  \
        _Pragma("unroll") for (int s_ = 0; s_ < 2; ++s_)                                  \
          acc[(ig0) + i_][j_] = __builtin_amdgcn_mfma_f32_16x16x32_bf16(                  \
              av8[(ig0) + i_][s_], bv_[j_][s_], acc[(ig0) + i_][j_], 0, 0, 0); } } }

// ---------------- plain 256x256 GEMM (Cc = bf16(v)) ----------
__global__ __launch_bounds__(512, 2) void k_g256(const u16* __restrict__ A,
                                                 const u16* __restrict__ Bt,
                                                 u16* __restrict__ Cc,
                                                 int N, int K) {
  extern __shared__ __align__(16) u16 lds[];
  char* const lc = (char*)lds;
  enum { A0B = 0, B0B = 32768, A1B = 65536, B1B = 98304 };
  const int tid = threadIdx.x;
  const int wid = tid >> 6, lane = tid & 63;
  const int wm = wid >> 2, wn = wid & 3;
  const int quad = lane >> 4, m16 = lane & 15;
  const int srow = lane >> 3, sc = lane & 7;
  const int scol = ((sc ^ srow) & 7) * 8;
  const int csw = m16 & 7;
  int bx = blockIdx.x, by = blockIdx.y;
  xcd_swz(bx, by);
  const int m0 = bx * 256, n0 = by * 256;
  const int kbeg = 0;
  const int ntile = K >> 6;
  const int nit = ntile >> 1;

  float4v acc[8][4];
#pragma unroll
  for (int i = 0; i < 8; i++)
#pragma unroll
    for (int j = 0; j < 4; j++) acc[i][j] = (float4v){0.f, 0.f, 0.f, 0.f};
  short8 av[4][2], b01[2][2], b23[2][2];

  STG8(Bt, n0, B0B, kbeg);
  STG8(Bt, n0 + 128, B0B + 16384, kbeg);
  STG8(A, m0, A0B, kbeg);
  STG8(A, m0 + 128, A0B + 16384, kbeg);
  STG8(Bt, n0, B1B, kbeg + 64);
  STG8(Bt, n0 + 128, B1B + 16384, kbeg + 64);
  VMW(4);
  GBAR();

#pragma unroll 1
  for (int it = 0; it < nit; ++it) {
    const int t2 = 2 * it + 2, t3 = 2 * it + 3;
    const int k1 = kbeg + (2 * it + 1) * 64;
    const int k2 = kbeg + (t2 < ntile ? t2 : t2 - ntile) * 64;
    const int k3 = kbeg + (t3 < ntile ? t3 : t3 - ntile) * 64;
    RDA4(av, A0B, 0);
    RDB4(b01, B0B, 0);
    STG8(A, m0, A1B, k1);
    GBAR(); LGKM0;
    PRIO1(); MM16(0, 0, b01); PRIO0();
    GBAR();
    RDB4(b23, B0B, 2);
    STG8(A, m0 + 128, A1B + 16384, k1);
    GBAR(); LGKM0;
    PRIO1(); MM16(0, 2, b23); PRIO0();
    GBAR();
    RDA4(av, A0B, 4);
    STG8(Bt, n0, B0B, k2);
    GBAR(); LGKM0;
    PRIO1(); MM16(4, 2, b23); PRIO0();
    GBAR();
    STG8(Bt, n0 + 128, B0B + 16384, k2);
    VMW(4);
    GBAR(); LGKM0;
    PRIO1(); MM16(4, 0, b01); PRIO0();
    GBAR();
    RDA4(av, A1B, 0);
    RDB4(b01, B1B, 0);
    STG8(A, m0, A0B, k2);
    GBAR(); LGKM0;
    PRIO1(); MM16(0, 0, b01); PRIO0();
    GBAR();
    RDB4(b23, B1B, 2);
    STG8(A, m0 + 128, A0B + 16384, k2);
    GBAR(); LGKM0;
    PRIO1(); MM16(0, 2, b23); PRIO0();
    GBAR();
    RDA4(av, A1B, 4);
    STG8(Bt, n0, B1B, k3);
    GBAR(); LGKM0;
    PRIO1(); MM16(4, 2, b23); PRIO0();
    GBAR();
    STG8(Bt, n0 + 128, B1B + 16384, k3);
    VMW(4);
    GBAR(); LGKM0;
    PRIO1(); MM16(4, 0, b01); PRIO0();
    GBAR();
  }

#pragma unroll
  for (int i = 0; i < 8; i++) {
    const int row0 = m0 + wm * 128 + i * 16 + quad * 4;
#pragma unroll
    for (int j = 0; j < 4; j++) {
      const int col = n0 + wn * 64 + j * 16 + m16;
#pragma unroll
      for (int r = 0; r < 4; r++)
        Cc[(size_t)(row0 + r) * N + col] = f2bf(acc[i][j][r]);
    }
  }
}

// ---------------- 256x128 single-B 4-phase GEMM (no atomics, split-K z=2) ----------
// EPI=1 (proj):  sv = gates[row*2]*v ; EPI=2 (down): sv = v
// z0: Pf[idx] = sv ; z1: Xf[idx] += sv   (single-writer each)
template <int EPI>
__global__ __launch_bounds__(512, 2) void k_g256n(const u16* __restrict__ A,
                                                  const u16* __restrict__ Bt,
                                                  float* __restrict__ Xf,
                                                  float* __restrict__ Pf,
                                                  const float* __restrict__ gates,
                                                  int N, int K) {
  extern __shared__ __align__(16) u16 lds[];
  char* const lc = (char*)lds;
  // buf0: A[0,32K) B[32K,48K); buf1: A[48K,80K) B[80K,96K)
  enum { SA0 = 0, SB0 = 32768, SA1 = 49152, SB1 = 81920 };
  const int tid = threadIdx.x;
  const int wid = tid >> 6, lane = tid & 63;
  const int wm = wid >> 2, wn = wid & 3;
  const int quad = lane >> 4, m16 = lane & 15;
  const int srow = lane >> 3, sc = lane & 7;
  const int scol = ((sc ^ srow) & 7) * 8;
  const int csw = m16 & 7;
  int bx = blockIdx.x, by = blockIdx.y;
  xcd_swz(bx, by);
  const int m0 = bx * 256, n0 = by * 128;
  const int Kslice = K / gridDim.z;
  const int kbeg = blockIdx.z * Kslice;
  const int ntile = Kslice >> 6;
  const int nit = ntile >> 1;

  float4v acc[8][2];
#pragma unroll
  for (int i = 0; i < 8; i++)
#pragma unroll
    for (int j = 0; j < 2; j++) acc[i][j] = (float4v){0.f, 0.f, 0.f, 0.f};
  short8 av8[8][2], bv[2][2];

  // prologue = steady state: t0 {B,A0,A1}, t1 {B,A0,A1}; retire t0, t1 in flight
  STG8(Bt, n0, SB0, kbeg);
  STG8(A, m0, SA0, kbeg);
  STG8(A, m0 + 128, SA0 + 16384, kbeg);
  STG8(Bt, n0, SB1, kbeg + 64);
  STG8(A, m0, SA1, kbeg + 64);
  STG8(A, m0 + 128, SA1 + 16384, kbeg + 64);
  VMW(6);
  GBAR();

#pragma unroll 1
  for (int it = 0; it < nit; ++it) {
    const int t2 = 2 * it + 2, t3 = 2 * it + 3;
    const int k2 = kbeg + (t2 < ntile ? t2 : t2 - ntile) * 64;  // wraps last iter (dead)
    const int k3 = kbeg + (t3 < ntile ? t3 : t3 - ntile) * 64;
    // P1: read ALL of buf0 (t0); MFMA lo
    RDA4(av8, SA0, 0);
    RDA4((&av8[4]), SA0, 4);
    RDBS(bv, SB0);
    GBAR(); LGKM0;
    PRIO1(); MMN(0, bv); PRIO0();
    GBAR();
    // P2: stage t2 -> buf0; VMW(6) retires t1 (needed P3); MFMA hi
    STG8(Bt, n0, SB0, k2);
    STG8(A, m0, SA0, k2);
    STG8(A, m0 + 128, SA0 + 16384, k2);
    VMW(6);
    GBAR(); LGKM0;
    PRIO1(); MMN(4, bv); PRIO0();
    GBAR();
    // P3: read ALL of buf1 (t1); MFMA lo
    RDA4(av8, SA1, 0);
    RDA4((&av8[4]), SA1, 4);
    RDBS(bv, SB1);
    GBAR(); LGKM0;
    PRIO1(); MMN(0, bv); PRIO0();
    GBAR();
    // P4: stage t3 -> buf1; VMW(6) retires t2 (needed next P1); MFMA hi
    STG8(Bt, n0, SB1, k3);
    STG8(A, m0, SA1, k3);
    STG8(A, m0 + 128, SA1 + 16384, k3);
    VMW(6);
    GBAR(); LGKM0;
    PRIO1(); MMN(4, bv); PRIO0();
    GBAR();
  }

#pragma unroll
  for (int i = 0; i < 8; i++) {
    const int row0 = m0 + wm * 128 + i * 16 + quad * 4;
#pragma unroll
    for (int j = 0; j < 2; j++) {
      const int col = n0 + wn * 32 + j * 16 + m16;
#pragma unroll
      for (int r = 0; r < 4; r++) {
        const size_t idx = (size_t)(row0 + r) * N + col;
        const float v = acc[i][j][r];
        const float sv = (EPI == 1) ? gates[(row0 + r) * 2] * v : v;
        if (blockIdx.z == 0) Pf[idx] = sv;
        else Xf[idx] += sv;
      }
    }
  }
}

// ---------------- fused SwiGLU dual-GEMM, 256x128 tile, 8-phase ----------
__global__ __launch_bounds__(512, 2) void k_g256s(const u16* __restrict__ A,
                                                  const u16* __restrict__ Btg,
                                                  const u16* __restrict__ Btu,
                                                  u16* __restrict__ Cc,
                                                  int N, int K) {
  extern __shared__ __align__(16) u16 lds[];
  char* const lc = (char*)lds;
  enum { SA0 = 0, SG0 = 32768, SU0 = 49152, SA1 = 65536, SG1 = 98304, SU1 = 114688 };
  const int tid = threadIdx.x;
  const int wid = tid >> 6, lane = tid & 63;
  const int wm = wid >> 2, wn = wid & 3;
  const int quad = lane >> 4, m16 = lane & 15;
  const int srow = lane >> 3, sc = lane & 7;
  const int scol = ((sc ^ srow) & 7) * 8;
  const int csw = m16 & 7;
  int bx = blockIdx.x, by = blockIdx.y;
  xcd_swz(bx, by);
  const int m0 = bx * 256, n0 = by * 128;
  const int kbeg = 0;
  const int ntile = K >> 6;
  const int nit = ntile >> 1;

  float4v accg[8][2], accu[8][2];
#pragma unroll
  for (int i = 0; i < 8; i++)
#pragma unroll
    for (int j = 0; j < 2; j++) {
      accg[i][j] = (float4v){0.f, 0.f, 0.f, 0.f};
      accu[i][j] = (float4v){0.f, 0.f, 0.f, 0.f};
    }
  short8 av[4][2], bg[2][2], bu[2][2];

  STG8(Btg, n0, SG0, kbeg);
  STG8(Btu, n0, SU0, kbeg);
  STG8(A, m0, SA0, kbeg);
  STG8(A, m0 + 128, SA0 + 16384, kbeg);
  STG8(Btg, n0, SG1, kbeg + 64);
  STG8(Btu, n0, SU1, kbeg + 64);
  STG8(A, m0, SA1, kbeg + 64);
  VMW(6);
  GBAR();

#pragma unroll 1
  for (int it = 0; it < nit; ++it) {
    const int t2 = 2 * it + 2, t3 = 2 * it + 3;
    const int k1 = kbeg + (2 * it + 1) * 64;
    const int k2 = kbeg + (t2 < ntile ? t2 : t2 - ntile) * 64;
    const int k3 = kbeg + (t3 < ntile ? t3 : t3 - ntile) * 64;
    RDA4(av, SA0, 0);
    RDBS(bg, SG0);
    STG8(A, m0 + 128, SA1 + 16384, k1);
    GBAR(); LGKM0;
    PRIO1(); MMS(accg, 0, bg); PRIO0();
    GBAR();
    RDBS(bu, SU0);
    STG8(Btg, n0, SG0, k2);
    GBAR(); LGKM0;
    PRIO1(); MMS(accu, 0, bu); PRIO0();
    GBAR();
    RDA4(av, SA0, 4);
    STG8(Btu, n0, SU0, k2);
    GBAR(); LGKM0;
    PRIO1(); MMS(accu, 4, bu); PRIO0();
    GBAR();
    STG8(A, m0, SA0, k2);
    VMW(6);
    GBAR(); LGKM0;
    PRIO1(); MMS(accg, 4, bg); PRIO0();
    GBAR();
    RDA4(av, SA1, 0);
    RDBS(bg, SG1);
    STG8(A, m0 + 128, SA0 + 16384, k2);
    GBAR(); LGKM0;
    PRIO1(); MMS(accg, 0, bg); PRIO0();
    GBAR();
    RDBS(bu, SU1);
    STG8(Btg, n0, SG1, k3);
    GBAR(); LGKM0;
    PRIO1(); MMS(accu, 0, bu); PRIO0();
    GBAR();
    RDA4(av, SA1, 4);
    STG8(Btu, n0, SU1, k3);
    GBAR(); LGKM0;
    PRIO1(); MMS(accu, 4, bu); PRIO0();
    GBAR();
    STG8(A, m0, SA1, k3);
    VMW(6);
    GBAR(); LGKM0;
    PRIO1(); MMS(accg, 4, bg); PRIO0();
    GBAR();
  }

#pragma unroll
  for (int i = 0; i < 8; i++) {
    const int row0 = m0 + wm * 128 + i * 16 + quad * 4;
#pragma unroll
    for (int j = 0; j < 2; j++) {
      const int col = n0 + wn * 32 + j * 16 + m16;
#pragma unroll
      for (int r = 0; r < 4; r++) {
        const float g = accg[i][j][r];
        const float u = accu[i][j][r];
        Cc[(size_t)(row0 + r) * N + col] = f2bf(u * g / (1.f + __expf(-g)));
      }
    }
  }
}

// ---------------- fused attention ----------------
__global__ __launch_bounds__(256) void k_attn(const u16* __restrict__ qkv,
                                              const u16* __restrict__ Vt,
                                              u16* __restrict__ o) {
  __shared__ u16 lds[4][16][290];
  const int wave = threadIdx.x >> 6;
  const int widG = blockIdx.x * 4 + wave;
  const int lane = threadIdx.x & 63;
  const int quad = lane >> 4;
  const int c16 = lane & 15;
  const int qt = (widG & 127) * 16;
  const int h = (widG >> 7) & 15;
  const int b = widG >> 11;
  const size_t rs = 3 * C_;
  const int jt0 = qt - 256;

  const u16* qrow = qkv + (size_t)(b * T_ + qt + c16) * rs + h * D_ + quad * 8;
  const short8 a0 = *(const short8*)(qrow);
  const short8 a1 = *(const short8*)(qrow + 32);
  float4v S[17];
  const short8 z8 = (short8){0, 0, 0, 0, 0, 0, 0, 0};
#pragma unroll
  for (int t = 0; t < 17; t++) {
    if (jt0 + t * 16 + 15 < 0) { S[t] = (float4v){0.f, 0.f, 0.f, 0.f}; continue; }
    const int j = jt0 + t * 16 + c16;
    short8 b0 = z8, b1 = z8;
    if (j >= 0) {
      const u16* krow = qkv + (size_t)(b * T_ + j) * rs + C_ + h * D_ + quad * 8;
      b0 = *(const short8*)(krow);
      b1 = *(const short8*)(krow + 32);
    }
    float4v z = (float4v){0.f, 0.f, 0.f, 0.f};
    z = __builtin_amdgcn_mfma_f32_16x16x32_bf16(a0, b0, z, 0, 0, 0);
    z = __builtin_amdgcn_mfma_f32_16x16x32_bf16(a1, b1, z, 0, 0, 0);
    S[t] = z;
  }
#pragma unroll
  for (int r = 0; r < 4; r++) {
    const int q = qt + quad * 4 + r;
    float mx = -1.0e30f;
#pragma unroll
    for (int t = 0; t < 17; t++) {
      const int j = jt0 + t * 16 + c16;
      const int w = j - q + 255;
      const bool vis = (j >= 0) && (w >= 0) && (w < 256);
      if (vis) {
        const float s = S[t][r] * 0.125f;
        S[t][r] = s;
        mx = fmaxf(mx, s);
      } else {
        S[t][r] = -1.0e30f;
      }
    }
#pragma unroll
    for (int o2 = 1; o2 < 16; o2 <<= 1) mx = fmaxf(mx, __shfl_xor(mx, o2));
    float sum = 0.f;
#pragma unroll
    for (int t = 0; t < 17; t++) {
      const float e = (S[t][r] > -0.9e30f) ? __expf(S[t][r] - mx) : 0.f;
      S[t][r] = e;
      sum += e;
    }
#pragma unroll
    for (int o2 = 1; o2 < 16; o2 <<= 1) sum += __shfl_xor(sum, o2);
    const float inv = 1.f / fmaxf(sum, 1e-30f);
    const int prow = quad * 4 + r;
#pragma unroll
    for (int t = 0; t < 17; t++) lds[wave][prow][t * 16 + c16] = f2bf(S[t][r] * inv);
    lds[wave][prow][272 + c16] = 0;
  }
  __syncthreads();

  float4v acc[4];
#pragma unroll
  for (int md = 0; md < 4; md++) acc[md] = (float4v){0.f, 0.f, 0.f, 0.f};
  const u16* vtb = Vt + (size_t)((b * H_ + h) * D_) * T_;
  const uint* prow32 = (const uint*)(&lds[wave][c16][0]);
  union { short8 s8; uint u[4]; } bf;
#pragma unroll
  for (int c = 0; c < 9; c++) {
    const int jbase = jt0 + c * 32;
    if (jbase + 31 < 0) continue;
#pragma unroll
    for (int w2 = 0; w2 < 4; w2++) bf.u[w2] = prow32[c * 16 + quad * 4 + w2];
    int j0 = jbase + quad * 8;
    j0 = (j0 < 0) ? 0 : ((j0 > T_ - 8) ? (T_ - 8) : j0);
#pragma unroll
    for (int md = 0; md < 4; md++) {
      const short8 af = *(const short8*)(vtb + (size_t)(md * 16 + c16) * T_ + j0);
      acc[md] = __builtin_amdgcn_mfma_f32_16x16x32_bf16(af, bf.s8, acc[md], 0, 0, 0);
    }
  }
#pragma unroll
  for (int md = 0; md < 4; md++) {
    uint u0 = (uint)f2bf(acc[md][0]) | ((uint)f2bf(acc[md][1]) << 16);
    uint u1 = (uint)f2bf(acc[md][2]) | ((uint)f2bf(acc[md][3]) << 16);
    uint2 pk = make_uint2(u0, u1);
    u16* dst = o + (size_t)(b * T_ + qt + c16) * C_ + h * D_ + md * 16 + quad * 4;
    *(uint2*)dst = pk;
  }
}

// ---------------- both layers' retrieval projections ---------------
__global__ void k_ret2(const float* __restrict__ rc, const float* __restrict__ rW,
                       float* __restrict__ ret) {
  const int l = blockIdx.x >> 3;
  const int bid = blockIdx.x & 7;
  const int b = bid >> 2;
  const int col = (bid & 3) * 256 + threadIdx.x;
  const float* rWl = rW + (size_t)l * C_ * C_;
  float s = 0.f;
  for (int k = 0; k < C_; k++) s += rc[b * C_ + k] * rWl[(size_t)k * C_ + col];
  ret[(size_t)l * B_ * C_ + b * C_ + col] = s;
}

// ---------------- launcher ----------------
extern "C" void kernel_launch(void* const* d_in, const int* in_sizes, int n_in,
                              void* d_out, int out_size, void* d_ws, size_t ws_size,
                              hipStream_t stream) {
  (void)in_sizes; (void)n_in; (void)out_size; (void)ws_size;
  const float* xin  = (const float*)d_in[0];
  const float* rc   = (const float*)d_in[1];
  const float* n1g  = (const float*)d_in[2];
  const float* Wqkv = (const float*)d_in[3];
  const float* Wpro = (const float*)d_in[4];
  const float* gW   = (const float*)d_in[5];
  const float* gb   = (const float*)d_in[6];
  const float* rW   = (const float*)d_in[7];
  const float* n2g  = (const float*)d_in[8];
  const float* fgW  = (const float*)d_in[9];
  const float* fuW  = (const float*)d_in[10];
  const float* fdW  = (const float*)d_in[11];

  static bool attr_done = false;
  if (!attr_done) {
    hipFuncSetAttribute((const void*)k_g256, hipFuncAttributeMaxDynamicSharedMemorySize, 131072);
    hipFuncSetAttribute((const void*)k_g256s, hipFuncAttributeMaxDynamicSharedMemorySize, 131072);
    hipFuncSetAttribute((const void*)k_g256n<1>, hipFuncAttributeMaxDynamicSharedMemorySize, 98304);
    hipFuncSetAttribute((const void*)k_g256n<2>, hipFuncAttributeMaxDynamicSharedMemorySize, 98304);
    attr_done = true;
  }

  // ---- workspace layout ----
  char* w = (char*)d_ws;
  float* gates = (float*)(w);                            // 32 KB (per-layer, reused)
  float* retb  = (float*)(w + 32768);                    // 16 KB: [L][B][C]
  float* xf32  = (float*)(w + 65536);                    // 16.78 MB residual (f32)
  u16* hbuf    = (u16*)(w + 65536 + (size_t)NELEM * 4);  // 8.39 MB h | h2 | fd^T
  u16* big     = hbuf + NELEM;                           // 33.55 MB region
  u16* qkv  = big;                          // 25.17 MB (attn phase)
  u16* obuf = big + (size_t)NTOK * 3 * C_;  // 8.39 MB  (attn phase)
  u16* gbuf = big;                          // 33.55 MB (FFN phase)
  u16* wT  = (u16*)d_out;                    // 8.39 MB
  u16* wTp = wT + (size_t)3 * C_ * C_;       // Wproj^T
  u16* Vt  = (u16*)d_out + (size_t)NELEM;    // 8.39 MB upper half
  u16* wT2 = Vt;                             // FFN alias
  float* Pf  = (float*)d_out;                // down z0 partial (16.78 MB, FFN tail)
  float* Pf2 = (float*)big;                  // proj z0 partial (16.78 MB; qkv dead after attn)

  k_ret2<<<16, 256, 0, stream>>>(rc, rW, retb);

  for (int l = 0; l < L_; l++) {
    // h = rms(x)*g1 + fused gate logits/softmax
    if (l == 0)
      k_rms_first<<<NTOK, 256, 0, stream>>>(xin, n1g, xf32, hbuf,
                                            gW, gb, gates);
    else
      k_rms_acc<<<NTOK, 256, 0, stream>>>(xf32, Pf, n1g + l * C_, hbuf,
                                          gW + (size_t)l * C_ * 3, gb + l * 3, gates);
    k_tr2<<<3072 + 1024, dim3(32, 8), 0, stream>>>(
        Wqkv + (size_t)l * C_ * 3 * C_, wT, C_, 3 * C_, 3072,
        Wpro + (size_t)l * C_ * C_, wTp, C_, C_);
    // qkv = h @ Wqkv  (8-phase 256^2, XCD-swizzled)
    k_g256<<<dim3(NTOK / 256, 3 * C_ / 256, 1), 512, 131072, stream>>>(
        hbuf, wT, qkv, 3 * C_, C_);
    k_vt<<<dim3(64, 2, 32), dim3(32, 8), 0, stream>>>(qkv, Vt);
    k_attn<<<1024, 256, 0, stream>>>(qkv, Vt, obuf);
    // gate0*(o @ Wproj): z=2 (full GPU) — z0 partial -> Pf2, z1 RMW xf32
    k_g256n<1><<<dim3(NTOK / 256, C_ / 128, 2), 512, 98304, stream>>>(
        obuf, wTp, xf32, Pf2, gates, C_, C_);
    // x += Pf2 + gate2*ret; h2 = rms(x)*g2
    k_rms2mix<<<NTOK, 256, 0, stream>>>(xf32, gates, retb + (size_t)l * B_ * C_,
                                        Pf2, n2g + l * C_, hbuf);
    k_tr2<<<4096 + 4096, dim3(32, 8), 0, stream>>>(
        fgW + (size_t)l * C_ * F_, wT, C_, F_, 4096,
        fuW + (size_t)l * C_ * F_, wT2, C_, F_);
    // gbuf = silu(h2@Wg) * (h2@Wu)  (fused 8-phase 256x128, XCD-swizzled)
    k_g256s<<<dim3(NTOK / 256, F_ / 128, 1), 512, 131072, stream>>>(
        hbuf, wT, wT2, gbuf, F_, C_);
    k_tr1<<<4096, dim3(32, 8), 0, stream>>>(fdW + (size_t)l * F_ * C_, hbuf, F_, C_);
    // down: z=2 — z0 writes f32 partial Pf (d_out, dead here), z1 RMWs xf32
    k_g256n<2><<<dim3(NTOK / 256, C_ / 128, 2), 512, 98304, stream>>>(
        gbuf, hbuf, xf32, Pf, nullptr, C_, F_);
  }

  // out = xf32 + Pf (Pf aliases d_out; in-place add)
  k_copyf_acc<<<NELEM / 256, 256, 0, stream>>>(xf32, (float*)d_out);
}

// Round 5
// 786.535 us; speedup vs baseline: 1.1618x; 1.0298x over previous
//
#include <hip/hip_runtime.h>

#define L_ 2
#define B_ 2
#define T_ 2048
#define C_ 1024
#define H_ 16
#define D_ 64
#define F_ 4096
#define NTOK 4096      // B*T
#define NELEM 4194304  // B*T*C

typedef unsigned short u16;
typedef __attribute__((ext_vector_type(8))) short short8;
typedef __attribute__((ext_vector_type(4))) float float4v;

__device__ __forceinline__ float bf2f(u16 u) {
  unsigned v = ((unsigned)u) << 16;
  return __builtin_bit_cast(float, v);
}
__device__ __forceinline__ u16 f2bf(float f) {
  unsigned u = __builtin_bit_cast(unsigned, f);
  u += 0x7FFFu + ((u >> 16) & 1u);   // round-to-nearest-even
  return (u16)(u >> 16);
}

// 2D-patch XCD chunking (requires gridDim.x == 16, gridDim.y % 4 == 0).
// HW round-robins flat id over 8 XCDs; XCD k owns an 8 x (gy/4) tile patch
// (2 patches in x, 4 in y). Concurrent per-XCD working set ~6 MB (vs 10 MB
// for 1D row chunking) -> better L2 residency of A/B panels. Bijective.
__device__ __forceinline__ void xcd_swz(int& bx, int& by) {
  const int gy4 = gridDim.y >> 2;
  const int f = by * 16 + bx;
  const int k = f & 7, s = f >> 3;
  bx = ((k & 1) << 3) + (s & 7);
  by = (k >> 1) * gy4 + (s >> 3);
}

// ---------------- elementwise ----------------
__global__ void k_copyf_acc(const float* __restrict__ in, float* __restrict__ out) {
  // out aliases the f32 partial buffer: out = x + partial (in place)
  const int i = blockIdx.x * 256 + threadIdx.x;
  out[i] = in[i] + out[i];
}

// ---------------- RMSNorm + fused gate (block per row, C=1024) ----------------
__device__ __forceinline__ void rms_gate_tail(float* vloc, const float* __restrict__ g,
                                              u16* __restrict__ orow,
                                              const float* __restrict__ gw3,
                                              const float* __restrict__ gb3,
                                              float* __restrict__ gates, int row) {
  float s = vloc[0] * vloc[0] + vloc[1] * vloc[1] + vloc[2] * vloc[2] + vloc[3] * vloc[3];
#pragma unroll
  for (int o = 32; o; o >>= 1) s += __shfl_down(s, o);
  __shared__ float red[4];
  __shared__ float rsv;
  if ((threadIdx.x & 63) == 0) red[threadIdx.x >> 6] = s;
  __syncthreads();
  if (threadIdx.x == 0) {
    float t = red[0] + red[1] + red[2] + red[3];
    rsv = rsqrtf(t * (1.f / C_) + 1e-6f);
  }
  __syncthreads();
  const float rr = rsv;
  float s0 = 0.f, s2 = 0.f;
#pragma unroll
  for (int i = 0; i < 4; i++) {
    const int c = threadIdx.x + i * 256;
    const float h = vloc[i] * rr * g[c];
    orow[c] = f2bf(h);
    s0 += h * gw3[c * 3 + 0];
    s2 += h * gw3[c * 3 + 2];
  }
#pragma unroll
  for (int o = 32; o; o >>= 1) { s0 += __shfl_down(s0, o); s2 += __shfl_down(s2, o); }
  __shared__ float r0[4], r2[4];
  if ((threadIdx.x & 63) == 0) { r0[threadIdx.x >> 6] = s0; r2[threadIdx.x >> 6] = s2; }
  __syncthreads();
  if (threadIdx.x == 0) {
    const float l0 = r0[0] + r0[1] + r0[2] + r0[3] + gb3[0];
    const float l2 = r2[0] + r2[1] + r2[2] + r2[3] + gb3[2];
    const float m = fmaxf(l0, l2);
    const float e0 = __expf(l0 - m), e2 = __expf(l2 - m);
    const float inv = 1.f / (e0 + e2);
    gates[row * 2 + 0] = e0 * inv;
    gates[row * 2 + 1] = e2 * inv;
  }
}

__global__ __launch_bounds__(256) void k_rms_first(const float* __restrict__ xin,
                                                   const float* __restrict__ g,
                                                   float* __restrict__ x,
                                                   u16* __restrict__ out,
                                                   const float* __restrict__ gw3,
                                                   const float* __restrict__ gb3,
                                                   float* __restrict__ gates) {
  const int row = blockIdx.x;
  const float* sr = xin + (size_t)row * C_;
  float* xr = x + (size_t)row * C_;
  float vloc[4];
#pragma unroll
  for (int i = 0; i < 4; i++) {
    const int c = threadIdx.x + i * 256;
    const float v = sr[c];
    vloc[i] = v;
    xr[c] = v;
  }
  rms_gate_tail(vloc, g, out + (size_t)row * C_, gw3, gb3, gates, row);
}

// first norm + fold-in of the down-proj z0 partial: x += pf (write back)
__global__ __launch_bounds__(256) void k_rms_acc(float* __restrict__ x,
                                                 const float* __restrict__ pf,
                                                 const float* __restrict__ g,
                                                 u16* __restrict__ out,
                                                 const float* __restrict__ gw3,
                                                 const float* __restrict__ gb3,
                                                 float* __restrict__ gates) {
  const int row = blockIdx.x;
  float* xr = x + (size_t)row * C_;
  const float* pr = pf + (size_t)row * C_;
  float vloc[4];
#pragma unroll
  for (int i = 0; i < 4; i++) {
    const int c = threadIdx.x + i * 256;
    const float v = xr[c] + pr[c];
    vloc[i] = v;
    xr[c] = v;
  }
  rms_gate_tail(vloc, g, out + (size_t)row * C_, gw3, gb3, gates, row);
}

// second norm: x += proj_z0_partial + g2*ret (write back), rms -> out
__global__ __launch_bounds__(256) void k_rms2mix(float* __restrict__ x,
                                                 const float* __restrict__ gates,
                                                 const float* __restrict__ ret,
                                                 const float* __restrict__ pf,
                                                 const float* __restrict__ g,
                                                 u16* __restrict__ out) {
  const int row = blockIdx.x;
  const int b = row >> 11;   // T=2048
  const float g2 = gates[row * 2 + 1];
  const float* rr_ = ret + b * C_;
  const float* pr = pf + (size_t)row * C_;
  float* xr = x + (size_t)row * C_;
  float vloc[4];
#pragma unroll
  for (int i = 0; i < 4; i++) {
    const int c = threadIdx.x + i * 256;
    const float v = xr[c] + pr[c] + g2 * rr_[c];
    vloc[i] = v;
    xr[c] = v;
  }
  float s = vloc[0] * vloc[0] + vloc[1] * vloc[1] + vloc[2] * vloc[2] + vloc[3] * vloc[3];
#pragma unroll
  for (int o = 32; o; o >>= 1) s += __shfl_down(s, o);
  __shared__ float red[4];
  __shared__ float rsv;
  if ((threadIdx.x & 63) == 0) red[threadIdx.x >> 6] = s;
  __syncthreads();
  if (threadIdx.x == 0) {
    float t = red[0] + red[1] + red[2] + red[3];
    rsv = rsqrtf(t * (1.f / C_) + 1e-6f);
  }
  __syncthreads();
  const float rr = rsv;
  u16* orow = out + (size_t)row * C_;
#pragma unroll
  for (int i = 0; i < 4; i++) {
    const int c = threadIdx.x + i * 256;
    orow[c] = f2bf(vloc[i] * rr * g[c]);
  }
}

// ---------------- batched transpose+convert: two f32 (K,N) -> bf16 (N,K) ----------
__global__ void k_tr2(const float* __restrict__ s0, u16* __restrict__ d0,
                      int K0, int N0, int t0,
                      const float* __restrict__ s1, u16* __restrict__ d1,
                      int K1, int N1) {
  __shared__ float tile[32][33];
  int t = blockIdx.x;
  const float* src; u16* dst; int K, N;
  if (t < t0) { src = s0; dst = d0; K = K0; N = N0; }
  else { t -= t0; src = s1; dst = d1; K = K1; N = N1; }
  const int ntx = N >> 5;
  const int tx = t % ntx, ty = t / ntx;
  const int x = tx * 32 + threadIdx.x;
  const int y0 = ty * 32 + threadIdx.y;
#pragma unroll
  for (int i = 0; i < 32; i += 8) tile[threadIdx.y + i][threadIdx.x] = src[(size_t)(y0 + i) * N + x];
  __syncthreads();
  const int x2 = ty * 32 + threadIdx.x;
  const int y2 = tx * 32 + threadIdx.y;
#pragma unroll
  for (int i = 0; i < 32; i += 8) dst[(size_t)(y2 + i) * K + x2] = f2bf(tile[threadIdx.x][threadIdx.y + i]);
}

__global__ void k_tr1(const float* __restrict__ in, u16* __restrict__ out, int K, int N) {
  __shared__ float tile[32][33];
  const int ntx = N >> 5;
  const int tx = blockIdx.x % ntx, ty = blockIdx.x / ntx;
  const int x = tx * 32 + threadIdx.x;
  const int y0 = ty * 32 + threadIdx.y;
#pragma unroll
  for (int i = 0; i < 32; i += 8) tile[threadIdx.y + i][threadIdx.x] = in[(size_t)(y0 + i) * N + x];
  __syncthreads();
  const int x2 = ty * 32 + threadIdx.x;
  const int y2 = tx * 32 + threadIdx.y;
#pragma unroll
  for (int i = 0; i < 32; i += 8) out[(size_t)(y2 + i) * K + x2] = f2bf(tile[threadIdx.x][threadIdx.y + i]);
}

// ---------------- V transpose ----------------
__global__ void k_vt(const u16* __restrict__ qkv, u16* __restrict__ Vt) {
  __shared__ u16 tile[32][34];
  const int jt = blockIdx.x;
  const int dt = blockIdx.y;
  const int bh = blockIdx.z;
  const int b = bh >> 4;
  const int h = bh & 15;
  const int tx = threadIdx.x, ty = threadIdx.y;
#pragma unroll
  for (int i = 0; i < 32; i += 8) {
    const int j = jt * 32 + ty + i;
    const int d = dt * 32 + tx;
    tile[ty + i][tx] = qkv[(size_t)(b * T_ + j) * (3 * C_) + 2 * C_ + h * D_ + d];
  }
  __syncthreads();
#pragma unroll
  for (int i = 0; i < 32; i += 8) {
    const int d = dt * 32 + ty + i;
    const int j = jt * 32 + tx;
    Vt[(size_t)(bh * D_ + d) * T_ + j] = tile[tx][ty + i];
  }
}

// ================== 8-phase 256-wide-tile GEMM machinery ==================
#define VMW(n) asm volatile("s_waitcnt vmcnt(" #n ")" ::: "memory")
#define LGKM0 asm volatile("s_waitcnt lgkmcnt(0)" ::: "memory")
#define GBAR() __builtin_amdgcn_s_barrier()
#define PRIO1() __builtin_amdgcn_s_setprio(1)
#define PRIO0() __builtin_amdgcn_s_setprio(0)

// Stage one 128-row x 64-col bf16 half-tile: 2 x global_load_lds_dwordx4.
#define STG8(gsrc, grow0, dstbyte, kk)                                                    \
  do {                                                                                    \
    const u16* g0_ = (gsrc) + (size_t)((grow0) + wid * 8 + srow) * K + (kk) + scol;       \
    __builtin_amdgcn_global_load_lds(                                                     \
        (const __attribute__((address_space(1))) void*)g0_,                               \
        (__attribute__((address_space(3))) void*)(lc + (dstbyte) + wid * 8 * 128),        \
        16, 0, 0);                                                                        \
    const u16* g1_ = g0_ + (size_t)64 * K;                                                \
    __builtin_amdgcn_global_load_lds(                                                     \
        (const __attribute__((address_space(1))) void*)g1_,                               \
        (__attribute__((address_space(3))) void*)(lc + (dstbyte) + (64 + wid * 8) * 128), \
        16, 0, 0);                                                                        \
  } while (0)

#define RDA4(dst, bufbyte, ig0)                                                           \
  { _Pragma("unroll") for (int i_ = 0; i_ < 4; ++i_) {                                    \
      _Pragma("unroll") for (int s_ = 0; s_ < 2; ++s_)                                    \
        dst[i_][s_] = *(const short8*)(lc + (bufbyte) +                                   \
            (wm * 128 + ((ig0) + i_) * 16 + m16) * 128 + (((s_ * 4 + quad) ^ csw) * 16)); } }

#define RDB4(dst, bufbyte, jg0)                                                           \
  { _Pragma("unroll") for (int j_ = 0; j_ < 2; ++j_) {                                    \
      _Pragma("unroll") for (int s_ = 0; s_ < 2; ++s_)                                    \
        dst[j_][s_] = *(const short8*)(lc + (bufbyte) +                                   \
            (wn * 64 + ((jg0) + j_) * 16 + m16) * 128 + (((s_ * 4 + quad) ^ csw) * 16)); } }

#define RDBS(dst, bufbyte)                                                                \
  { _Pragma("unroll") for (int j_ = 0; j_ < 2; ++j_) {                                    \
      _Pragma("unroll") for (int s_ = 0; s_ < 2; ++s_)                                    \
        dst[j_][s_] = *(const short8*)(lc + (bufbyte) +                                   \
            (wn * 32 + j_ * 16 + m16) * 128 + (((s_ * 4 + quad) ^ csw) * 16)); } }

#define MM16(ig0, jg0, bv_)                                                               \
  { _Pragma("unroll") for (int i_ = 0; i_ < 4; ++i_) {                                    \
      _Pragma("unroll") for (int j_ = 0; j_ < 2; ++j_) {                                  \
        _Pragma("unroll") for (int s_ = 0; s_ < 2; ++s_)                                  \
          acc[(ig0) + i_][(jg0) + j_] = __builtin_amdgcn_mfma_f32_16x16x32_bf16(          \
              av[i_][s_], bv_[j_][s_], acc[(ig0) + i_][(jg0) + j_], 0, 0, 0); } } }

#define MMS(accv, ig0, bv_)                                                               \
  { _Pragma("unroll") for (int i_ = 0; i_ < 4; ++i_) {                                    \
      _Pragma("unroll") for (int j_ = 0; j_ < 2; ++j_) {                                  \
        _Pragma("unroll") for (int s_ = 0; s_ < 2; ++s_)                                  \
          accv[(ig0) + i_][j_] = __builtin_amdgcn_mfma_f32_16x16x32_bf16(                 \
              av[i_][s_], bv_[j_][s_], accv[(ig0) + i_][j_], 0, 0, 0); } } }

// 16-MFMA cluster using av8[ig0..ig0+3]
#define MMN(ig0, bv_)                                                                     \
  { _Pragma("unroll") for (int i_ = 0; i_ < 4; ++i_) {                                    \
      _Pragma("unroll") for (int j_ = 0; j_ < 2; ++j_) {                                  \
        _Pragma("unroll") for (int s_ = 0; s_ < 2; ++s_)                                  \
          acc[(ig0) + i_][j_] = __builtin_amdgcn_mfma_f32_16x16x32_bf16(                  \
              av8[(ig0) + i_][s_], bv_[j_][s_], acc[(ig0) + i_][j_], 0, 0, 0); } } }

// ---------------- plain 256x256 GEMM (Cc = bf16(v)) ----------
__global__ __launch_bounds__(512, 2) void k_g256(const u16* __restrict__ A,
                                                 const u16* __restrict__ Bt,
                                                 u16* __restrict__ Cc,
                                                 int N, int K) {
  extern __shared__ __align__(16) u16 lds[];
  char* const lc = (char*)lds;
  enum { A0B = 0, B0B = 32768, A1B = 65536, B1B = 98304 };
  const int tid = threadIdx.x;
  const int wid = tid >> 6, lane = tid & 63;
  const int wm = wid >> 2, wn = wid & 3;
  const int quad = lane >> 4, m16 = lane & 15;
  const int srow = lane >> 3, sc = lane & 7;
  const int scol = ((sc ^ srow) & 7) * 8;
  const int csw = m16 & 7;
  int bx = blockIdx.x, by = blockIdx.y;
  xcd_swz(bx, by);
  const int m0 = bx * 256, n0 = by * 256;
  const int kbeg = 0;
  const int ntile = K >> 6;
  const int nit = ntile >> 1;

  float4v acc[8][4];
#pragma unroll
  for (int i = 0; i < 8; i++)
#pragma unroll
    for (int j = 0; j < 4; j++) acc[i][j] = (float4v){0.f, 0.f, 0.f, 0.f};
  short8 av[4][2], b01[2][2], b23[2][2];

  STG8(Bt, n0, B0B, kbeg);
  STG8(Bt, n0 + 128, B0B + 16384, kbeg);
  STG8(A, m0, A0B, kbeg);
  STG8(A, m0 + 128, A0B + 16384, kbeg);
  STG8(Bt, n0, B1B, kbeg + 64);
  STG8(Bt, n0 + 128, B1B + 16384, kbeg + 64);
  VMW(4);
  GBAR();

#pragma unroll 1
  for (int it = 0; it < nit; ++it) {
    const int t2 = 2 * it + 2, t3 = 2 * it + 3;
    const int k1 = kbeg + (2 * it + 1) * 64;
    const int k2 = kbeg + (t2 < ntile ? t2 : t2 - ntile) * 64;
    const int k3 = kbeg + (t3 < ntile ? t3 : t3 - ntile) * 64;
    RDA4(av, A0B, 0);
    RDB4(b01, B0B, 0);
    STG8(A, m0, A1B, k1);
    GBAR(); LGKM0;
    PRIO1(); MM16(0, 0, b01); PRIO0();
    GBAR();
    RDB4(b23, B0B, 2);
    STG8(A, m0 + 128, A1B + 16384, k1);
    GBAR(); LGKM0;
    PRIO1(); MM16(0, 2, b23); PRIO0();
    GBAR();
    RDA4(av, A0B, 4);
    STG8(Bt, n0, B0B, k2);
    GBAR(); LGKM0;
    PRIO1(); MM16(4, 2, b23); PRIO0();
    GBAR();
    STG8(Bt, n0 + 128, B0B + 16384, k2);
    VMW(4);
    GBAR(); LGKM0;
    PRIO1(); MM16(4, 0, b01); PRIO0();
    GBAR();
    RDA4(av, A1B, 0);
    RDB4(b01, B1B, 0);
    STG8(A, m0, A0B, k2);
    GBAR(); LGKM0;
    PRIO1(); MM16(0, 0, b01); PRIO0();
    GBAR();
    RDB4(b23, B1B, 2);
    STG8(A, m0 + 128, A0B + 16384, k2);
    GBAR(); LGKM0;
    PRIO1(); MM16(0, 2, b23); PRIO0();
    GBAR();
    RDA4(av, A1B, 4);
    STG8(Bt, n0, B1B, k3);
    GBAR(); LGKM0;
    PRIO1(); MM16(4, 2, b23); PRIO0();
    GBAR();
    STG8(Bt, n0 + 128, B1B + 16384, k3);
    VMW(4);
    GBAR(); LGKM0;
    PRIO1(); MM16(4, 0, b01); PRIO0();
    GBAR();
  }

#pragma unroll
  for (int i = 0; i < 8; i++) {
    const int row0 = m0 + wm * 128 + i * 16 + quad * 4;
#pragma unroll
    for (int j = 0; j < 4; j++) {
      const int col = n0 + wn * 64 + j * 16 + m16;
#pragma unroll
      for (int r = 0; r < 4; r++)
        Cc[(size_t)(row0 + r) * N + col] = f2bf(acc[i][j][r]);
    }
  }
}

// ---------------- 256x128 single-B 4-phase GEMM (no atomics, split-K z=2) ----------
// EPI=1 (proj):  sv = gates[row*2]*v ; EPI=2 (down): sv = v
// z0: Pf[idx] = sv ; z1: Xf[idx] += sv   (single-writer each)
template <int EPI>
__global__ __launch_bounds__(512, 2) void k_g256n(const u16* __restrict__ A,
                                                  const u16* __restrict__ Bt,
                                                  float* __restrict__ Xf,
                                                  float* __restrict__ Pf,
                                                  const float* __restrict__ gates,
                                                  int N, int K) {
  extern __shared__ __align__(16) u16 lds[];
  char* const lc = (char*)lds;
  // buf0: A[0,32K) B[32K,48K); buf1: A[48K,80K) B[80K,96K)
  enum { SA0 = 0, SB0 = 32768, SA1 = 49152, SB1 = 81920 };
  const int tid = threadIdx.x;
  const int wid = tid >> 6, lane = tid & 63;
  const int wm = wid >> 2, wn = wid & 3;
  const int quad = lane >> 4, m16 = lane & 15;
  const int srow = lane >> 3, sc = lane & 7;
  const int scol = ((sc ^ srow) & 7) * 8;
  const int csw = m16 & 7;
  int bx = blockIdx.x, by = blockIdx.y;
  xcd_swz(bx, by);
  const int m0 = bx * 256, n0 = by * 128;
  const int Kslice = K / gridDim.z;
  const int kbeg = blockIdx.z * Kslice;
  const int ntile = Kslice >> 6;
  const int nit = ntile >> 1;

  float4v acc[8][2];
#pragma unroll
  for (int i = 0; i < 8; i++)
#pragma unroll
    for (int j = 0; j < 2; j++) acc[i][j] = (float4v){0.f, 0.f, 0.f, 0.f};
  short8 av8[8][2], bv[2][2];

  // prologue = steady state: t0 {B,A0,A1}, t1 {B,A0,A1}; retire t0, t1 in flight
  STG8(Bt, n0, SB0, kbeg);
  STG8(A, m0, SA0, kbeg);
  STG8(A, m0 + 128, SA0 + 16384, kbeg);
  STG8(Bt, n0, SB1, kbeg + 64);
  STG8(A, m0, SA1, kbeg + 64);
  STG8(A, m0 + 128, SA1 + 16384, kbeg + 64);
  VMW(6);
  GBAR();

#pragma unroll 1
  for (int it = 0; it < nit; ++it) {
    const int t2 = 2 * it + 2, t3 = 2 * it + 3;
    const int k2 = kbeg + (t2 < ntile ? t2 : t2 - ntile) * 64;  // wraps last iter (dead)
    const int k3 = kbeg + (t3 < ntile ? t3 : t3 - ntile) * 64;
    // P1: read ALL of buf0 (t0); MFMA lo
    RDA4(av8, SA0, 0);
    RDA4((&av8[4]), SA0, 4);
    RDBS(bv, SB0);
    GBAR(); LGKM0;
    PRIO1(); MMN(0, bv); PRIO0();
    GBAR();
    // P2: stage t2 -> buf0; VMW(6) retires t1 (needed P3); MFMA hi
    STG8(Bt, n0, SB0, k2);
    STG8(A, m0, SA0, k2);
    STG8(A, m0 + 128, SA0 + 16384, k2);
    VMW(6);
    GBAR(); LGKM0;
    PRIO1(); MMN(4, bv); PRIO0();
    GBAR();
    // P3: read ALL of buf1 (t1); MFMA lo
    RDA4(av8, SA1, 0);
    RDA4((&av8[4]), SA1, 4);
    RDBS(bv, SB1);
    GBAR(); LGKM0;
    PRIO1(); MMN(0, bv); PRIO0();
    GBAR();
    // P4: stage t3 -> buf1; VMW(6) retires t2 (needed next P1); MFMA hi
    STG8(Bt, n0, SB1, k3);
    STG8(A, m0, SA1, k3);
    STG8(A, m0 + 128, SA1 + 16384, k3);
    VMW(6);
    GBAR(); LGKM0;
    PRIO1(); MMN(4, bv); PRIO0();
    GBAR();
  }

#pragma unroll
  for (int i = 0; i < 8; i++) {
    const int row0 = m0 + wm * 128 + i * 16 + quad * 4;
#pragma unroll
    for (int j = 0; j < 2; j++) {
      const int col = n0 + wn * 32 + j * 16 + m16;
#pragma unroll
      for (int r = 0; r < 4; r++) {
        const size_t idx = (size_t)(row0 + r) * N + col;
        const float v = acc[i][j][r];
        const float sv = (EPI == 1) ? gates[(row0 + r) * 2] * v : v;
        if (blockIdx.z == 0) Pf[idx] = sv;
        else Xf[idx] += sv;
      }
    }
  }
}

// ---------------- fused SwiGLU dual-GEMM, 256x128 tile, 8-phase ----------
__global__ __launch_bounds__(512, 2) void k_g256s(const u16* __restrict__ A,
                                                  const u16* __restrict__ Btg,
                                                  const u16* __restrict__ Btu,
                                                  u16* __restrict__ Cc,
                                                  int N, int K) {
  extern __shared__ __align__(16) u16 lds[];
  char* const lc = (char*)lds;
  enum { SA0 = 0, SG0 = 32768, SU0 = 49152, SA1 = 65536, SG1 = 98304, SU1 = 114688 };
  const int tid = threadIdx.x;
  const int wid = tid >> 6, lane = tid & 63;
  const int wm = wid >> 2, wn = wid & 3;
  const int quad = lane >> 4, m16 = lane & 15;
  const int srow = lane >> 3, sc = lane & 7;
  const int scol = ((sc ^ srow) & 7) * 8;
  const int csw = m16 & 7;
  int bx = blockIdx.x, by = blockIdx.y;
  xcd_swz(bx, by);
  const int m0 = bx * 256, n0 = by * 128;
  const int kbeg = 0;
  const int ntile = K >> 6;
  const int nit = ntile >> 1;

  float4v accg[8][2], accu[8][2];
#pragma unroll
  for (int i = 0; i < 8; i++)
#pragma unroll
    for (int j = 0; j < 2; j++) {
      accg[i][j] = (float4v){0.f, 0.f, 0.f, 0.f};
      accu[i][j] = (float4v){0.f, 0.f, 0.f, 0.f};
    }
  short8 av[4][2], bg[2][2], bu[2][2];

  STG8(Btg, n0, SG0, kbeg);
  STG8(Btu, n0, SU0, kbeg);
  STG8(A, m0, SA0, kbeg);
  STG8(A, m0 + 128, SA0 + 16384, kbeg);
  STG8(Btg, n0, SG1, kbeg + 64);
  STG8(Btu, n0, SU1, kbeg + 64);
  STG8(A, m0, SA1, kbeg + 64);
  VMW(6);
  GBAR();

#pragma unroll 1
  for (int it = 0; it < nit; ++it) {
    const int t2 = 2 * it + 2, t3 = 2 * it + 3;
    const int k1 = kbeg + (2 * it + 1) * 64;
    const int k2 = kbeg + (t2 < ntile ? t2 : t2 - ntile) * 64;
    const int k3 = kbeg + (t3 < ntile ? t3 : t3 - ntile) * 64;
    RDA4(av, SA0, 0);
    RDBS(bg, SG0);
    STG8(A, m0 + 128, SA1 + 16384, k1);
    GBAR(); LGKM0;
    PRIO1(); MMS(accg, 0, bg); PRIO0();
    GBAR();
    RDBS(bu, SU0);
    STG8(Btg, n0, SG0, k2);
    GBAR(); LGKM0;
    PRIO1(); MMS(accu, 0, bu); PRIO0();
    GBAR();
    RDA4(av, SA0, 4);
    STG8(Btu, n0, SU0, k2);
    GBAR(); LGKM0;
    PRIO1(); MMS(accu, 4, bu); PRIO0();
    GBAR();
    STG8(A, m0, SA0, k2);
    VMW(6);
    GBAR(); LGKM0;
    PRIO1(); MMS(accg, 4, bg); PRIO0();
    GBAR();
    RDA4(av, SA1, 0);
    RDBS(bg, SG1);
    STG8(A, m0 + 128, SA0 + 16384, k2);
    GBAR(); LGKM0;
    PRIO1(); MMS(accg, 0, bg); PRIO0();
    GBAR();
    RDBS(bu, SU1);
    STG8(Btg, n0, SG1, k3);
    GBAR(); LGKM0;
    PRIO1(); MMS(accu, 0, bu); PRIO0();
    GBAR();
    RDA4(av, SA1, 4);
    STG8(Btu, n0, SU1, k3);
    GBAR(); LGKM0;
    PRIO1(); MMS(accu, 4, bu); PRIO0();
    GBAR();
    STG8(A, m0, SA1, k3);
    VMW(6);
    GBAR(); LGKM0;
    PRIO1(); MMS(accg, 4, bg); PRIO0();
    GBAR();
  }

#pragma unroll
  for (int i = 0; i < 8; i++) {
    const int row0 = m0 + wm * 128 + i * 16 + quad * 4;
#pragma unroll
    for (int j = 0; j < 2; j++) {
      const int col = n0 + wn * 32 + j * 16 + m16;
#pragma unroll
      for (int r = 0; r < 4; r++) {
        const float g = accg[i][j][r];
        const float u = accu[i][j][r];
        Cc[(size_t)(row0 + r) * N + col] = f2bf(u * g / (1.f + __expf(-g)));
      }
    }
  }
}

// ---------------- fused attention ----------------
__global__ __launch_bounds__(256) void k_attn(const u16* __restrict__ qkv,
                                              const u16* __restrict__ Vt,
                                              u16* __restrict__ o) {
  __shared__ u16 lds[4][16][290];
  const int wave = threadIdx.x >> 6;
  // XCD-chunked remap: 1024 blocks = 8 XCD x 128; each XCD owns 4 contiguous
  // (b,h) groups -> its K/V working set (2 MB) is L2-resident.
  const int bid = ((blockIdx.x & 7) << 7) + (blockIdx.x >> 3);
  const int widG = bid * 4 + wave;
  const int lane = threadIdx.x & 63;
  const int quad = lane >> 4;
  const int c16 = lane & 15;
  const int qt = (widG & 127) * 16;
  const int h = (widG >> 7) & 15;
  const int b = widG >> 11;
  const size_t rs = 3 * C_;
  const int jt0 = qt - 256;

  const u16* qrow = qkv + (size_t)(b * T_ + qt + c16) * rs + h * D_ + quad * 8;
  const short8 a0 = *(const short8*)(qrow);
  const short8 a1 = *(const short8*)(qrow + 32);
  float4v S[17];
  const short8 z8 = (short8){0, 0, 0, 0, 0, 0, 0, 0};
#pragma unroll
  for (int t = 0; t < 17; t++) {
    if (jt0 + t * 16 + 15 < 0) { S[t] = (float4v){0.f, 0.f, 0.f, 0.f}; continue; }
    const int j = jt0 + t * 16 + c16;
    short8 b0 = z8, b1 = z8;
    if (j >= 0) {
      const u16* krow = qkv + (size_t)(b * T_ + j) * rs + C_ + h * D_ + quad * 8;
      b0 = *(const short8*)(krow);
      b1 = *(const short8*)(krow + 32);
    }
    float4v z = (float4v){0.f, 0.f, 0.f, 0.f};
    PRIO1();
    z = __builtin_amdgcn_mfma_f32_16x16x32_bf16(a0, b0, z, 0, 0, 0);
    z = __builtin_amdgcn_mfma_f32_16x16x32_bf16(a1, b1, z, 0, 0, 0);
    PRIO0();
    S[t] = z;
  }
#pragma unroll
  for (int r = 0; r < 4; r++) {
    const int q = qt + quad * 4 + r;
    float mx = -1.0e30f;
#pragma unroll
    for (int t = 0; t < 17; t++) {
      const int j = jt0 + t * 16 + c16;
      const int w = j - q + 255;
      const bool vis = (j >= 0) && (w >= 0) && (w < 256);
      if (vis) {
        const float s = S[t][r] * 0.125f;
        S[t][r] = s;
        mx = fmaxf(mx, s);
      } else {
        S[t][r] = -1.0e30f;
      }
    }
#pragma unroll
    for (int o2 = 1; o2 < 16; o2 <<= 1) mx = fmaxf(mx, __shfl_xor(mx, o2));
    float sum = 0.f;
#pragma unroll
    for (int t = 0; t < 17; t++) {
      const float e = (S[t][r] > -0.9e30f) ? __expf(S[t][r] - mx) : 0.f;
      S[t][r] = e;
      sum += e;
    }
#pragma unroll
    for (int o2 = 1; o2 < 16; o2 <<= 1) sum += __shfl_xor(sum, o2);
    const float inv = 1.f / fmaxf(sum, 1e-30f);
    const int prow = quad * 4 + r;
#pragma unroll
    for (int t = 0; t < 17; t++) lds[wave][prow][t * 16 + c16] = f2bf(S[t][r] * inv);
    lds[wave][prow][272 + c16] = 0;
  }
  __syncthreads();

  float4v acc[4];
#pragma unroll
  for (int md = 0; md < 4; md++) acc[md] = (float4v){0.f, 0.f, 0.f, 0.f};
  const u16* vtb = Vt + (size_t)((b * H_ + h) * D_) * T_;
  const uint* prow32 = (const uint*)(&lds[wave][c16][0]);
  union { short8 s8; uint u[4]; } bf;
#pragma unroll
  for (int c = 0; c < 9; c++) {
    const int jbase = jt0 + c * 32;
    if (jbase + 31 < 0) continue;
#pragma unroll
    for (int w2 = 0; w2 < 4; w2++) bf.u[w2] = prow32[c * 16 + quad * 4 + w2];
    int j0 = jbase + quad * 8;
    j0 = (j0 < 0) ? 0 : ((j0 > T_ - 8) ? (T_ - 8) : j0);
    PRIO1();
#pragma unroll
    for (int md = 0; md < 4; md++) {
      const short8 af = *(const short8*)(vtb + (size_t)(md * 16 + c16) * T_ + j0);
      acc[md] = __builtin_amdgcn_mfma_f32_16x16x32_bf16(af, bf.s8, acc[md], 0, 0, 0);
    }
    PRIO0();
  }
#pragma unroll
  for (int md = 0; md < 4; md++) {
    uint u0 = (uint)f2bf(acc[md][0]) | ((uint)f2bf(acc[md][1]) << 16);
    uint u1 = (uint)f2bf(acc[md][2]) | ((uint)f2bf(acc[md][3]) << 16);
    uint2 pk = make_uint2(u0, u1);
    u16* dst = o + (size_t)(b * T_ + qt + c16) * C_ + h * D_ + md * 16 + quad * 4;
    *(uint2*)dst = pk;
  }
}

// ---------------- both layers' retrieval projections ---------------
__global__ void k_ret2(const float* __restrict__ rc, const float* __restrict__ rW,
                       float* __restrict__ ret) {
  const int l = blockIdx.x >> 3;
  const int bid = blockIdx.x & 7;
  const int b = bid >> 2;
  const int col = (bid & 3) * 256 + threadIdx.x;
  const float* rWl = rW + (size_t)l * C_ * C_;
  float s = 0.f;
  for (int k = 0; k < C_; k++) s += rc[b * C_ + k] * rWl[(size_t)k * C_ + col];
  ret[(size_t)l * B_ * C_ + b * C_ + col] = s;
}

// ---------------- launcher ----------------
extern "C" void kernel_launch(void* const* d_in, const int* in_sizes, int n_in,
                              void* d_out, int out_size, void* d_ws, size_t ws_size,
                              hipStream_t stream) {
  (void)in_sizes; (void)n_in; (void)out_size; (void)ws_size;
  const float* xin  = (const float*)d_in[0];
  const float* rc   = (const float*)d_in[1];
  const float* n1g  = (const float*)d_in[2];
  const float* Wqkv = (const float*)d_in[3];
  const float* Wpro = (const float*)d_in[4];
  const float* gW   = (const float*)d_in[5];
  const float* gb   = (const float*)d_in[6];
  const float* rW   = (const float*)d_in[7];
  const float* n2g  = (const float*)d_in[8];
  const float* fgW  = (const float*)d_in[9];
  const float* fuW  = (const float*)d_in[10];
  const float* fdW  = (const float*)d_in[11];

  static bool attr_done = false;
  if (!attr_done) {
    hipFuncSetAttribute((const void*)k_g256, hipFuncAttributeMaxDynamicSharedMemorySize, 131072);
    hipFuncSetAttribute((const void*)k_g256s, hipFuncAttributeMaxDynamicSharedMemorySize, 131072);
    hipFuncSetAttribute((const void*)k_g256n<1>, hipFuncAttributeMaxDynamicSharedMemorySize, 98304);
    hipFuncSetAttribute((const void*)k_g256n<2>, hipFuncAttributeMaxDynamicSharedMemorySize, 98304);
    attr_done = true;
  }

  // ---- workspace layout ----
  char* w = (char*)d_ws;
  float* gates = (float*)(w);                            // 32 KB (per-layer, reused)
  float* retb  = (float*)(w + 32768);                    // 16 KB: [L][B][C]
  float* xf32  = (float*)(w + 65536);                    // 16.78 MB residual (f32)
  u16* hbuf    = (u16*)(w + 65536 + (size_t)NELEM * 4);  // 8.39 MB h | h2 | fd^T
  u16* big     = hbuf + NELEM;                           // 33.55 MB region
  u16* qkv  = big;                          // 25.17 MB (attn phase)
  u16* obuf = big + (size_t)NTOK * 3 * C_;  // 8.39 MB  (attn phase)
  u16* gbuf = big;                          // 33.55 MB (FFN phase)
  u16* wT  = (u16*)d_out;                    // 8.39 MB
  u16* wTp = wT + (size_t)3 * C_ * C_;       // Wproj^T
  u16* Vt  = (u16*)d_out + (size_t)NELEM;    // 8.39 MB upper half
  u16* wT2 = Vt;                             // FFN alias
  float* Pf  = (float*)d_out;                // down z0 partial (16.78 MB, FFN tail)
  float* Pf2 = (float*)big;                  // proj z0 partial (16.78 MB; qkv dead after attn)

  k_ret2<<<16, 256, 0, stream>>>(rc, rW, retb);

  for (int l = 0; l < L_; l++) {
    // h = rms(x)*g1 + fused gate logits/softmax
    if (l == 0)
      k_rms_first<<<NTOK, 256, 0, stream>>>(xin, n1g, xf32, hbuf,
                                            gW, gb, gates);
    else
      k_rms_acc<<<NTOK, 256, 0, stream>>>(xf32, Pf, n1g + l * C_, hbuf,
                                          gW + (size_t)l * C_ * 3, gb + l * 3, gates);
    k_tr2<<<3072 + 1024, dim3(32, 8), 0, stream>>>(
        Wqkv + (size_t)l * C_ * 3 * C_, wT, C_, 3 * C_, 3072,
        Wpro + (size_t)l * C_ * C_, wTp, C_, C_);
    // qkv = h @ Wqkv  (8-phase 256^2, patch-swizzled)
    k_g256<<<dim3(NTOK / 256, 3 * C_ / 256, 1), 512, 131072, stream>>>(
        hbuf, wT, qkv, 3 * C_, C_);
    k_vt<<<dim3(64, 2, 32), dim3(32, 8), 0, stream>>>(qkv, Vt);
    k_attn<<<1024, 256, 0, stream>>>(qkv, Vt, obuf);
    // gate0*(o @ Wproj): z=2 — z0 partial -> Pf2, z1 RMW xf32
    k_g256n<1><<<dim3(NTOK / 256, C_ / 128, 2), 512, 98304, stream>>>(
        obuf, wTp, xf32, Pf2, gates, C_, C_);
    // x += Pf2 + gate2*ret; h2 = rms(x)*g2
    k_rms2mix<<<NTOK, 256, 0, stream>>>(xf32, gates, retb + (size_t)l * B_ * C_,
                                        Pf2, n2g + l * C_, hbuf);
    k_tr2<<<4096 + 4096, dim3(32, 8), 0, stream>>>(
        fgW + (size_t)l * C_ * F_, wT, C_, F_, 4096,
        fuW + (size_t)l * C_ * F_, wT2, C_, F_);
    // gbuf = silu(h2@Wg) * (h2@Wu)  (fused 8-phase 256x128, patch-swizzled)
    k_g256s<<<dim3(NTOK / 256, F_ / 128, 1), 512, 131072, stream>>>(
        hbuf, wT, wT2, gbuf, F_, C_);
    k_tr1<<<4096, dim3(32, 8), 0, stream>>>(fdW + (size_t)l * F_ * C_, hbuf, F_, C_);
    // down: z=2 — z0 writes f32 partial Pf (d_out, dead here), z1 RMWs xf32
    k_g256n<2><<<dim3(NTOK / 256, C_ / 128, 2), 512, 98304, stream>>>(
        gbuf, hbuf, xf32, Pf, nullptr, C_, F_);
  }

  // out = xf32 + Pf (Pf aliases d_out; in-place add)
  k_copyf_acc<<<NELEM / 256, 256, 0, stream>>>(xf32, (float*)d_out);
}

// Round 6
// 746.152 us; speedup vs baseline: 1.2246x; 1.0541x over previous
//
#include <hip/hip_runtime.h>

#define L_ 2
#define B_ 2
#define T_ 2048
#define C_ 1024
#define H_ 16
#define D_ 64
#define F_ 4096
#define NTOK 4096      // B*T
#define NELEM 4194304  // B*T*C

typedef unsigned short u16;
typedef __attribute__((ext_vector_type(8))) short short8;
typedef __attribute__((ext_vector_type(4))) float float4v;

__device__ __forceinline__ float bf2f(u16 u) {
  unsigned v = ((unsigned)u) << 16;
  return __builtin_bit_cast(float, v);
}
__device__ __forceinline__ u16 f2bf(float f) {
  unsigned u = __builtin_bit_cast(unsigned, f);
  u += 0x7FFFu + ((u >> 16) & 1u);   // round-to-nearest-even
  return (u16)(u >> 16);
}

// 2D-patch XCD chunking (requires gridDim.x == 16, gridDim.y % 4 == 0).
__device__ __forceinline__ void xcd_swz(int& bx, int& by) {
  const int gy4 = gridDim.y >> 2;
  const int f = by * 16 + bx;
  const int k = f & 7, s = f >> 3;
  bx = ((k & 1) << 3) + (s & 7);
  by = (k >> 1) * gy4 + (s >> 3);
}

// ---------------- elementwise ----------------
__global__ void k_copyf_acc(const float* __restrict__ in, float* __restrict__ out) {
  const int i = blockIdx.x * 256 + threadIdx.x;
  out[i] = in[i] + out[i];
}

// ---------------- RMSNorm + fused gate (block per row, C=1024) ----------------
__device__ __forceinline__ void rms_gate_tail(float* vloc, const float* __restrict__ g,
                                              u16* __restrict__ orow,
                                              const float* __restrict__ gw3,
                                              const float* __restrict__ gb3,
                                              float* __restrict__ gates, int row) {
  float s = vloc[0] * vloc[0] + vloc[1] * vloc[1] + vloc[2] * vloc[2] + vloc[3] * vloc[3];
#pragma unroll
  for (int o = 32; o; o >>= 1) s += __shfl_down(s, o);
  __shared__ float red[4];
  __shared__ float rsv;
  if ((threadIdx.x & 63) == 0) red[threadIdx.x >> 6] = s;
  __syncthreads();
  if (threadIdx.x == 0) {
    float t = red[0] + red[1] + red[2] + red[3];
    rsv = rsqrtf(t * (1.f / C_) + 1e-6f);
  }
  __syncthreads();
  const float rr = rsv;
  float s0 = 0.f, s2 = 0.f;
#pragma unroll
  for (int i = 0; i < 4; i++) {
    const int c = threadIdx.x + i * 256;
    const float h = vloc[i] * rr * g[c];
    orow[c] = f2bf(h);
    s0 += h * gw3[c * 3 + 0];
    s2 += h * gw3[c * 3 + 2];
  }
#pragma unroll
  for (int o = 32; o; o >>= 1) { s0 += __shfl_down(s0, o); s2 += __shfl_down(s2, o); }
  __shared__ float r0[4], r2[4];
  if ((threadIdx.x & 63) == 0) { r0[threadIdx.x >> 6] = s0; r2[threadIdx.x >> 6] = s2; }
  __syncthreads();
  if (threadIdx.x == 0) {
    const float l0 = r0[0] + r0[1] + r0[2] + r0[3] + gb3[0];
    const float l2 = r2[0] + r2[1] + r2[2] + r2[3] + gb3[2];
    const float m = fmaxf(l0, l2);
    const float e0 = __expf(l0 - m), e2 = __expf(l2 - m);
    const float inv = 1.f / (e0 + e2);
    gates[row * 2 + 0] = e0 * inv;
    gates[row * 2 + 1] = e2 * inv;
  }
}

__global__ __launch_bounds__(256) void k_rms_first(const float* __restrict__ xin,
                                                   const float* __restrict__ g,
                                                   float* __restrict__ x,
                                                   u16* __restrict__ out,
                                                   const float* __restrict__ gw3,
                                                   const float* __restrict__ gb3,
                                                   float* __restrict__ gates) {
  const int row = blockIdx.x;
  const float* sr = xin + (size_t)row * C_;
  float* xr = x + (size_t)row * C_;
  float vloc[4];
#pragma unroll
  for (int i = 0; i < 4; i++) {
    const int c = threadIdx.x + i * 256;
    const float v = sr[c];
    vloc[i] = v;
    xr[c] = v;
  }
  rms_gate_tail(vloc, g, out + (size_t)row * C_, gw3, gb3, gates, row);
}

__global__ __launch_bounds__(256) void k_rms_acc(float* __restrict__ x,
                                                 const float* __restrict__ pf,
                                                 const float* __restrict__ g,
                                                 u16* __restrict__ out,
                                                 const float* __restrict__ gw3,
                                                 const float* __restrict__ gb3,
                                                 float* __restrict__ gates) {
  const int row = blockIdx.x;
  float* xr = x + (size_t)row * C_;
  const float* pr = pf + (size_t)row * C_;
  float vloc[4];
#pragma unroll
  for (int i = 0; i < 4; i++) {
    const int c = threadIdx.x + i * 256;
    const float v = xr[c] + pr[c];
    vloc[i] = v;
    xr[c] = v;
  }
  rms_gate_tail(vloc, g, out + (size_t)row * C_, gw3, gb3, gates, row);
}

__global__ __launch_bounds__(256) void k_rms2mix(float* __restrict__ x,
                                                 const float* __restrict__ gates,
                                                 const float* __restrict__ ret,
                                                 const float* __restrict__ pf,
                                                 const float* __restrict__ g,
                                                 u16* __restrict__ out) {
  const int row = blockIdx.x;
  const int b = row >> 11;   // T=2048
  const float g2 = gates[row * 2 + 1];
  const float* rr_ = ret + b * C_;
  const float* pr = pf + (size_t)row * C_;
  float* xr = x + (size_t)row * C_;
  float vloc[4];
#pragma unroll
  for (int i = 0; i < 4; i++) {
    const int c = threadIdx.x + i * 256;
    const float v = xr[c] + pr[c] + g2 * rr_[c];
    vloc[i] = v;
    xr[c] = v;
  }
  float s = vloc[0] * vloc[0] + vloc[1] * vloc[1] + vloc[2] * vloc[2] + vloc[3] * vloc[3];
#pragma unroll
  for (int o = 32; o; o >>= 1) s += __shfl_down(s, o);
  __shared__ float red[4];
  __shared__ float rsv;
  if ((threadIdx.x & 63) == 0) red[threadIdx.x >> 6] = s;
  __syncthreads();
  if (threadIdx.x == 0) {
    float t = red[0] + red[1] + red[2] + red[3];
    rsv = rsqrtf(t * (1.f / C_) + 1e-6f);
  }
  __syncthreads();
  const float rr = rsv;
  u16* orow = out + (size_t)row * C_;
#pragma unroll
  for (int i = 0; i < 4; i++) {
    const int c = threadIdx.x + i * 256;
    orow[c] = f2bf(vloc[i] * rr * g[c]);
  }
}

// ---------------- batched transpose+convert: two f32 (K,N) -> bf16 (N,K) ----------
__global__ void k_tr2(const float* __restrict__ s0, u16* __restrict__ d0,
                      int K0, int N0, int t0,
                      const float* __restrict__ s1, u16* __restrict__ d1,
                      int K1, int N1) {
  __shared__ float tile[32][33];
  int t = blockIdx.x;
  const float* src; u16* dst; int K, N;
  if (t < t0) { src = s0; dst = d0; K = K0; N = N0; }
  else { t -= t0; src = s1; dst = d1; K = K1; N = N1; }
  const int ntx = N >> 5;
  const int tx = t % ntx, ty = t / ntx;
  const int x = tx * 32 + threadIdx.x;
  const int y0 = ty * 32 + threadIdx.y;
#pragma unroll
  for (int i = 0; i < 32; i += 8) tile[threadIdx.y + i][threadIdx.x] = src[(size_t)(y0 + i) * N + x];
  __syncthreads();
  const int x2 = ty * 32 + threadIdx.x;
  const int y2 = tx * 32 + threadIdx.y;
#pragma unroll
  for (int i = 0; i < 32; i += 8) dst[(size_t)(y2 + i) * K + x2] = f2bf(tile[threadIdx.x][threadIdx.y + i]);
}

// FFN transpose with 16-col g/u interleave into Bcat[2F][C]:
// weight col n of g -> Bcat row ((n>>4)<<5)+(n&15); of u -> +16.
__global__ void k_tr2i(const float* __restrict__ s0, const float* __restrict__ s1,
                       u16* __restrict__ dst, int t0) {
  __shared__ float tile[32][33];
  int t = blockIdx.x;
  const float* src; int ofs;
  if (t < t0) { src = s0; ofs = 0; }
  else { t -= t0; src = s1; ofs = 16; }
  const int N = F_, K = C_;
  const int ntx = N >> 5;
  const int tx = t % ntx, ty = t / ntx;
  const int x = tx * 32 + threadIdx.x;
  const int y0 = ty * 32 + threadIdx.y;
#pragma unroll
  for (int i = 0; i < 32; i += 8) tile[threadIdx.y + i][threadIdx.x] = src[(size_t)(y0 + i) * N + x];
  __syncthreads();
  const int x2 = ty * 32 + threadIdx.x;
  const int y2 = tx * 32 + threadIdx.y;
#pragma unroll
  for (int i = 0; i < 32; i += 8) {
    const int n = y2 + i;
    const int rowp = ((n >> 4) << 5) + (n & 15) + ofs;
    dst[(size_t)rowp * K + x2] = f2bf(tile[threadIdx.x][threadIdx.y + i]);
  }
}

__global__ void k_tr1(const float* __restrict__ in, u16* __restrict__ out, int K, int N) {
  __shared__ float tile[32][33];
  const int ntx = N >> 5;
  const int tx = blockIdx.x % ntx, ty = blockIdx.x / ntx;
  const int x = tx * 32 + threadIdx.x;
  const int y0 = ty * 32 + threadIdx.y;
#pragma unroll
  for (int i = 0; i < 32; i += 8) tile[threadIdx.y + i][threadIdx.x] = in[(size_t)(y0 + i) * N + x];
  __syncthreads();
  const int x2 = ty * 32 + threadIdx.x;
  const int y2 = tx * 32 + threadIdx.y;
#pragma unroll
  for (int i = 0; i < 32; i += 8) out[(size_t)(y2 + i) * K + x2] = f2bf(tile[threadIdx.x][threadIdx.y + i]);
}

// ================== 8-phase 256-wide-tile GEMM machinery ==================
#define VMW(n) asm volatile("s_waitcnt vmcnt(" #n ")" ::: "memory")
#define LGKM0 asm volatile("s_waitcnt lgkmcnt(0)" ::: "memory")
#define GBAR() __builtin_amdgcn_s_barrier()
#define PRIO1() __builtin_amdgcn_s_setprio(1)
#define PRIO0() __builtin_amdgcn_s_setprio(0)

// Stage one 128-row x 64-col bf16 half-tile: 2 x global_load_lds_dwordx4.
#define STG8(gsrc, grow0, dstbyte, kk)                                                    \
  do {                                                                                    \
    const u16* g0_ = (gsrc) + (size_t)((grow0) + wid * 8 + srow) * K + (kk) + scol;       \
    __builtin_amdgcn_global_load_lds(                                                     \
        (const __attribute__((address_space(1))) void*)g0_,                               \
        (__attribute__((address_space(3))) void*)(lc + (dstbyte) + wid * 8 * 128),        \
        16, 0, 0);                                                                        \
    const u16* g1_ = g0_ + (size_t)64 * K;                                                \
    __builtin_amdgcn_global_load_lds(                                                     \
        (const __attribute__((address_space(1))) void*)g1_,                               \
        (__attribute__((address_space(3))) void*)(lc + (dstbyte) + (64 + wid * 8) * 128), \
        16, 0, 0);                                                                        \
  } while (0)

#define RDA4(dst, bufbyte, ig0)                                                           \
  { _Pragma("unroll") for (int i_ = 0; i_ < 4; ++i_) {                                    \
      _Pragma("unroll") for (int s_ = 0; s_ < 2; ++s_)                                    \
        dst[i_][s_] = *(const short8*)(lc + (bufbyte) +                                   \
            (wm * 128 + ((ig0) + i_) * 16 + m16) * 128 + (((s_ * 4 + quad) ^ csw) * 16)); } }

#define RDB4(dst, bufbyte, jg0)                                                           \
  { _Pragma("unroll") for (int j_ = 0; j_ < 2; ++j_) {                                    \
      _Pragma("unroll") for (int s_ = 0; s_ < 2; ++s_)                                    \
        dst[j_][s_] = *(const short8*)(lc + (bufbyte) +                                   \
            (wn * 64 + ((jg0) + j_) * 16 + m16) * 128 + (((s_ * 4 + quad) ^ csw) * 16)); } }

#define RDBS(dst, bufbyte)                                                                \
  { _Pragma("unroll") for (int j_ = 0; j_ < 2; ++j_) {                                    \
      _Pragma("unroll") for (int s_ = 0; s_ < 2; ++s_)                                    \
        dst[j_][s_] = *(const short8*)(lc + (bufbyte) +                                   \
            (wn * 32 + j_ * 16 + m16) * 128 + (((s_ * 4 + quad) ^ csw) * 16)); } }

#define MM16(ig0, jg0, bv_)                                                               \
  { _Pragma("unroll") for (int i_ = 0; i_ < 4; ++i_) {                                    \
      _Pragma("unroll") for (int j_ = 0; j_ < 2; ++j_) {                                  \
        _Pragma("unroll") for (int s_ = 0; s_ < 2; ++s_)                                  \
          acc[(ig0) + i_][(jg0) + j_] = __builtin_amdgcn_mfma_f32_16x16x32_bf16(          \
              av[i_][s_], bv_[j_][s_], acc[(ig0) + i_][(jg0) + j_], 0, 0, 0); } } }

// 16-MFMA cluster using av8[ig0..ig0+3]
#define MMN(ig0, bv_)                                                                     \
  { _Pragma("unroll") for (int i_ = 0; i_ < 4; ++i_) {                                    \
      _Pragma("unroll") for (int j_ = 0; j_ < 2; ++j_) {                                  \
        _Pragma("unroll") for (int s_ = 0; s_ < 2; ++s_)                                  \
          acc[(ig0) + i_][j_] = __builtin_amdgcn_mfma_f32_16x16x32_bf16(                  \
              av8[(ig0) + i_][s_], bv_[j_][s_], acc[(ig0) + i_][j_], 0, 0, 0); } } }

// ---------------- plain 256x256 GEMM, 8-phase ----------
// EPI=0 (qkv): Cc = bf16(v); V-cols (>=2C) written transposed into Vt.
// EPI=3 (swiglu over Bcat): j-frags pair (g,u); Cc = bf16(silu(g)*u), width N.
template <int EPI>
__global__ __launch_bounds__(512, 2) void k_g256(const u16* __restrict__ A,
                                                 const u16* __restrict__ Bt,
                                                 u16* __restrict__ Cc,
                                                 u16* __restrict__ Vt,
                                                 int N, int K) {
  extern __shared__ __align__(16) u16 lds[];
  char* const lc = (char*)lds;
  enum { A0B = 0, B0B = 32768, A1B = 65536, B1B = 98304 };
  const int tid = threadIdx.x;
  const int wid = tid >> 6, lane = tid & 63;
  const int wm = wid >> 2, wn = wid & 3;
  const int quad = lane >> 4, m16 = lane & 15;
  const int srow = lane >> 3, sc = lane & 7;
  const int scol = ((sc ^ srow) & 7) * 8;
  const int csw = m16 & 7;
  int bx = blockIdx.x, by = blockIdx.y;
  xcd_swz(bx, by);
  const int m0 = bx * 256, n0 = by * 256;
  const int kbeg = 0;
  const int ntile = K >> 6;
  const int nit = ntile >> 1;

  float4v acc[8][4];
#pragma unroll
  for (int i = 0; i < 8; i++)
#pragma unroll
    for (int j = 0; j < 4; j++) acc[i][j] = (float4v){0.f, 0.f, 0.f, 0.f};
  short8 av[4][2], b01[2][2], b23[2][2];

  STG8(Bt, n0, B0B, kbeg);
  STG8(Bt, n0 + 128, B0B + 16384, kbeg);
  STG8(A, m0, A0B, kbeg);
  STG8(A, m0 + 128, A0B + 16384, kbeg);
  STG8(Bt, n0, B1B, kbeg + 64);
  STG8(Bt, n0 + 128, B1B + 16384, kbeg + 64);
  VMW(4);
  GBAR();

#pragma unroll 1
  for (int it = 0; it < nit; ++it) {
    const int t2 = 2 * it + 2, t3 = 2 * it + 3;
    const int k1 = kbeg + (2 * it + 1) * 64;
    const int k2 = kbeg + (t2 < ntile ? t2 : t2 - ntile) * 64;
    const int k3 = kbeg + (t3 < ntile ? t3 : t3 - ntile) * 64;
    RDA4(av, A0B, 0);
    RDB4(b01, B0B, 0);
    STG8(A, m0, A1B, k1);
    GBAR(); LGKM0;
    PRIO1(); MM16(0, 0, b01); PRIO0();
    GBAR();
    RDB4(b23, B0B, 2);
    STG8(A, m0 + 128, A1B + 16384, k1);
    GBAR(); LGKM0;
    PRIO1(); MM16(0, 2, b23); PRIO0();
    GBAR();
    RDA4(av, A0B, 4);
    STG8(Bt, n0, B0B, k2);
    GBAR(); LGKM0;
    PRIO1(); MM16(4, 2, b23); PRIO0();
    GBAR();
    STG8(Bt, n0 + 128, B0B + 16384, k2);
    VMW(4);
    GBAR(); LGKM0;
    PRIO1(); MM16(4, 0, b01); PRIO0();
    GBAR();
    RDA4(av, A1B, 0);
    RDB4(b01, B1B, 0);
    STG8(A, m0, A0B, k2);
    GBAR(); LGKM0;
    PRIO1(); MM16(0, 0, b01); PRIO0();
    GBAR();
    RDB4(b23, B1B, 2);
    STG8(A, m0 + 128, A0B + 16384, k2);
    GBAR(); LGKM0;
    PRIO1(); MM16(0, 2, b23); PRIO0();
    GBAR();
    RDA4(av, A1B, 4);
    STG8(Bt, n0, B1B, k3);
    GBAR(); LGKM0;
    PRIO1(); MM16(4, 2, b23); PRIO0();
    GBAR();
    STG8(Bt, n0 + 128, B1B + 16384, k3);
    VMW(4);
    GBAR(); LGKM0;
    PRIO1(); MM16(4, 0, b01); PRIO0();
    GBAR();
  }

  if (EPI == 3) {
    // Bcat pairing: j=2p (g) and j=2p+1 (u) hold the same output cols.
#pragma unroll
    for (int i = 0; i < 8; i++) {
      const int row0 = m0 + wm * 128 + i * 16 + quad * 4;
#pragma unroll
      for (int jp = 0; jp < 2; jp++) {
        const int col = by * 128 + wn * 32 + jp * 16 + m16;
#pragma unroll
        for (int r = 0; r < 4; r++) {
          const float g = acc[i][jp * 2][r];
          const float u = acc[i][jp * 2 + 1][r];
          Cc[(size_t)(row0 + r) * N + col] = f2bf(u * g / (1.f + __expf(-g)));
        }
      }
    }
  } else {
#pragma unroll
    for (int i = 0; i < 8; i++) {
      const int row0 = m0 + wm * 128 + i * 16 + quad * 4;
#pragma unroll
      for (int j = 0; j < 4; j++) {
        const int colb = n0 + wn * 64 + j * 16;
        if (colb >= 2 * C_) {
          // V-part: write transposed into Vt[(b*H+h)*64+d][tok], 4 toks packed
          const int d = colb + m16 - 2 * C_;
          const int bh = d >> 6;           // head (uniform across lanes)
          const int dd = d & 63;
          const int b_ = row0 >> 11;
          const int tok = row0 & (T_ - 1);
          uint u0 = (uint)f2bf(acc[i][j][0]) | ((uint)f2bf(acc[i][j][1]) << 16);
          uint u1 = (uint)f2bf(acc[i][j][2]) | ((uint)f2bf(acc[i][j][3]) << 16);
          *(uint2*)(Vt + (size_t)((b_ * H_ + bh) * D_ + dd) * T_ + tok) = make_uint2(u0, u1);
        } else {
          const int col = colb + m16;
#pragma unroll
          for (int r = 0; r < 4; r++)
            Cc[(size_t)(row0 + r) * N + col] = f2bf(acc[i][j][r]);
        }
      }
    }
  }
}

// ---------------- 256x128 single-B 4-phase GEMM (no atomics, split-K z=2) ----------
// EPI=1 (proj):  sv = gates[row*2]*v ; EPI=2 (down): sv = v
// z0: Pf[idx] = sv ; z1: Xf[idx] += sv   (single-writer each)
template <int EPI>
__global__ __launch_bounds__(512, 2) void k_g256n(const u16* __restrict__ A,
                                                  const u16* __restrict__ Bt,
                                                  float* __restrict__ Xf,
                                                  float* __restrict__ Pf,
                                                  const float* __restrict__ gates,
                                                  int N, int K) {
  extern __shared__ __align__(16) u16 lds[];
  char* const lc = (char*)lds;
  // buf0: A[0,32K) B[32K,48K); buf1: A[48K,80K) B[80K,96K)
  enum { SA0 = 0, SB0 = 32768, SA1 = 49152, SB1 = 81920 };
  const int tid = threadIdx.x;
  const int wid = tid >> 6, lane = tid & 63;
  const int wm = wid >> 2, wn = wid & 3;
  const int quad = lane >> 4, m16 = lane & 15;
  const int srow = lane >> 3, sc = lane & 7;
  const int scol = ((sc ^ srow) & 7) * 8;
  const int csw = m16 & 7;
  int bx = blockIdx.x, by = blockIdx.y;
  xcd_swz(bx, by);
  const int m0 = bx * 256, n0 = by * 128;
  const int Kslice = K / gridDim.z;
  const int kbeg = blockIdx.z * Kslice;
  const int ntile = Kslice >> 6;
  const int nit = ntile >> 1;

  float4v acc[8][2];
#pragma unroll
  for (int i = 0; i < 8; i++)
#pragma unroll
    for (int j = 0; j < 2; j++) acc[i][j] = (float4v){0.f, 0.f, 0.f, 0.f};
  short8 av8[8][2], bv[2][2];

  STG8(Bt, n0, SB0, kbeg);
  STG8(A, m0, SA0, kbeg);
  STG8(A, m0 + 128, SA0 + 16384, kbeg);
  STG8(Bt, n0, SB1, kbeg + 64);
  STG8(A, m0, SA1, kbeg + 64);
  STG8(A, m0 + 128, SA1 + 16384, kbeg + 64);
  VMW(6);
  GBAR();

#pragma unroll 1
  for (int it = 0; it < nit; ++it) {
    const int t2 = 2 * it + 2, t3 = 2 * it + 3;
    const int k2 = kbeg + (t2 < ntile ? t2 : t2 - ntile) * 64;  // wraps last iter (dead)
    const int k3 = kbeg + (t3 < ntile ? t3 : t3 - ntile) * 64;
    RDA4(av8, SA0, 0);
    RDA4((&av8[4]), SA0, 4);
    RDBS(bv, SB0);
    GBAR(); LGKM0;
    PRIO1(); MMN(0, bv); PRIO0();
    GBAR();
    STG8(Bt, n0, SB0, k2);
    STG8(A, m0, SA0, k2);
    STG8(A, m0 + 128, SA0 + 16384, k2);
    VMW(6);
    GBAR(); LGKM0;
    PRIO1(); MMN(4, bv); PRIO0();
    GBAR();
    RDA4(av8, SA1, 0);
    RDA4((&av8[4]), SA1, 4);
    RDBS(bv, SB1);
    GBAR(); LGKM0;
    PRIO1(); MMN(0, bv); PRIO0();
    GBAR();
    STG8(Bt, n0, SB1, k3);
    STG8(A, m0, SA1, k3);
    STG8(A, m0 + 128, SA1 + 16384, k3);
    VMW(6);
    GBAR(); LGKM0;
    PRIO1(); MMN(4, bv); PRIO0();
    GBAR();
  }

#pragma unroll
  for (int i = 0; i < 8; i++) {
    const int row0 = m0 + wm * 128 + i * 16 + quad * 4;
#pragma unroll
    for (int j = 0; j < 2; j++) {
      const int col = n0 + wn * 32 + j * 16 + m16;
#pragma unroll
      for (int r = 0; r < 4; r++) {
        const size_t idx = (size_t)(row0 + r) * N + col;
        const float v = acc[i][j][r];
        const float sv = (EPI == 1) ? gates[(row0 + r) * 2] * v : v;
        if (blockIdx.z == 0) Pf[idx] = sv;
        else Xf[idx] += sv;
      }
    }
  }
}

// ---------------- fused attention ----------------
__global__ __launch_bounds__(256) void k_attn(const u16* __restrict__ qkv,
                                              const u16* __restrict__ Vt,
                                              u16* __restrict__ o) {
  __shared__ u16 lds[4][16][290];
  const int wave = threadIdx.x >> 6;
  const int bid = ((blockIdx.x & 7) << 7) + (blockIdx.x >> 3);
  const int widG = bid * 4 + wave;
  const int lane = threadIdx.x & 63;
  const int quad = lane >> 4;
  const int c16 = lane & 15;
  const int qt = (widG & 127) * 16;
  const int h = (widG >> 7) & 15;
  const int b = widG >> 11;
  const size_t rs = 3 * C_;
  const int jt0 = qt - 256;

  const u16* qrow = qkv + (size_t)(b * T_ + qt + c16) * rs + h * D_ + quad * 8;
  const short8 a0 = *(const short8*)(qrow);
  const short8 a1 = *(const short8*)(qrow + 32);
  float4v S[17];
  const short8 z8 = (short8){0, 0, 0, 0, 0, 0, 0, 0};
#pragma unroll
  for (int t = 0; t < 17; t++) {
    if (jt0 + t * 16 + 15 < 0) { S[t] = (float4v){0.f, 0.f, 0.f, 0.f}; continue; }
    const int j = jt0 + t * 16 + c16;
    short8 b0 = z8, b1 = z8;
    if (j >= 0) {
      const u16* krow = qkv + (size_t)(b * T_ + j) * rs + C_ + h * D_ + quad * 8;
      b0 = *(const short8*)(krow);
      b1 = *(const short8*)(krow + 32);
    }
    float4v z = (float4v){0.f, 0.f, 0.f, 0.f};
    PRIO1();
    z = __builtin_amdgcn_mfma_f32_16x16x32_bf16(a0, b0, z, 0, 0, 0);
    z = __builtin_amdgcn_mfma_f32_16x16x32_bf16(a1, b1, z, 0, 0, 0);
    PRIO0();
    S[t] = z;
  }
#pragma unroll
  for (int r = 0; r < 4; r++) {
    const int q = qt + quad * 4 + r;
    float mx = -1.0e30f;
#pragma unroll
    for (int t = 0; t < 17; t++) {
      const int j = jt0 + t * 16 + c16;
      const int w = j - q + 255;
      const bool vis = (j >= 0) && (w >= 0) && (w < 256);
      if (vis) {
        const float s = S[t][r] * 0.125f;
        S[t][r] = s;
        mx = fmaxf(mx, s);
      } else {
        S[t][r] = -1.0e30f;
      }
    }
#pragma unroll
    for (int o2 = 1; o2 < 16; o2 <<= 1) mx = fmaxf(mx, __shfl_xor(mx, o2));
    float sum = 0.f;
#pragma unroll
    for (int t = 0; t < 17; t++) {
      const float e = (S[t][r] > -0.9e30f) ? __expf(S[t][r] - mx) : 0.f;
      S[t][r] = e;
      sum += e;
    }
#pragma unroll
    for (int o2 = 1; o2 < 16; o2 <<= 1) sum += __shfl_xor(sum, o2);
    const float inv = 1.f / fmaxf(sum, 1e-30f);
    const int prow = quad * 4 + r;
#pragma unroll
    for (int t = 0; t < 17; t++) lds[wave][prow][t * 16 + c16] = f2bf(S[t][r] * inv);
    lds[wave][prow][272 + c16] = 0;
  }
  __syncthreads();

  float4v acc[4];
#pragma unroll
  for (int md = 0; md < 4; md++) acc[md] = (float4v){0.f, 0.f, 0.f, 0.f};
  const u16* vtb = Vt + (size_t)((b * H_ + h) * D_) * T_;
  const uint* prow32 = (const uint*)(&lds[wave][c16][0]);
  union { short8 s8; uint u[4]; } bf;
#pragma unroll
  for (int c = 0; c < 9; c++) {
    const int jbase = jt0 + c * 32;
    if (jbase + 31 < 0) continue;
#pragma unroll
    for (int w2 = 0; w2 < 4; w2++) bf.u[w2] = prow32[c * 16 + quad * 4 + w2];
    int j0 = jbase + quad * 8;
    j0 = (j0 < 0) ? 0 : ((j0 > T_ - 8) ? (T_ - 8) : j0);
    PRIO1();
#pragma unroll
    for (int md = 0; md < 4; md++) {
      const short8 af = *(const short8*)(vtb + (size_t)(md * 16 + c16) * T_ + j0);
      acc[md] = __builtin_amdgcn_mfma_f32_16x16x32_bf16(af, bf.s8, acc[md], 0, 0, 0);
    }
    PRIO0();
  }
#pragma unroll
  for (int md = 0; md < 4; md++) {
    uint u0 = (uint)f2bf(acc[md][0]) | ((uint)f2bf(acc[md][1]) << 16);
    uint u1 = (uint)f2bf(acc[md][2]) | ((uint)f2bf(acc[md][3]) << 16);
    uint2 pk = make_uint2(u0, u1);
    u16* dst = o + (size_t)(b * T_ + qt + c16) * C_ + h * D_ + md * 16 + quad * 4;
    *(uint2*)dst = pk;
  }
}

// ---------------- both layers' retrieval projections (k-sliced, 256 blocks) -------
__global__ __launch_bounds__(256) void k_ret2(const float* __restrict__ rc,
                                              const float* __restrict__ rW,
                                              float* __restrict__ ret) {
  // grid 256: l(2) x b(2) x 64 col-chunks of 16
  const int l = blockIdx.x >> 7;
  const int b = (blockIdx.x >> 6) & 1;
  const int cc = blockIdx.x & 63;
  const int col = cc * 16 + (threadIdx.x & 15);
  const int ks = threadIdx.x >> 4;      // 16 k-slices of 64
  const float* rWl = rW + (size_t)l * C_ * C_;
  const float* rcb = rc + b * C_;
  float s = 0.f;
  for (int k = ks * 64; k < ks * 64 + 64; k++) s += rcb[k] * rWl[(size_t)k * C_ + col];
  __shared__ float red[256];
  red[threadIdx.x] = s;
  __syncthreads();
  if (threadIdx.x < 16) {
    float t = 0.f;
#pragma unroll
    for (int i = 0; i < 16; i++) t += red[i * 16 + threadIdx.x];
    ret[(size_t)l * B_ * C_ + b * C_ + cc * 16 + threadIdx.x] = t;
  }
}

// ---------------- launcher ----------------
extern "C" void kernel_launch(void* const* d_in, const int* in_sizes, int n_in,
                              void* d_out, int out_size, void* d_ws, size_t ws_size,
                              hipStream_t stream) {
  (void)in_sizes; (void)n_in; (void)out_size; (void)ws_size;
  const float* xin  = (const float*)d_in[0];
  const float* rc   = (const float*)d_in[1];
  const float* n1g  = (const float*)d_in[2];
  const float* Wqkv = (const float*)d_in[3];
  const float* Wpro = (const float*)d_in[4];
  const float* gW   = (const float*)d_in[5];
  const float* gb   = (const float*)d_in[6];
  const float* rW   = (const float*)d_in[7];
  const float* n2g  = (const float*)d_in[8];
  const float* fgW  = (const float*)d_in[9];
  const float* fuW  = (const float*)d_in[10];
  const float* fdW  = (const float*)d_in[11];

  static bool attr_done = false;
  if (!attr_done) {
    hipFuncSetAttribute((const void*)k_g256<0>, hipFuncAttributeMaxDynamicSharedMemorySize, 131072);
    hipFuncSetAttribute((const void*)k_g256<3>, hipFuncAttributeMaxDynamicSharedMemorySize, 131072);
    hipFuncSetAttribute((const void*)k_g256n<1>, hipFuncAttributeMaxDynamicSharedMemorySize, 98304);
    hipFuncSetAttribute((const void*)k_g256n<2>, hipFuncAttributeMaxDynamicSharedMemorySize, 98304);
    attr_done = true;
  }

  // ---- workspace layout ----
  char* w = (char*)d_ws;
  float* gates = (float*)(w);                            // 32 KB (per-layer, reused)
  float* retb  = (float*)(w + 32768);                    // 16 KB: [L][B][C]
  float* xf32  = (float*)(w + 65536);                    // 16.78 MB residual (f32)
  u16* hbuf    = (u16*)(w + 65536 + (size_t)NELEM * 4);  // 8.39 MB h | h2 | fd^T
  u16* big     = hbuf + NELEM;                           // 33.55 MB region
  u16* qkv  = big;                          // 25.17 MB (attn phase)
  u16* obuf = big + (size_t)NTOK * 3 * C_;  // 8.39 MB  (attn phase)
  u16* gbuf = big;                          // 33.55 MB (FFN phase)
  u16* wT  = (u16*)d_out;                    // 8.39 MB lower (Wqkv^T + Wproj^T)
  u16* wTp = wT + (size_t)3 * C_ * C_;       // Wproj^T
  u16* Vt  = (u16*)d_out + (size_t)NELEM;    // 8.39 MB upper (V transposed)
  u16* Bcat = (u16*)d_out;                   // 16.78 MB FFN interleaved [8192][1024]
  float* Pf  = (float*)d_out;                // down z0 partial (16.78 MB, FFN tail)
  float* Pf2 = (float*)big;                  // proj z0 partial (qkv dead after attn)

  k_ret2<<<256, 256, 0, stream>>>(rc, rW, retb);

  for (int l = 0; l < L_; l++) {
    // h = rms(x)*g1 + fused gate logits/softmax
    if (l == 0)
      k_rms_first<<<NTOK, 256, 0, stream>>>(xin, n1g, xf32, hbuf,
                                            gW, gb, gates);
    else
      k_rms_acc<<<NTOK, 256, 0, stream>>>(xf32, Pf, n1g + l * C_, hbuf,
                                          gW + (size_t)l * C_ * 3, gb + l * 3, gates);
    k_tr2<<<3072 + 1024, dim3(32, 8), 0, stream>>>(
        Wqkv + (size_t)l * C_ * 3 * C_, wT, C_, 3 * C_, 3072,
        Wpro + (size_t)l * C_ * C_, wTp, C_, C_);
    // qkv = h @ Wqkv; V-cols written transposed to Vt in-epilogue (k_vt fused)
    k_g256<0><<<dim3(NTOK / 256, 3 * C_ / 256, 1), 512, 131072, stream>>>(
        hbuf, wT, qkv, Vt, 3 * C_, C_);
    k_attn<<<1024, 256, 0, stream>>>(qkv, Vt, obuf);
    // gate0*(o @ Wproj): z=2 — z0 partial -> Pf2, z1 RMW xf32
    k_g256n<1><<<dim3(NTOK / 256, C_ / 128, 2), 512, 98304, stream>>>(
        obuf, wTp, xf32, Pf2, gates, C_, C_);
    // x += Pf2 + gate2*ret; h2 = rms(x)*g2
    k_rms2mix<<<NTOK, 256, 0, stream>>>(xf32, gates, retb + (size_t)l * B_ * C_,
                                        Pf2, n2g + l * C_, hbuf);
    // FFN weights -> interleaved Bcat (g/u 16-col interleave)
    k_tr2i<<<4096 + 4096, dim3(32, 8), 0, stream>>>(
        fgW + (size_t)l * C_ * F_, fuW + (size_t)l * C_ * F_, Bcat, 4096);
    // gbuf = silu(h2@Wg)*(h2@Wu) as ONE plain 2-stream GEMM over Bcat
    k_g256<3><<<dim3(NTOK / 256, 2 * F_ / 256, 1), 512, 131072, stream>>>(
        hbuf, Bcat, gbuf, nullptr, F_, C_);
    k_tr1<<<4096, dim3(32, 8), 0, stream>>>(fdW + (size_t)l * F_ * C_, hbuf, F_, C_);
    // down: z=2 — z0 writes f32 partial Pf (d_out, dead here), z1 RMWs xf32
    k_g256n<2><<<dim3(NTOK / 256, C_ / 128, 2), 512, 98304, stream>>>(
        gbuf, hbuf, xf32, Pf, nullptr, C_, F_);
  }

  // out = xf32 + Pf (Pf aliases d_out; in-place add)
  k_copyf_acc<<<NELEM / 256, 256, 0, stream>>>(xf32, (float*)d_out);
}